// Round 10
// baseline (1458.530 us; speedup 1.0000x reference)
//
#include <hip/hip_runtime.h>
#include <hip/hip_bf16.h>

// ---------------------------------------------------------------------------
// DimeNet++ interaction block, round 10:
//   - GEMM kernels (k1, kbig): 128-thread blocks, 2 waves x 32 rows/wave
//     (2x 16-row A-fragments). Each B LDS read now feeds 6 MFMAs instead of
//     3 -> halves the LDS-read traffic that bounded round 9 (MfmaUtil 21.7%).
//   - everything else (CSR rank trick, e1fill, gather, wprep) unchanged.
// ---------------------------------------------------------------------------

typedef __attribute__((ext_vector_type(8))) short bf16x8;
typedef __attribute__((ext_vector_type(4))) float f32x4;
typedef __attribute__((ext_vector_type(4))) unsigned int u32x4;

__device__ __forceinline__ float silu_f(float v) {
    return v * __builtin_amdgcn_rcpf(1.0f + __expf(-v));
}
__device__ __forceinline__ short f2bf(float f) {          // RNE (wprep only)
    unsigned u = __float_as_uint(f);
    unsigned r = u + 0x7fffu + ((u >> 16) & 1u);
    return (short)(r >> 16);
}
__device__ __forceinline__ float bf2f(short s) {
    return __uint_as_float(((unsigned)(unsigned short)s) << 16);
}

__device__ __forceinline__ unsigned cvt_pk_bf16(float a, float b) {
    __hip_bfloat162 h = __float22bfloat162_rn(float2{a, b});   // v_cvt_pk_bf16_f32
    return *reinterpret_cast<unsigned*>(&h);
}
__device__ __forceinline__ void split44(f32x4 a, f32x4 b, bf16x8& hi, bf16x8& lo) {
    float f[8] = {a[0], a[1], a[2], a[3], b[0], b[1], b[2], b[3]};
    u32x4 H, L;
    #pragma unroll
    for (int j = 0; j < 4; ++j) {
        const float f0 = f[2 * j], f1 = f[2 * j + 1];
        const unsigned h = cvt_pk_bf16(f0, f1);
        const float r0 = f0 - __uint_as_float(h << 16);
        const float r1 = f1 - __uint_as_float(h & 0xffff0000u);
        H[j] = h;
        L[j] = cvt_pk_bf16(r0, r1);
    }
    hi = __builtin_bit_cast(bf16x8, H);
    lo = __builtin_bit_cast(bf16x8, L);
}

__device__ __forceinline__ void gll16(const void* g, void* l) {
    __builtin_amdgcn_global_load_lds((const __attribute__((address_space(1))) void*)g,
                                     (__attribute__((address_space(3))) void*)l, 16, 0, 0);
}
// stage a 16 KB slab with 2 waves (8 x 1KB iters per wave)
__device__ __forceinline__ void stage16(const char* g, short* l, int lane, int wid) {
    #pragma unroll
    for (int i = 0; i < 8; ++i) {
        const int off = ((i * 2 + wid) << 10);
        gll16(g + off + lane * 16, (char*)l + off);
    }
}
// stage an 8 KB slab with 2 waves
__device__ __forceinline__ void stage8(const char* g, short* l, int lane, int wid) {
    #pragma unroll
    for (int i = 0; i < 4; ++i) {
        const int off = ((i * 2 + wid) << 10);
        gll16(g + off + lane * 16, (char*)l + off);
    }
}

// one 32-k step, 3-pass split MFMA, TWO row-fragments sharing each B read
template<int NF>
__device__ __forceinline__ void mfma_ks2(bf16x8 ah0, bf16x8 al0, bf16x8 ah1, bf16x8 al1,
                                         const short* slot, int acol, int kq,
                                         f32x4* acc0, f32x4* acc1) {
    #pragma unroll
    for (int n = 0; n < NF; ++n) {
        const int c = n * 16 + acol;
        const int x = (c >> 2) & 1;
        const int sw = (kq ^ (c & 3)) << 3;
        const bf16x8 bh = *(const bf16x8*)&slot[c * 64 + x * 32 + sw];
        const bf16x8 bl = *(const bf16x8*)&slot[c * 64 + (x ^ 1) * 32 + sw];
        acc0[n] = __builtin_amdgcn_mfma_f32_16x16x32_bf16(ah0, bh, acc0[n], 0, 0, 0);
        acc0[n] = __builtin_amdgcn_mfma_f32_16x16x32_bf16(al0, bh, acc0[n], 0, 0, 0);
        acc0[n] = __builtin_amdgcn_mfma_f32_16x16x32_bf16(ah0, bl, acc0[n], 0, 0, 0);
        acc1[n] = __builtin_amdgcn_mfma_f32_16x16x32_bf16(ah1, bh, acc1[n], 0, 0, 0);
        acc1[n] = __builtin_amdgcn_mfma_f32_16x16x32_bf16(al1, bh, acc1[n], 0, 0, 0);
        acc1[n] = __builtin_amdgcn_mfma_f32_16x16x32_bf16(ah1, bl, acc1[n], 0, 0, 0);
    }
}
template<int NF>
__device__ __forceinline__ void gphase2(f32x4 a00, f32x4 a01, f32x4 a10, f32x4 a11,
                                        const short* slot, int acol, int kq,
                                        f32x4* acc0, f32x4* acc1) {
    bf16x8 ah0, al0, ah1, al1;
    split44(a00, a01, ah0, al0);
    split44(a10, a11, ah1, al1);
    mfma_ks2<NF>(ah0, al0, ah1, al1, slot, acol, kq, acc0, acc1);
}
template<int NF>
__device__ __forceinline__ void tphase2(const float* tl, int rb0, int rb1, int q,
                                        int kq, int acol, const short* slot,
                                        f32x4* acc0, f32x4* acc1) {
    const f32x4 ta0 = *(const f32x4*)&tl[rb0 + q * 32 + kq * 8];
    const f32x4 tb0 = *(const f32x4*)&tl[rb0 + q * 32 + kq * 8 + 4];
    const f32x4 ta1 = *(const f32x4*)&tl[rb1 + q * 32 + kq * 8];
    const f32x4 tb1 = *(const f32x4*)&tl[rb1 + q * 32 + kq * 8 + 4];
    bf16x8 ah0, al0, ah1, al1;
    split44(ta0, tb0, ah0, al0);
    split44(ta1, tb1, ah1, al1);
    mfma_ks2<NF>(ah0, al0, ah1, al1, slot, acol, kq, acc0, acc1);
}

__device__ __forceinline__ void tgemm4(const char* img, const char* imgnext,
                                       short* sA, short* sB, const float* tl,
                                       int rb0, int rb1, int kq, int acol,
                                       int lane, int wid, f32x4* acc0, f32x4* acc1)
{
    stage16(img + 16384, sB, lane, wid);
    tphase2<8>(tl, rb0, rb1, 0, kq, acol, sA, acc0, acc1); __syncthreads();
    stage16(img + 32768, sA, lane, wid);
    tphase2<8>(tl, rb0, rb1, 1, kq, acol, sB, acc0, acc1); __syncthreads();
    stage16(img + 49152, sB, lane, wid);
    tphase2<8>(tl, rb0, rb1, 2, kq, acol, sA, acc0, acc1); __syncthreads();
    if (imgnext) stage16(imgnext, sA, lane, wid);
    tphase2<8>(tl, rb0, rb1, 3, kq, acol, sB, acc0, acc1); __syncthreads();
}

#define TPITCH 132

// ---------------- weight pre-conversion -------------------------------------
struct WDesc { const float* src; char* dst; int K; int N; };
struct WPrepArgs { WDesc w[11]; };

__global__ void wprep_kernel(WPrepArgs args) {
    const WDesc d = args.w[blockIdx.y];
    const int h = blockIdx.x;
    if (h * 32 >= d.K) return;
    char* slab = d.dst + (size_t)h * d.N * 128;
    for (int idx = threadIdx.x; idx < d.N * 4; idx += 256) {
        const int c = idx >> 2, ch = idx & 3;
        bf16x8 hi, lo;
        #pragma unroll
        for (int j = 0; j < 8; ++j) {
            const float f = d.src[(size_t)(h * 32 + ch * 8 + j) * d.N + c];
            const short hb = f2bf(f);
            hi[j] = hb;
            lo[j] = f2bf(f - bf2f(hb));
        }
        const int x = (c >> 2) & 1;
        const int sw = (ch ^ (c & 3)) * 16;
        *(bf16x8*)(slab + c * 128 + x * 64 + sw)       = hi;
        *(bf16x8*)(slab + c * 128 + (x ^ 1) * 64 + sw) = lo;
    }
}

// ---------------- prologue / CSR --------------------------------------------

__global__ void rbf1_kernel(const float* __restrict__ rbf, const float* __restrict__ w_rbf1,
                            float* __restrict__ re1, int E) {
    const int i = blockIdx.x * 256 + threadIdx.x;
    const int e = i >> 3, p = i & 7;
    if (e < E) {
        float s = 0.f;
        #pragma unroll
        for (int q = 0; q < 6; ++q) s = fmaf(rbf[e * 6 + q], w_rbf1[q * 8 + p], s);
        re1[i] = s;
    }
}

__global__ void count_rank_kernel(const int* __restrict__ idx_ji, int* __restrict__ cnt,
                                  int* __restrict__ rank, int T) {
    const int i = (blockIdx.x * 256 + threadIdx.x) * 4;
    if (i + 3 < T) {
        const int4 j = *(const int4*)&idx_ji[i];
        int4 r;
        r.x = atomicAdd(&cnt[j.x], 1);
        r.y = atomicAdd(&cnt[j.y], 1);
        r.z = atomicAdd(&cnt[j.z], 1);
        r.w = atomicAdd(&cnt[j.w], 1);
        *(int4*)&rank[i] = r;
    } else {
        for (int k = i; k < T; ++k) rank[k] = atomicAdd(&cnt[idx_ji[k]], 1);
    }
}

__global__ void scan_partial_kernel(const int* __restrict__ cnt, int* __restrict__ partial, int E) {
    __shared__ int red[256];
    const int tid = threadIdx.x;
    const int base = blockIdx.x * 1024 + tid * 4;
    int s = 0;
    #pragma unroll
    for (int i = 0; i < 4; ++i) { const int g = base + i; if (g < E) s += cnt[g]; }
    red[tid] = s;
    __syncthreads();
    for (int off = 128; off > 0; off >>= 1) {
        if (tid < off) red[tid] += red[tid + off];
        __syncthreads();
    }
    if (tid == 0) partial[blockIdx.x] = red[0];
}

__global__ void scan_block_kernel(const int* __restrict__ partial, int* __restrict__ blockoff,
                                  int NB, int* offsets, int E) {
    __shared__ int red[256];
    const int tid = threadIdx.x;
    int v[4]; int s = 0;
    #pragma unroll
    for (int i = 0; i < 4; ++i) { const int g = tid * 4 + i; v[i] = (g < NB) ? partial[g] : 0; s += v[i]; }
    red[tid] = s;
    __syncthreads();
    for (int off = 1; off < 256; off <<= 1) {
        const int add = (tid >= off) ? red[tid - off] : 0;
        __syncthreads();
        red[tid] += add;
        __syncthreads();
    }
    int excl = (tid == 0) ? 0 : red[tid - 1];
    #pragma unroll
    for (int i = 0; i < 4; ++i) { const int g = tid * 4 + i; if (g < NB) blockoff[g] = excl; excl += v[i]; }
    if (tid == 255) offsets[E] = red[255];
}

__global__ void scan_final_kernel(const int* __restrict__ cnt, const int* __restrict__ blockoff,
                                  int* __restrict__ offsets, int E) {
    __shared__ int red[256];
    const int tid = threadIdx.x;
    const int base = blockIdx.x * 1024 + tid * 4;
    int v[4]; int s = 0;
    #pragma unroll
    for (int i = 0; i < 4; ++i) { const int g = base + i; v[i] = (g < E) ? cnt[g] : 0; s += v[i]; }
    red[tid] = s;
    __syncthreads();
    for (int off = 1; off < 256; off <<= 1) {
        const int add = (tid >= off) ? red[tid - off] : 0;
        __syncthreads();
        red[tid] += add;
        __syncthreads();
    }
    int run = blockoff[blockIdx.x] + ((tid == 0) ? 0 : red[tid - 1]);
    #pragma unroll
    for (int i = 0; i < 4; ++i) {
        const int g = base + i;
        if (g < E) offsets[g] = run;
        run += v[i];
    }
}

__launch_bounds__(256, 3)
__global__ void e1fill_kernel(const float* __restrict__ sbf, const float* __restrict__ w_sbf1,
                              const int* __restrict__ idx_ji, const int* __restrict__ idx_kj,
                              const int* __restrict__ rank, const int* __restrict__ offsets,
                              float* __restrict__ E1p, int* __restrict__ kjp, int T)
{
    __shared__ float s_lds[256 * 43];
    const int tid = threadIdx.x;
    const long long t0 = (long long)blockIdx.x * 256;
    const int nrow = min(256, (int)(T - t0));
    const int nel  = nrow * 42;
    const float* base = sbf + t0 * 42;

    for (int i = tid * 4; i + 3 < nel; i += 1024) {
        const float4 v = *(const float4*)&base[i];
        s_lds[(i + 0) + (i + 0) / 42] = v.x;
        s_lds[(i + 1) + (i + 1) / 42] = v.y;
        s_lds[(i + 2) + (i + 2) / 42] = v.z;
        s_lds[(i + 3) + (i + 3) / 42] = v.w;
    }
    const int tail0 = nel & ~3;
    if (tid < nel - tail0) { const int g = tail0 + tid; s_lds[g + g / 42] = base[g]; }
    __syncthreads();

    const int t = (int)t0 + tid;
    if (t >= T) return;
    const float* srow = &s_lds[tid * 43];
    float e1[8] = {0.f, 0.f, 0.f, 0.f, 0.f, 0.f, 0.f, 0.f};
    #pragma unroll
    for (int q = 0; q < 42; ++q) {
        const float s = srow[q];
        #pragma unroll
        for (int p = 0; p < 8; ++p) e1[p] = fmaf(s, w_sbf1[q * 8 + p], e1[p]);
    }
    const int ji  = idx_ji[t];
    const int pos = offsets[ji] + rank[t];
    *(float4*)&E1p[(size_t)pos * 8]     = *(float4*)&e1[0];
    *(float4*)&E1p[(size_t)pos * 8 + 4] = *(float4*)&e1[4];
    kjp[pos] = idx_kj[t];
}

__launch_bounds__(256, 4)
__global__ void gather_kernel(const float* __restrict__ E1p, const int* __restrict__ kjp,
                              const float* __restrict__ w_sbf2, const int* __restrict__ offsets,
                              const float* __restrict__ xkjd, float* __restrict__ agg, int E)
{
    const int tid  = threadIdx.x;
    const int lane = tid & 63;
    const int e    = blockIdx.x * 4 + (tid >> 6);

    float w2[8];
    #pragma unroll
    for (int p = 0; p < 8; ++p) w2[p] = w_sbf2[p * 64 + lane];

    if (e >= E) return;
    const int j0 = __builtin_amdgcn_readfirstlane(offsets[e]);
    const int j1 = __builtin_amdgcn_readfirstlane(offsets[e + 1]);

    float acc = 0.f;
    if (j0 < j1) {
        int kj = __builtin_amdgcn_readfirstlane(kjp[j0]);
        float4 ea = *(const float4*)&E1p[(size_t)j0 * 8];
        float4 eb = *(const float4*)&E1p[(size_t)j0 * 8 + 4];
        for (int j = j0; j < j1; ++j) {
            const float xv = xkjd[(size_t)kj * 64 + lane];
            int kn = 0; float4 ean = {}, ebn = {};
            if (j + 1 < j1) {
                kn  = __builtin_amdgcn_readfirstlane(kjp[j + 1]);
                ean = *(const float4*)&E1p[(size_t)(j + 1) * 8];
                ebn = *(const float4*)&E1p[(size_t)(j + 1) * 8 + 4];
            }
            float sv = ea.x * w2[0];
            sv = fmaf(ea.y, w2[1], sv);
            sv = fmaf(ea.z, w2[2], sv);
            sv = fmaf(ea.w, w2[3], sv);
            sv = fmaf(eb.x, w2[4], sv);
            sv = fmaf(eb.y, w2[5], sv);
            sv = fmaf(eb.z, w2[6], sv);
            sv = fmaf(eb.w, w2[7], sv);
            acc = fmaf(xv, sv, acc);
            kj = kn; ea = ean; eb = ebn;
        }
    }
    agg[(size_t)e * 64 + lane] = acc;
}

// ---------------- K1: W3 = silu((silu(x@w_kj+b)*rbf_e)@w_down) --------------
// 128 threads = 2 waves x 32 rows (2 row-frags), 64 rows/block.
__launch_bounds__(128, 1)
__global__ void k1_kernel(const float* __restrict__ x, const char* __restrict__ wkj_i,
                          const float* __restrict__ b_kj, const float* __restrict__ re1,
                          const float* __restrict__ w_rbf2, const char* __restrict__ wdn_i,
                          float* __restrict__ W3, int E)
{
    __shared__ short slotA[8192], slotB[8192];
    __shared__ float t_lds[64 * TPITCH];
    __shared__ float w2_lds[8 * 128];
    const int tid = threadIdx.x, lane = tid & 63, wid = tid >> 6;  // wid 0..1
    const int acol = lane & 15, kq = lane >> 4;
    const int row0 = blockIdx.x * 64 + wid * 32;   // wave's 32-row base

    stage16(wkj_i, slotA, lane, wid);

    f32x4 a[2][4][2];
    #pragma unroll
    for (int rf = 0; rf < 2; ++rf) {
        const int ar = row0 + rf * 16 + acol;
        const bool av = ar < E;
        const float* xr = x + (size_t)ar * 128;
        #pragma unroll
        for (int ks = 0; ks < 4; ++ks) {
            a[rf][ks][0] = f32x4{0.f, 0.f, 0.f, 0.f}; a[rf][ks][1] = f32x4{0.f, 0.f, 0.f, 0.f};
            if (av) { a[rf][ks][0] = *(const f32x4*)&xr[ks * 32 + kq * 8];
                      a[rf][ks][1] = *(const f32x4*)&xr[ks * 32 + kq * 8 + 4]; }
        }
    }
    float bv[8];
    #pragma unroll
    for (int n = 0; n < 8; ++n) bv[n] = b_kj[n * 16 + acol];
    f32x4 e1a[2][4], e1b[2][4];
    #pragma unroll
    for (int rf = 0; rf < 2; ++rf)
        #pragma unroll
        for (int r = 0; r < 4; ++r) {
            const int ge = row0 + rf * 16 + kq * 4 + r;
            e1a[rf][r] = f32x4{0.f, 0.f, 0.f, 0.f}; e1b[rf][r] = f32x4{0.f, 0.f, 0.f, 0.f};
            if (ge < E) { e1a[rf][r] = *(const f32x4*)&re1[(size_t)ge * 8];
                          e1b[rf][r] = *(const f32x4*)&re1[(size_t)ge * 8 + 4]; }
        }
    for (int i = tid; i < 1024; i += 128) w2_lds[i] = w_rbf2[i];
    __syncthreads();

    f32x4 acc0[8], acc1[8];
    #pragma unroll
    for (int n = 0; n < 8; ++n) { acc0[n] = f32x4{0.f, 0.f, 0.f, 0.f}; acc1[n] = f32x4{0.f, 0.f, 0.f, 0.f}; }

    stage16(wkj_i + 16384, slotB, lane, wid);
    gphase2<8>(a[0][0][0], a[0][0][1], a[1][0][0], a[1][0][1], slotA, acol, kq, acc0, acc1); __syncthreads();
    stage16(wkj_i + 32768, slotA, lane, wid);
    gphase2<8>(a[0][1][0], a[0][1][1], a[1][1][0], a[1][1][1], slotB, acol, kq, acc0, acc1); __syncthreads();
    stage16(wkj_i + 49152, slotB, lane, wid);
    gphase2<8>(a[0][2][0], a[0][2][1], a[1][2][0], a[1][2][1], slotA, acol, kq, acc0, acc1); __syncthreads();
    stage8(wdn_i, slotA, lane, wid);
    gphase2<8>(a[0][3][0], a[0][3][1], a[1][3][0], a[1][3][1], slotB, acol, kq, acc0, acc1); __syncthreads();

    #pragma unroll
    for (int rf = 0; rf < 2; ++rf) {
        f32x4* acc = rf ? acc1 : acc0;
        #pragma unroll
        for (int n = 0; n < 8; ++n) {
            const int c = n * 16 + acol;
            float w2c[8];
            #pragma unroll
            for (int p = 0; p < 8; ++p) w2c[p] = w2_lds[p * 128 + c];
            #pragma unroll
            for (int r = 0; r < 4; ++r) {
                float s = e1a[rf][r][0] * w2c[0];
                s = fmaf(e1a[rf][r][1], w2c[1], s);
                s = fmaf(e1a[rf][r][2], w2c[2], s);
                s = fmaf(e1a[rf][r][3], w2c[3], s);
                s = fmaf(e1b[rf][r][0], w2c[4], s);
                s = fmaf(e1b[rf][r][1], w2c[5], s);
                s = fmaf(e1b[rf][r][2], w2c[6], s);
                s = fmaf(e1b[rf][r][3], w2c[7], s);
                t_lds[(wid * 32 + rf * 16 + kq * 4 + r) * TPITCH + c] = silu_f(acc[n][r] + bv[n]) * s;
            }
        }
    }
    __syncthreads();

    f32x4 acc20[4], acc21[4];
    #pragma unroll
    for (int n = 0; n < 4; ++n) { acc20[n] = f32x4{0.f, 0.f, 0.f, 0.f}; acc21[n] = f32x4{0.f, 0.f, 0.f, 0.f}; }
    const int rb0 = (wid * 32 + acol) * TPITCH;
    const int rb1 = (wid * 32 + 16 + acol) * TPITCH;

    stage8(wdn_i + 8192, slotB, lane, wid);
    tphase2<4>(t_lds, rb0, rb1, 0, kq, acol, slotA, acc20, acc21); __syncthreads();
    stage8(wdn_i + 16384, slotA, lane, wid);
    tphase2<4>(t_lds, rb0, rb1, 1, kq, acol, slotB, acc20, acc21); __syncthreads();
    stage8(wdn_i + 24576, slotB, lane, wid);
    tphase2<4>(t_lds, rb0, rb1, 2, kq, acol, slotA, acc20, acc21); __syncthreads();
    tphase2<4>(t_lds, rb0, rb1, 3, kq, acol, slotB, acc20, acc21);

    #pragma unroll
    for (int rf = 0; rf < 2; ++rf) {
        f32x4* acc = rf ? acc21 : acc20;
        #pragma unroll
        for (int n = 0; n < 4; ++n) {
            const int c = n * 16 + acol;
            #pragma unroll
            for (int r = 0; r < 4; ++r) {
                const int ge = row0 + rf * 16 + kq * 4 + r;
                if (ge < E) W3[(size_t)ge * 64 + c] = silu_f(acc[n][r]);
            }
        }
    }
}

// ---------------- kbig: h0 -> res1 -> w_bs+skip -> res2 -> res3 (9 GEMMs) ---
struct KBigArgs {
    const float* x; const float* W4; float* out;
    const char *wji, *wup, *r1w1, *r1w2, *wbs, *r2w1, *r2w2, *r3w1, *r3w2;
    const float *bji, *r1b1, *r1b2, *bbs, *r2b1, *r2b2, *r3b1, *r3b2;
    int E;
};

__launch_bounds__(128, 1)
__global__ void kbig_kernel(KBigArgs A_)
{
    __shared__ short slotA[8192], slotB[8192];
    __shared__ float t_lds[64 * TPITCH];
    const int tid = threadIdx.x, lane = tid & 63, wid = tid >> 6;  // 0..1
    const int acol = lane & 15, kq = lane >> 4;
    const int row0 = blockIdx.x * 64 + wid * 32;
    const int E = A_.E;
    const int rb0 = (wid * 32 + acol) * TPITCH;
    const int rb1 = (wid * 32 + 16 + acol) * TPITCH;

    stage16(A_.wji, slotA, lane, wid);

    f32x4 a[2][4][2], u[2][2][2];
    #pragma unroll
    for (int rf = 0; rf < 2; ++rf) {
        const int ar = row0 + rf * 16 + acol;
        const bool av = ar < E;
        const float* xr = A_.x + (size_t)ar * 128;
        const float* wr = A_.W4 + (size_t)ar * 64;
        #pragma unroll
        for (int ks = 0; ks < 4; ++ks) {
            a[rf][ks][0] = f32x4{0.f, 0.f, 0.f, 0.f}; a[rf][ks][1] = f32x4{0.f, 0.f, 0.f, 0.f};
            if (av) { a[rf][ks][0] = *(const f32x4*)&xr[ks * 32 + kq * 8];
                      a[rf][ks][1] = *(const f32x4*)&xr[ks * 32 + kq * 8 + 4]; }
        }
        #pragma unroll
        for (int ks = 0; ks < 2; ++ks) {
            u[rf][ks][0] = f32x4{0.f, 0.f, 0.f, 0.f}; u[rf][ks][1] = f32x4{0.f, 0.f, 0.f, 0.f};
            if (av) { u[rf][ks][0] = *(const f32x4*)&wr[ks * 32 + kq * 8];
                      u[rf][ks][1] = *(const f32x4*)&wr[ks * 32 + kq * 8 + 4]; }
        }
    }
    __syncthreads();

    f32x4 acc0[8], acc1[8];
    #pragma unroll
    for (int n = 0; n < 8; ++n) { acc0[n] = f32x4{0.f, 0.f, 0.f, 0.f}; acc1[n] = f32x4{0.f, 0.f, 0.f, 0.f}; }

    // GEMM1: x @ w_ji
    stage16(A_.wji + 16384, slotB, lane, wid);
    gphase2<8>(a[0][0][0], a[0][0][1], a[1][0][0], a[1][0][1], slotA, acol, kq, acc0, acc1); __syncthreads();
    stage16(A_.wji + 32768, slotA, lane, wid);
    gphase2<8>(a[0][1][0], a[0][1][1], a[1][1][0], a[1][1][1], slotB, acol, kq, acc0, acc1); __syncthreads();
    stage16(A_.wji + 49152, slotB, lane, wid);
    gphase2<8>(a[0][2][0], a[0][2][1], a[1][2][0], a[1][2][1], slotA, acol, kq, acc0, acc1); __syncthreads();
    stage16(A_.wup, slotA, lane, wid);
    gphase2<8>(a[0][3][0], a[0][3][1], a[1][3][0], a[1][3][1], slotB, acol, kq, acc0, acc1); __syncthreads();

    float res[2][8][4];
    #pragma unroll
    for (int rf = 0; rf < 2; ++rf) {
        f32x4* acc = rf ? acc1 : acc0;
        #pragma unroll
        for (int n = 0; n < 8; ++n) {
            const float bv = A_.bji[n * 16 + acol];
            #pragma unroll
            for (int r = 0; r < 4; ++r) { res[rf][n][r] = silu_f(acc[n][r] + bv); acc[n][r] = 0.f; }
        }
    }

    // GEMM2: W4 @ w_up (K=64)
    stage16(A_.wup + 16384, slotB, lane, wid);
    gphase2<8>(u[0][0][0], u[0][0][1], u[1][0][0], u[1][0][1], slotA, acol, kq, acc0, acc1); __syncthreads();
    stage16(A_.r1w1, slotA, lane, wid);
    gphase2<8>(u[0][1][0], u[0][1][1], u[1][1][0], u[1][1][1], slotB, acol, kq, acc0, acc1); __syncthreads();

    #pragma unroll
    for (int rf = 0; rf < 2; ++rf) {
        f32x4* acc = rf ? acc1 : acc0;
        #pragma unroll
        for (int n = 0; n < 8; ++n) {
            const int c = n * 16 + acol;
            #pragma unroll
            for (int r = 0; r < 4; ++r) {
                res[rf][n][r] += silu_f(acc[n][r]);             // h0
                t_lds[(wid * 32 + rf * 16 + kq * 4 + r) * TPITCH + c] = res[rf][n][r];
                acc[n][r] = 0.f;
            }
        }
    }
    __syncthreads();

    // GEMM3: h0 @ r1w1 -> t1
    tgemm4(A_.r1w1, A_.r1w2, slotA, slotB, t_lds, rb0, rb1, kq, acol, lane, wid, acc0, acc1);
    #pragma unroll
    for (int rf = 0; rf < 2; ++rf) {
        f32x4* acc = rf ? acc1 : acc0;
        #pragma unroll
        for (int n = 0; n < 8; ++n) {
            const float bv = A_.r1b1[n * 16 + acol];
            const int c = n * 16 + acol;
            #pragma unroll
            for (int r = 0; r < 4; ++r) {
                t_lds[(wid * 32 + rf * 16 + kq * 4 + r) * TPITCH + c] = silu_f(acc[n][r] + bv);
                acc[n][r] = 0.f;
            }
        }
    }
    __syncthreads();

    // GEMM4: t1 @ r1w2 -> t2 = h0 + silu(.)
    tgemm4(A_.r1w2, A_.wbs, slotA, slotB, t_lds, rb0, rb1, kq, acol, lane, wid, acc0, acc1);
    #pragma unroll
    for (int rf = 0; rf < 2; ++rf) {
        f32x4* acc = rf ? acc1 : acc0;
        #pragma unroll
        for (int n = 0; n < 8; ++n) {
            const float bv = A_.r1b2[n * 16 + acol];
            const int c = n * 16 + acol;
            #pragma unroll
            for (int r = 0; r < 4; ++r) {
                t_lds[(wid * 32 + rf * 16 + kq * 4 + r) * TPITCH + c] = res[rf][n][r] + silu_f(acc[n][r] + bv);
                acc[n][r] = 0.f;
            }
        }
    }
    __syncthreads();

    // GEMM5: t2 @ w_bs -> h2 = silu(.) + x
    tgemm4(A_.wbs, A_.r2w1, slotA, slotB, t_lds, rb0, rb1, kq, acol, lane, wid, acc0, acc1);
    #pragma unroll
    for (int rf = 0; rf < 2; ++rf) {
        f32x4* acc = rf ? acc1 : acc0;
        #pragma unroll
        for (int n = 0; n < 8; ++n) {
            const float bv = A_.bbs[n * 16 + acol];
            const int c = n * 16 + acol;
            #pragma unroll
            for (int r = 0; r < 4; ++r) {
                const int ge = row0 + rf * 16 + kq * 4 + r;
                const float xv = (ge < E) ? A_.x[(size_t)ge * 128 + c] : 0.f;
                res[rf][n][r] = silu_f(acc[n][r] + bv) + xv;    // h2
                t_lds[(wid * 32 + rf * 16 + kq * 4 + r) * TPITCH + c] = res[rf][n][r];
                acc[n][r] = 0.f;
            }
        }
    }
    __syncthreads();

    // GEMM6: h2 @ r2w1 -> t3
    tgemm4(A_.r2w1, A_.r2w2, slotA, slotB, t_lds, rb0, rb1, kq, acol, lane, wid, acc0, acc1);
    #pragma unroll
    for (int rf = 0; rf < 2; ++rf) {
        f32x4* acc = rf ? acc1 : acc0;
        #pragma unroll
        for (int n = 0; n < 8; ++n) {
            const float bv = A_.r2b1[n * 16 + acol];
            const int c = n * 16 + acol;
            #pragma unroll
            for (int r = 0; r < 4; ++r) {
                t_lds[(wid * 32 + rf * 16 + kq * 4 + r) * TPITCH + c] = silu_f(acc[n][r] + bv);
                acc[n][r] = 0.f;
            }
        }
    }
    __syncthreads();

    // GEMM7: t3 @ r2w2 -> h3 = h2 + silu(.)
    tgemm4(A_.r2w2, A_.r3w1, slotA, slotB, t_lds, rb0, rb1, kq, acol, lane, wid, acc0, acc1);
    #pragma unroll
    for (int rf = 0; rf < 2; ++rf) {
        f32x4* acc = rf ? acc1 : acc0;
        #pragma unroll
        for (int n = 0; n < 8; ++n) {
            const float bv = A_.r2b2[n * 16 + acol];
            const int c = n * 16 + acol;
            #pragma unroll
            for (int r = 0; r < 4; ++r) {
                res[rf][n][r] += silu_f(acc[n][r] + bv);        // h3
                t_lds[(wid * 32 + rf * 16 + kq * 4 + r) * TPITCH + c] = res[rf][n][r];
                acc[n][r] = 0.f;
            }
        }
    }
    __syncthreads();

    // GEMM8: h3 @ r3w1 -> t4
    tgemm4(A_.r3w1, A_.r3w2, slotA, slotB, t_lds, rb0, rb1, kq, acol, lane, wid, acc0, acc1);
    #pragma unroll
    for (int rf = 0; rf < 2; ++rf) {
        f32x4* acc = rf ? acc1 : acc0;
        #pragma unroll
        for (int n = 0; n < 8; ++n) {
            const float bv = A_.r3b1[n * 16 + acol];
            const int c = n * 16 + acol;
            #pragma unroll
            for (int r = 0; r < 4; ++r) {
                t_lds[(wid * 32 + rf * 16 + kq * 4 + r) * TPITCH + c] = silu_f(acc[n][r] + bv);
                acc[n][r] = 0.f;
            }
        }
    }
    __syncthreads();

    // GEMM9: t4 @ r3w2 -> out = h3 + silu(.)
    tgemm4(A_.r3w2, nullptr, slotA, slotB, t_lds, rb0, rb1, kq, acol, lane, wid, acc0, acc1);
    #pragma unroll
    for (int rf = 0; rf < 2; ++rf) {
        f32x4* acc = rf ? acc1 : acc0;
        #pragma unroll
        for (int n = 0; n < 8; ++n) {
            const float bv = A_.r3b2[n * 16 + acol];
            const int c = n * 16 + acol;
            #pragma unroll
            for (int r = 0; r < 4; ++r) {
                const int ge = row0 + rf * 16 + kq * 4 + r;
                if (ge < E)
                    A_.out[(size_t)ge * 128 + c] = res[rf][n][r] + silu_f(acc[n][r] + bv);
            }
        }
    }
}

// ---------------------------------------------------------------------------

extern "C" void kernel_launch(void* const* d_in, const int* in_sizes, int n_in,
                              void* d_out, int out_size, void* d_ws, size_t ws_size,
                              hipStream_t stream)
{
    const float* x      = (const float*)d_in[0];
    const float* rbf    = (const float*)d_in[1];
    const float* sbf    = (const float*)d_in[2];
    const int*   idx_kj = (const int*)d_in[3];
    const int*   idx_ji = (const int*)d_in[4];
    const float* w_rbf1 = (const float*)d_in[5];
    const float* w_rbf2 = (const float*)d_in[6];
    const float* w_sbf1 = (const float*)d_in[7];
    const float* w_sbf2 = (const float*)d_in[8];
    const float* w_kj   = (const float*)d_in[9];
    const float* b_kj   = (const float*)d_in[10];
    const float* w_ji   = (const float*)d_in[11];
    const float* b_ji   = (const float*)d_in[12];
    const float* w_down = (const float*)d_in[13];
    const float* w_up   = (const float*)d_in[14];
    const float* r1w1   = (const float*)d_in[15];
    const float* r1b1   = (const float*)d_in[16];
    const float* r1w2   = (const float*)d_in[17];
    const float* r1b2   = (const float*)d_in[18];
    const float* w_bs   = (const float*)d_in[19];
    const float* b_bs   = (const float*)d_in[20];
    const float* r2w1   = (const float*)d_in[21];
    const float* r2b1   = (const float*)d_in[22];
    const float* r2w2   = (const float*)d_in[23];
    const float* r2b2   = (const float*)d_in[24];
    const float* r3w1   = (const float*)d_in[25];
    const float* r3b1   = (const float*)d_in[26];
    const float* r3w2   = (const float*)d_in[27];
    const float* r3b2   = (const float*)d_in[28];

    const int E = in_sizes[0] / 128;
    const int T = in_sizes[2] / 42;

    float* OUT = (float*)d_out;
    float* W3  = (float*)((char*)d_ws + (size_t)E * 128 * 4);         // [E,64]
    float* W4  = (float*)((char*)d_ws + (size_t)E * 128 * 4
                                      + (size_t)E * 64 * 4);          // [E,64]

    int*   cnt      = (int*)d_ws;                            // [E]
    int*   offsets  = cnt + (E + 64);                        // [E+1]
    int*   partial  = offsets + (E + 64);                    // [<=1024]
    int*   blockoff = partial + 1024;                        // [<=1024]
    float* E1p      = (float*)((char*)d_ws + (4u << 20));    // [T,8]   96 MB
    int*   kjp      = (int*)((char*)d_ws + (102u << 20));    // [T]     12 MB
    float* re1      = (float*)((char*)d_ws + (116u << 20));  // [E,8]  9.6 MB
    char*  wimg     = (char*)d_ws + (130u << 20);            // 640 KB
    int*   rank     = (int*)((char*)d_ws + (134u << 20));    // [T]     12 MB

    char* wkj_i  = wimg;
    char* wji_i  = wimg + 65536;
    char* wdn_i  = wimg + 131072;
    char* wup_i  = wimg + 163840;
    char* r1w1_i = wimg + 196608;
    char* r1w2_i = wimg + 262144;
    char* wbs_i  = wimg + 327680;
    char* r2w1_i = wimg + 393216;
    char* r2w2_i = wimg + 458752;
    char* r3w1_i = wimg + 524288;
    char* r3w2_i = wimg + 589824;

    WPrepArgs pa;
    pa.w[0]  = {w_kj,   wkj_i,  128, 128};
    pa.w[1]  = {w_ji,   wji_i,  128, 128};
    pa.w[2]  = {w_down, wdn_i,  128,  64};
    pa.w[3]  = {w_up,   wup_i,   64, 128};
    pa.w[4]  = {r1w1,   r1w1_i, 128, 128};
    pa.w[5]  = {r1w2,   r1w2_i, 128, 128};
    pa.w[6]  = {w_bs,   wbs_i,  128, 128};
    pa.w[7]  = {r2w1,   r2w1_i, 128, 128};
    pa.w[8]  = {r2w2,   r2w2_i, 128, 128};
    pa.w[9]  = {r3w1,   r3w1_i, 128, 128};
    pa.w[10] = {r3w2,   r3w2_i, 128, 128};

    const dim3 b256(256), b128(128);
    const int gB  = (E + 63) / 64;
    const int gT  = (T + 255) / 256;
    const int gT4 = (T + 1023) / 1024;
    const int NB  = (E + 1023) / 1024;
    const int gE4 = (E + 3) / 4;
    const int gR  = (E * 8 + 255) / 256;

    wprep_kernel<<<dim3(4, 11), b256, 0, stream>>>(pa);
    rbf1_kernel<<<gR, b256, 0, stream>>>(rbf, w_rbf1, re1, E);
    hipMemsetAsync(cnt, 0, (size_t)E * 4, stream);
    count_rank_kernel<<<gT4, b256, 0, stream>>>(idx_ji, cnt, rank, T);
    scan_partial_kernel<<<NB, b256, 0, stream>>>(cnt, partial, E);
    scan_block_kernel<<<1, b256, 0, stream>>>(partial, blockoff, NB, offsets, E);
    scan_final_kernel<<<NB, b256, 0, stream>>>(cnt, blockoff, offsets, E);
    e1fill_kernel<<<gT, b256, 0, stream>>>(sbf, w_sbf1, idx_ji, idx_kj, rank, offsets, E1p, kjp, T);

    k1_kernel<<<gB, b128, 0, stream>>>(x, wkj_i, b_kj, re1, w_rbf2, wdn_i, W3, E);
    gather_kernel<<<gE4, b256, 0, stream>>>(E1p, kjp, w_sbf2, offsets, W3, W4, E);

    KBigArgs ka;
    ka.x = x; ka.W4 = W4; ka.out = OUT;
    ka.wji = wji_i; ka.wup = wup_i; ka.r1w1 = r1w1_i; ka.r1w2 = r1w2_i; ka.wbs = wbs_i;
    ka.r2w1 = r2w1_i; ka.r2w2 = r2w2_i; ka.r3w1 = r3w1_i; ka.r3w2 = r3w2_i;
    ka.bji = b_ji; ka.r1b1 = r1b1; ka.r1b2 = r1b2; ka.bbs = b_bs;
    ka.r2b1 = r2b1; ka.r2b2 = r2b2; ka.r3b1 = r3b1; ka.r3b2 = r3b2;
    ka.E = E;
    kbig_kernel<<<gB, b128, 0, stream>>>(ka);
}

// Round 11
// 1259.301 us; speedup vs baseline: 1.1582x; 1.1582x over previous
//
#include <hip/hip_runtime.h>
#include <hip/hip_bf16.h>

// ---------------------------------------------------------------------------
// DimeNet++ interaction block, round 11:
//   Quadrant GEMM: 256 thr / 4 waves / 64 rows/block (round-9 occupancy),
//   wave (wr,wc) owns rows wr*32..+31 x cols wc*64..+63.
//   Each B LDS read feeds 6 MFMAs; per-phase LDS traffic 72->48 KB.
// ---------------------------------------------------------------------------

typedef __attribute__((ext_vector_type(8))) short bf16x8;
typedef __attribute__((ext_vector_type(4))) float f32x4;
typedef __attribute__((ext_vector_type(4))) unsigned int u32x4;

__device__ __forceinline__ float silu_f(float v) {
    return v * __builtin_amdgcn_rcpf(1.0f + __expf(-v));
}
__device__ __forceinline__ short f2bf(float f) {          // RNE (wprep only)
    unsigned u = __float_as_uint(f);
    unsigned r = u + 0x7fffu + ((u >> 16) & 1u);
    return (short)(r >> 16);
}
__device__ __forceinline__ float bf2f(short s) {
    return __uint_as_float(((unsigned)(unsigned short)s) << 16);
}

__device__ __forceinline__ unsigned cvt_pk_bf16(float a, float b) {
    __hip_bfloat162 h = __float22bfloat162_rn(float2{a, b});   // v_cvt_pk_bf16_f32
    return *reinterpret_cast<unsigned*>(&h);
}
__device__ __forceinline__ void split44(f32x4 a, f32x4 b, bf16x8& hi, bf16x8& lo) {
    float f[8] = {a[0], a[1], a[2], a[3], b[0], b[1], b[2], b[3]};
    u32x4 H, L;
    #pragma unroll
    for (int j = 0; j < 4; ++j) {
        const float f0 = f[2 * j], f1 = f[2 * j + 1];
        const unsigned h = cvt_pk_bf16(f0, f1);
        const float r0 = f0 - __uint_as_float(h << 16);
        const float r1 = f1 - __uint_as_float(h & 0xffff0000u);
        H[j] = h;
        L[j] = cvt_pk_bf16(r0, r1);
    }
    hi = __builtin_bit_cast(bf16x8, H);
    lo = __builtin_bit_cast(bf16x8, L);
}

__device__ __forceinline__ void gll16(const void* g, void* l) {
    __builtin_amdgcn_global_load_lds((const __attribute__((address_space(1))) void*)g,
                                     (__attribute__((address_space(3))) void*)l, 16, 0, 0);
}
// stage a 16 KB slab with 4 waves
__device__ __forceinline__ void stage16(const char* g, short* l, int lane, int wid) {
    #pragma unroll
    for (int i = 0; i < 4; ++i) {
        const int off = ((i * 4 + wid) << 10);
        gll16(g + off + lane * 16, (char*)l + off);
    }
}
// stage an 8 KB slab with 4 waves
__device__ __forceinline__ void stage8(const char* g, short* l, int lane, int wid) {
    #pragma unroll
    for (int i = 0; i < 2; ++i) {
        const int off = ((i * 4 + wid) << 10);
        gll16(g + off + lane * 16, (char*)l + off);
    }
}

// one 32-k step: 2 A-frags x NF col-frags, 3-pass split MFMA
template<int NF>
__device__ __forceinline__ void mfma_q(bf16x8 ah0, bf16x8 al0, bf16x8 ah1, bf16x8 al1,
                                       const short* slot, int cbase, int acol, int kq,
                                       f32x4* acc0, f32x4* acc1) {
    #pragma unroll
    for (int n = 0; n < NF; ++n) {
        const int c = cbase + n * 16 + acol;
        const int x = (c >> 2) & 1;
        const int sw = (kq ^ (c & 3)) << 3;
        const bf16x8 bh = *(const bf16x8*)&slot[c * 64 + x * 32 + sw];
        const bf16x8 bl = *(const bf16x8*)&slot[c * 64 + (x ^ 1) * 32 + sw];
        acc0[n] = __builtin_amdgcn_mfma_f32_16x16x32_bf16(ah0, bh, acc0[n], 0, 0, 0);
        acc0[n] = __builtin_amdgcn_mfma_f32_16x16x32_bf16(al0, bh, acc0[n], 0, 0, 0);
        acc0[n] = __builtin_amdgcn_mfma_f32_16x16x32_bf16(ah0, bl, acc0[n], 0, 0, 0);
        acc1[n] = __builtin_amdgcn_mfma_f32_16x16x32_bf16(ah1, bh, acc1[n], 0, 0, 0);
        acc1[n] = __builtin_amdgcn_mfma_f32_16x16x32_bf16(al1, bh, acc1[n], 0, 0, 0);
        acc1[n] = __builtin_amdgcn_mfma_f32_16x16x32_bf16(ah1, bl, acc1[n], 0, 0, 0);
    }
}
template<int NF>
__device__ __forceinline__ void gphase_q(f32x4 a00, f32x4 a01, f32x4 a10, f32x4 a11,
                                         const short* slot, int cbase, int acol, int kq,
                                         f32x4* acc0, f32x4* acc1) {
    bf16x8 ah0, al0, ah1, al1;
    split44(a00, a01, ah0, al0);
    split44(a10, a11, ah1, al1);
    mfma_q<NF>(ah0, al0, ah1, al1, slot, cbase, acol, kq, acc0, acc1);
}
template<int NF>
__device__ __forceinline__ void tphase_q(const float* tl, int rb0, int rb1, int q,
                                         int cbase, int kq, int acol, const short* slot,
                                         f32x4* acc0, f32x4* acc1) {
    const f32x4 ta0 = *(const f32x4*)&tl[rb0 + q * 32 + kq * 8];
    const f32x4 tb0 = *(const f32x4*)&tl[rb0 + q * 32 + kq * 8 + 4];
    const f32x4 ta1 = *(const f32x4*)&tl[rb1 + q * 32 + kq * 8];
    const f32x4 tb1 = *(const f32x4*)&tl[rb1 + q * 32 + kq * 8 + 4];
    bf16x8 ah0, al0, ah1, al1;
    split44(ta0, tb0, ah0, al0);
    split44(ta1, tb1, ah1, al1);
    mfma_q<NF>(ah0, al0, ah1, al1, slot, cbase, acol, kq, acc0, acc1);
}

__device__ __forceinline__ void tgemm4q(const char* img, const char* imgnext,
                                        short* sA, short* sB, const float* tl,
                                        int rb0, int rb1, int cbase, int kq, int acol,
                                        int lane, int wid, f32x4* acc0, f32x4* acc1)
{
    stage16(img + 16384, sB, lane, wid);
    tphase_q<4>(tl, rb0, rb1, 0, cbase, kq, acol, sA, acc0, acc1); __syncthreads();
    stage16(img + 32768, sA, lane, wid);
    tphase_q<4>(tl, rb0, rb1, 1, cbase, kq, acol, sB, acc0, acc1); __syncthreads();
    stage16(img + 49152, sB, lane, wid);
    tphase_q<4>(tl, rb0, rb1, 2, cbase, kq, acol, sA, acc0, acc1); __syncthreads();
    if (imgnext) stage16(imgnext, sA, lane, wid);
    tphase_q<4>(tl, rb0, rb1, 3, cbase, kq, acol, sB, acc0, acc1); __syncthreads();
}

#define TPITCH 132

// ---------------- weight pre-conversion -------------------------------------
struct WDesc { const float* src; char* dst; int K; int N; };
struct WPrepArgs { WDesc w[11]; };

__global__ void wprep_kernel(WPrepArgs args) {
    const WDesc d = args.w[blockIdx.y];
    const int h = blockIdx.x;
    if (h * 32 >= d.K) return;
    char* slab = d.dst + (size_t)h * d.N * 128;
    for (int idx = threadIdx.x; idx < d.N * 4; idx += 256) {
        const int c = idx >> 2, ch = idx & 3;
        bf16x8 hi, lo;
        #pragma unroll
        for (int j = 0; j < 8; ++j) {
            const float f = d.src[(size_t)(h * 32 + ch * 8 + j) * d.N + c];
            const short hb = f2bf(f);
            hi[j] = hb;
            lo[j] = f2bf(f - bf2f(hb));
        }
        const int x = (c >> 2) & 1;
        const int sw = (ch ^ (c & 3)) * 16;
        *(bf16x8*)(slab + c * 128 + x * 64 + sw)       = hi;
        *(bf16x8*)(slab + c * 128 + (x ^ 1) * 64 + sw) = lo;
    }
}

// ---------------- prologue / CSR --------------------------------------------

__global__ void rbf1_kernel(const float* __restrict__ rbf, const float* __restrict__ w_rbf1,
                            float* __restrict__ re1, int E) {
    const int i = blockIdx.x * 256 + threadIdx.x;
    const int e = i >> 3, p = i & 7;
    if (e < E) {
        float s = 0.f;
        #pragma unroll
        for (int q = 0; q < 6; ++q) s = fmaf(rbf[e * 6 + q], w_rbf1[q * 8 + p], s);
        re1[i] = s;
    }
}

__global__ void count_rank_kernel(const int* __restrict__ idx_ji, int* __restrict__ cnt,
                                  int* __restrict__ rank, int T) {
    const int i = (blockIdx.x * 256 + threadIdx.x) * 4;
    if (i + 3 < T) {
        const int4 j = *(const int4*)&idx_ji[i];
        int4 r;
        r.x = atomicAdd(&cnt[j.x], 1);
        r.y = atomicAdd(&cnt[j.y], 1);
        r.z = atomicAdd(&cnt[j.z], 1);
        r.w = atomicAdd(&cnt[j.w], 1);
        *(int4*)&rank[i] = r;
    } else {
        for (int k = i; k < T; ++k) rank[k] = atomicAdd(&cnt[idx_ji[k]], 1);
    }
}

__global__ void scan_partial_kernel(const int* __restrict__ cnt, int* __restrict__ partial, int E) {
    __shared__ int red[256];
    const int tid = threadIdx.x;
    const int base = blockIdx.x * 1024 + tid * 4;
    int s = 0;
    #pragma unroll
    for (int i = 0; i < 4; ++i) { const int g = base + i; if (g < E) s += cnt[g]; }
    red[tid] = s;
    __syncthreads();
    for (int off = 128; off > 0; off >>= 1) {
        if (tid < off) red[tid] += red[tid + off];
        __syncthreads();
    }
    if (tid == 0) partial[blockIdx.x] = red[0];
}

__global__ void scan_block_kernel(const int* __restrict__ partial, int* __restrict__ blockoff,
                                  int NB, int* offsets, int E) {
    __shared__ int red[256];
    const int tid = threadIdx.x;
    int v[4]; int s = 0;
    #pragma unroll
    for (int i = 0; i < 4; ++i) { const int g = tid * 4 + i; v[i] = (g < NB) ? partial[g] : 0; s += v[i]; }
    red[tid] = s;
    __syncthreads();
    for (int off = 1; off < 256; off <<= 1) {
        const int add = (tid >= off) ? red[tid - off] : 0;
        __syncthreads();
        red[tid] += add;
        __syncthreads();
    }
    int excl = (tid == 0) ? 0 : red[tid - 1];
    #pragma unroll
    for (int i = 0; i < 4; ++i) { const int g = tid * 4 + i; if (g < NB) blockoff[g] = excl; excl += v[i]; }
    if (tid == 255) offsets[E] = red[255];
}

__global__ void scan_final_kernel(const int* __restrict__ cnt, const int* __restrict__ blockoff,
                                  int* __restrict__ offsets, int E) {
    __shared__ int red[256];
    const int tid = threadIdx.x;
    const int base = blockIdx.x * 1024 + tid * 4;
    int v[4]; int s = 0;
    #pragma unroll
    for (int i = 0; i < 4; ++i) { const int g = base + i; v[i] = (g < E) ? cnt[g] : 0; s += v[i]; }
    red[tid] = s;
    __syncthreads();
    for (int off = 1; off < 256; off <<= 1) {
        const int add = (tid >= off) ? red[tid - off] : 0;
        __syncthreads();
        red[tid] += add;
        __syncthreads();
    }
    int run = blockoff[blockIdx.x] + ((tid == 0) ? 0 : red[tid - 1]);
    #pragma unroll
    for (int i = 0; i < 4; ++i) {
        const int g = base + i;
        if (g < E) offsets[g] = run;
        run += v[i];
    }
}

__launch_bounds__(256, 3)
__global__ void e1fill_kernel(const float* __restrict__ sbf, const float* __restrict__ w_sbf1,
                              const int* __restrict__ idx_ji, const int* __restrict__ idx_kj,
                              const int* __restrict__ rank, const int* __restrict__ offsets,
                              float* __restrict__ E1p, int* __restrict__ kjp, int T)
{
    __shared__ float s_lds[256 * 43];
    const int tid = threadIdx.x;
    const long long t0 = (long long)blockIdx.x * 256;
    const int nrow = min(256, (int)(T - t0));
    const int nel  = nrow * 42;
    const float* base = sbf + t0 * 42;

    for (int i = tid * 4; i + 3 < nel; i += 1024) {
        const float4 v = *(const float4*)&base[i];
        s_lds[(i + 0) + (i + 0) / 42] = v.x;
        s_lds[(i + 1) + (i + 1) / 42] = v.y;
        s_lds[(i + 2) + (i + 2) / 42] = v.z;
        s_lds[(i + 3) + (i + 3) / 42] = v.w;
    }
    const int tail0 = nel & ~3;
    if (tid < nel - tail0) { const int g = tail0 + tid; s_lds[g + g / 42] = base[g]; }
    __syncthreads();

    const int t = (int)t0 + tid;
    if (t >= T) return;
    const float* srow = &s_lds[tid * 43];
    float e1[8] = {0.f, 0.f, 0.f, 0.f, 0.f, 0.f, 0.f, 0.f};
    #pragma unroll
    for (int q = 0; q < 42; ++q) {
        const float s = srow[q];
        #pragma unroll
        for (int p = 0; p < 8; ++p) e1[p] = fmaf(s, w_sbf1[q * 8 + p], e1[p]);
    }
    const int ji  = idx_ji[t];
    const int pos = offsets[ji] + rank[t];
    *(float4*)&E1p[(size_t)pos * 8]     = *(float4*)&e1[0];
    *(float4*)&E1p[(size_t)pos * 8 + 4] = *(float4*)&e1[4];
    kjp[pos] = idx_kj[t];
}

__launch_bounds__(256, 4)
__global__ void gather_kernel(const float* __restrict__ E1p, const int* __restrict__ kjp,
                              const float* __restrict__ w_sbf2, const int* __restrict__ offsets,
                              const float* __restrict__ xkjd, float* __restrict__ agg, int E)
{
    const int tid  = threadIdx.x;
    const int lane = tid & 63;
    const int e    = blockIdx.x * 4 + (tid >> 6);

    float w2[8];
    #pragma unroll
    for (int p = 0; p < 8; ++p) w2[p] = w_sbf2[p * 64 + lane];

    if (e >= E) return;
    const int j0 = __builtin_amdgcn_readfirstlane(offsets[e]);
    const int j1 = __builtin_amdgcn_readfirstlane(offsets[e + 1]);

    float acc = 0.f;
    if (j0 < j1) {
        int kj = __builtin_amdgcn_readfirstlane(kjp[j0]);
        float4 ea = *(const float4*)&E1p[(size_t)j0 * 8];
        float4 eb = *(const float4*)&E1p[(size_t)j0 * 8 + 4];
        for (int j = j0; j < j1; ++j) {
            const float xv = xkjd[(size_t)kj * 64 + lane];
            int kn = 0; float4 ean = {}, ebn = {};
            if (j + 1 < j1) {
                kn  = __builtin_amdgcn_readfirstlane(kjp[j + 1]);
                ean = *(const float4*)&E1p[(size_t)(j + 1) * 8];
                ebn = *(const float4*)&E1p[(size_t)(j + 1) * 8 + 4];
            }
            float sv = ea.x * w2[0];
            sv = fmaf(ea.y, w2[1], sv);
            sv = fmaf(ea.z, w2[2], sv);
            sv = fmaf(ea.w, w2[3], sv);
            sv = fmaf(eb.x, w2[4], sv);
            sv = fmaf(eb.y, w2[5], sv);
            sv = fmaf(eb.z, w2[6], sv);
            sv = fmaf(eb.w, w2[7], sv);
            acc = fmaf(xv, sv, acc);
            kj = kn; ea = ean; eb = ebn;
        }
    }
    agg[(size_t)e * 64 + lane] = acc;
}

// ---------------- K1: W3 = silu((silu(x@w_kj+b)*rbf_e)@w_down) --------------
// 256 thr / 4 waves; wave (wr,wc): rows wr*32..+31, cols wc*64..+63 (G1) /
// wc*32..+31 (G2).
__launch_bounds__(256, 2)
__global__ void k1_kernel(const float* __restrict__ x, const char* __restrict__ wkj_i,
                          const float* __restrict__ b_kj, const float* __restrict__ re1,
                          const float* __restrict__ w_rbf2, const char* __restrict__ wdn_i,
                          float* __restrict__ W3, int E)
{
    __shared__ short slotA[8192], slotB[8192];
    __shared__ float t_lds[64 * TPITCH];
    __shared__ float w2_lds[8 * 128];
    const int tid = threadIdx.x, lane = tid & 63, wid = tid >> 6;
    const int acol = lane & 15, kq = lane >> 4;
    const int wr = wid >> 1, wc = wid & 1;
    const int cb1 = wc * 64;            // GEMM1 col base (N=128)
    const int cb2 = wc * 32;            // GEMM2 col base (N=64)
    const int row0 = blockIdx.x * 64 + wr * 32;

    stage16(wkj_i, slotA, lane, wid);

    f32x4 a[2][4][2];
    #pragma unroll
    for (int rf = 0; rf < 2; ++rf) {
        const int ar = row0 + rf * 16 + acol;
        const bool av = ar < E;
        const float* xr = x + (size_t)ar * 128;
        #pragma unroll
        for (int ks = 0; ks < 4; ++ks) {
            a[rf][ks][0] = f32x4{0.f, 0.f, 0.f, 0.f}; a[rf][ks][1] = f32x4{0.f, 0.f, 0.f, 0.f};
            if (av) { a[rf][ks][0] = *(const f32x4*)&xr[ks * 32 + kq * 8];
                      a[rf][ks][1] = *(const f32x4*)&xr[ks * 32 + kq * 8 + 4]; }
        }
    }
    float bv[4];
    #pragma unroll
    for (int n = 0; n < 4; ++n) bv[n] = b_kj[cb1 + n * 16 + acol];
    f32x4 e1a[2][4], e1b[2][4];
    #pragma unroll
    for (int rf = 0; rf < 2; ++rf)
        #pragma unroll
        for (int r = 0; r < 4; ++r) {
            const int ge = row0 + rf * 16 + kq * 4 + r;
            e1a[rf][r] = f32x4{0.f, 0.f, 0.f, 0.f}; e1b[rf][r] = f32x4{0.f, 0.f, 0.f, 0.f};
            if (ge < E) { e1a[rf][r] = *(const f32x4*)&re1[(size_t)ge * 8];
                          e1b[rf][r] = *(const f32x4*)&re1[(size_t)ge * 8 + 4]; }
        }
    for (int i = tid; i < 1024; i += 256) w2_lds[i] = w_rbf2[i];
    __syncthreads();

    f32x4 acc0[4], acc1[4];
    #pragma unroll
    for (int n = 0; n < 4; ++n) { acc0[n] = f32x4{0.f, 0.f, 0.f, 0.f}; acc1[n] = f32x4{0.f, 0.f, 0.f, 0.f}; }

    stage16(wkj_i + 16384, slotB, lane, wid);
    gphase_q<4>(a[0][0][0], a[0][0][1], a[1][0][0], a[1][0][1], slotA, cb1, acol, kq, acc0, acc1); __syncthreads();
    stage16(wkj_i + 32768, slotA, lane, wid);
    gphase_q<4>(a[0][1][0], a[0][1][1], a[1][1][0], a[1][1][1], slotB, cb1, acol, kq, acc0, acc1); __syncthreads();
    stage16(wkj_i + 49152, slotB, lane, wid);
    gphase_q<4>(a[0][2][0], a[0][2][1], a[1][2][0], a[1][2][1], slotA, cb1, acol, kq, acc0, acc1); __syncthreads();
    stage8(wdn_i, slotA, lane, wid);
    gphase_q<4>(a[0][3][0], a[0][3][1], a[1][3][0], a[1][3][1], slotB, cb1, acol, kq, acc0, acc1); __syncthreads();

    #pragma unroll
    for (int rf = 0; rf < 2; ++rf) {
        f32x4* acc = rf ? acc1 : acc0;
        #pragma unroll
        for (int n = 0; n < 4; ++n) {
            const int c = cb1 + n * 16 + acol;
            float w2c[8];
            #pragma unroll
            for (int p = 0; p < 8; ++p) w2c[p] = w2_lds[p * 128 + c];
            #pragma unroll
            for (int r = 0; r < 4; ++r) {
                float s = e1a[rf][r][0] * w2c[0];
                s = fmaf(e1a[rf][r][1], w2c[1], s);
                s = fmaf(e1a[rf][r][2], w2c[2], s);
                s = fmaf(e1a[rf][r][3], w2c[3], s);
                s = fmaf(e1b[rf][r][0], w2c[4], s);
                s = fmaf(e1b[rf][r][1], w2c[5], s);
                s = fmaf(e1b[rf][r][2], w2c[6], s);
                s = fmaf(e1b[rf][r][3], w2c[7], s);
                t_lds[(wr * 32 + rf * 16 + kq * 4 + r) * TPITCH + c] = silu_f(acc[n][r] + bv[n]) * s;
            }
        }
    }
    __syncthreads();

    f32x4 acc20[2], acc21[2];
    #pragma unroll
    for (int n = 0; n < 2; ++n) { acc20[n] = f32x4{0.f, 0.f, 0.f, 0.f}; acc21[n] = f32x4{0.f, 0.f, 0.f, 0.f}; }
    const int rb0 = (wr * 32 + acol) * TPITCH;
    const int rb1 = (wr * 32 + 16 + acol) * TPITCH;

    stage8(wdn_i + 8192, slotB, lane, wid);
    tphase_q<2>(t_lds, rb0, rb1, 0, cb2, kq, acol, slotA, acc20, acc21); __syncthreads();
    stage8(wdn_i + 16384, slotA, lane, wid);
    tphase_q<2>(t_lds, rb0, rb1, 1, cb2, kq, acol, slotB, acc20, acc21); __syncthreads();
    stage8(wdn_i + 24576, slotB, lane, wid);
    tphase_q<2>(t_lds, rb0, rb1, 2, cb2, kq, acol, slotA, acc20, acc21); __syncthreads();
    tphase_q<2>(t_lds, rb0, rb1, 3, cb2, kq, acol, slotB, acc20, acc21);

    #pragma unroll
    for (int rf = 0; rf < 2; ++rf) {
        f32x4* acc = rf ? acc21 : acc20;
        #pragma unroll
        for (int n = 0; n < 2; ++n) {
            const int c = cb2 + n * 16 + acol;
            #pragma unroll
            for (int r = 0; r < 4; ++r) {
                const int ge = row0 + rf * 16 + kq * 4 + r;
                if (ge < E) W3[(size_t)ge * 64 + c] = silu_f(acc[n][r]);
            }
        }
    }
}

// ---------------- kbig: h0 -> res1 -> w_bs+skip -> res2 -> res3 (9 GEMMs) ---
struct KBigArgs {
    const float* x; const float* W4; float* out;
    const char *wji, *wup, *r1w1, *r1w2, *wbs, *r2w1, *r2w2, *r3w1, *r3w2;
    const float *bji, *r1b1, *r1b2, *bbs, *r2b1, *r2b2, *r3b1, *r3b2;
    int E;
};

__launch_bounds__(256, 2)
__global__ void kbig_kernel(KBigArgs A_)
{
    __shared__ short slotA[8192], slotB[8192];
    __shared__ float t_lds[64 * TPITCH];
    const int tid = threadIdx.x, lane = tid & 63, wid = tid >> 6;
    const int acol = lane & 15, kq = lane >> 4;
    const int wr = wid >> 1, wc = wid & 1;
    const int cb = wc * 64;
    const int row0 = blockIdx.x * 64 + wr * 32;
    const int E = A_.E;
    const int rb0 = (wr * 32 + acol) * TPITCH;
    const int rb1 = (wr * 32 + 16 + acol) * TPITCH;

    stage16(A_.wji, slotA, lane, wid);

    f32x4 a[2][4][2], u[2][2][2];
    #pragma unroll
    for (int rf = 0; rf < 2; ++rf) {
        const int ar = row0 + rf * 16 + acol;
        const bool av = ar < E;
        const float* xr = A_.x + (size_t)ar * 128;
        const float* wr4 = A_.W4 + (size_t)ar * 64;
        #pragma unroll
        for (int ks = 0; ks < 4; ++ks) {
            a[rf][ks][0] = f32x4{0.f, 0.f, 0.f, 0.f}; a[rf][ks][1] = f32x4{0.f, 0.f, 0.f, 0.f};
            if (av) { a[rf][ks][0] = *(const f32x4*)&xr[ks * 32 + kq * 8];
                      a[rf][ks][1] = *(const f32x4*)&xr[ks * 32 + kq * 8 + 4]; }
        }
        #pragma unroll
        for (int ks = 0; ks < 2; ++ks) {
            u[rf][ks][0] = f32x4{0.f, 0.f, 0.f, 0.f}; u[rf][ks][1] = f32x4{0.f, 0.f, 0.f, 0.f};
            if (av) { u[rf][ks][0] = *(const f32x4*)&wr4[ks * 32 + kq * 8];
                      u[rf][ks][1] = *(const f32x4*)&wr4[ks * 32 + kq * 8 + 4]; }
        }
    }
    __syncthreads();

    f32x4 acc0[4], acc1[4];
    #pragma unroll
    for (int n = 0; n < 4; ++n) { acc0[n] = f32x4{0.f, 0.f, 0.f, 0.f}; acc1[n] = f32x4{0.f, 0.f, 0.f, 0.f}; }

    // GEMM1: x @ w_ji
    stage16(A_.wji + 16384, slotB, lane, wid);
    gphase_q<4>(a[0][0][0], a[0][0][1], a[1][0][0], a[1][0][1], slotA, cb, acol, kq, acc0, acc1); __syncthreads();
    stage16(A_.wji + 32768, slotA, lane, wid);
    gphase_q<4>(a[0][1][0], a[0][1][1], a[1][1][0], a[1][1][1], slotB, cb, acol, kq, acc0, acc1); __syncthreads();
    stage16(A_.wji + 49152, slotB, lane, wid);
    gphase_q<4>(a[0][2][0], a[0][2][1], a[1][2][0], a[1][2][1], slotA, cb, acol, kq, acc0, acc1); __syncthreads();
    stage16(A_.wup, slotA, lane, wid);
    gphase_q<4>(a[0][3][0], a[0][3][1], a[1][3][0], a[1][3][1], slotB, cb, acol, kq, acc0, acc1); __syncthreads();

    float res[2][4][4];
    #pragma unroll
    for (int rf = 0; rf < 2; ++rf) {
        f32x4* acc = rf ? acc1 : acc0;
        #pragma unroll
        for (int n = 0; n < 4; ++n) {
            const float bvv = A_.bji[cb + n * 16 + acol];
            #pragma unroll
            for (int r = 0; r < 4; ++r) { res[rf][n][r] = silu_f(acc[n][r] + bvv); acc[n][r] = 0.f; }
        }
    }

    // GEMM2: W4 @ w_up (K=64)
    stage16(A_.wup + 16384, slotB, lane, wid);
    gphase_q<4>(u[0][0][0], u[0][0][1], u[1][0][0], u[1][0][1], slotA, cb, acol, kq, acc0, acc1); __syncthreads();
    stage16(A_.r1w1, slotA, lane, wid);
    gphase_q<4>(u[0][1][0], u[0][1][1], u[1][1][0], u[1][1][1], slotB, cb, acol, kq, acc0, acc1); __syncthreads();

    #pragma unroll
    for (int rf = 0; rf < 2; ++rf) {
        f32x4* acc = rf ? acc1 : acc0;
        #pragma unroll
        for (int n = 0; n < 4; ++n) {
            const int c = cb + n * 16 + acol;
            #pragma unroll
            for (int r = 0; r < 4; ++r) {
                res[rf][n][r] += silu_f(acc[n][r]);             // h0
                t_lds[(wr * 32 + rf * 16 + kq * 4 + r) * TPITCH + c] = res[rf][n][r];
                acc[n][r] = 0.f;
            }
        }
    }
    __syncthreads();

    // GEMM3: h0 @ r1w1 -> t1
    tgemm4q(A_.r1w1, A_.r1w2, slotA, slotB, t_lds, rb0, rb1, cb, kq, acol, lane, wid, acc0, acc1);
    #pragma unroll
    for (int rf = 0; rf < 2; ++rf) {
        f32x4* acc = rf ? acc1 : acc0;
        #pragma unroll
        for (int n = 0; n < 4; ++n) {
            const float bvv = A_.r1b1[cb + n * 16 + acol];
            const int c = cb + n * 16 + acol;
            #pragma unroll
            for (int r = 0; r < 4; ++r) {
                t_lds[(wr * 32 + rf * 16 + kq * 4 + r) * TPITCH + c] = silu_f(acc[n][r] + bvv);
                acc[n][r] = 0.f;
            }
        }
    }
    __syncthreads();

    // GEMM4: t1 @ r1w2 -> t2 = h0 + silu(.)
    tgemm4q(A_.r1w2, A_.wbs, slotA, slotB, t_lds, rb0, rb1, cb, kq, acol, lane, wid, acc0, acc1);
    #pragma unroll
    for (int rf = 0; rf < 2; ++rf) {
        f32x4* acc = rf ? acc1 : acc0;
        #pragma unroll
        for (int n = 0; n < 4; ++n) {
            const float bvv = A_.r1b2[cb + n * 16 + acol];
            const int c = cb + n * 16 + acol;
            #pragma unroll
            for (int r = 0; r < 4; ++r) {
                t_lds[(wr * 32 + rf * 16 + kq * 4 + r) * TPITCH + c] = res[rf][n][r] + silu_f(acc[n][r] + bvv);
                acc[n][r] = 0.f;
            }
        }
    }
    __syncthreads();

    // GEMM5: t2 @ w_bs -> h2 = silu(.) + x
    tgemm4q(A_.wbs, A_.r2w1, slotA, slotB, t_lds, rb0, rb1, cb, kq, acol, lane, wid, acc0, acc1);
    #pragma unroll
    for (int rf = 0; rf < 2; ++rf) {
        f32x4* acc = rf ? acc1 : acc0;
        #pragma unroll
        for (int n = 0; n < 4; ++n) {
            const float bvv = A_.bbs[cb + n * 16 + acol];
            const int c = cb + n * 16 + acol;
            #pragma unroll
            for (int r = 0; r < 4; ++r) {
                const int ge = row0 + rf * 16 + kq * 4 + r;
                const float xv = (ge < E) ? A_.x[(size_t)ge * 128 + c] : 0.f;
                res[rf][n][r] = silu_f(acc[n][r] + bvv) + xv;   // h2
                t_lds[(wr * 32 + rf * 16 + kq * 4 + r) * TPITCH + c] = res[rf][n][r];
                acc[n][r] = 0.f;
            }
        }
    }
    __syncthreads();

    // GEMM6: h2 @ r2w1 -> t3
    tgemm4q(A_.r2w1, A_.r2w2, slotA, slotB, t_lds, rb0, rb1, cb, kq, acol, lane, wid, acc0, acc1);
    #pragma unroll
    for (int rf = 0; rf < 2; ++rf) {
        f32x4* acc = rf ? acc1 : acc0;
        #pragma unroll
        for (int n = 0; n < 4; ++n) {
            const float bvv = A_.r2b1[cb + n * 16 + acol];
            const int c = cb + n * 16 + acol;
            #pragma unroll
            for (int r = 0; r < 4; ++r) {
                t_lds[(wr * 32 + rf * 16 + kq * 4 + r) * TPITCH + c] = silu_f(acc[n][r] + bvv);
                acc[n][r] = 0.f;
            }
        }
    }
    __syncthreads();

    // GEMM7: t3 @ r2w2 -> h3 = h2 + silu(.)
    tgemm4q(A_.r2w2, A_.r3w1, slotA, slotB, t_lds, rb0, rb1, cb, kq, acol, lane, wid, acc0, acc1);
    #pragma unroll
    for (int rf = 0; rf < 2; ++rf) {
        f32x4* acc = rf ? acc1 : acc0;
        #pragma unroll
        for (int n = 0; n < 4; ++n) {
            const float bvv = A_.r2b2[cb + n * 16 + acol];
            const int c = cb + n * 16 + acol;
            #pragma unroll
            for (int r = 0; r < 4; ++r) {
                res[rf][n][r] += silu_f(acc[n][r] + bvv);       // h3
                t_lds[(wr * 32 + rf * 16 + kq * 4 + r) * TPITCH + c] = res[rf][n][r];
                acc[n][r] = 0.f;
            }
        }
    }
    __syncthreads();

    // GEMM8: h3 @ r3w1 -> t4
    tgemm4q(A_.r3w1, A_.r3w2, slotA, slotB, t_lds, rb0, rb1, cb, kq, acol, lane, wid, acc0, acc1);
    #pragma unroll
    for (int rf = 0; rf < 2; ++rf) {
        f32x4* acc = rf ? acc1 : acc0;
        #pragma unroll
        for (int n = 0; n < 4; ++n) {
            const float bvv = A_.r3b1[cb + n * 16 + acol];
            const int c = cb + n * 16 + acol;
            #pragma unroll
            for (int r = 0; r < 4; ++r) {
                t_lds[(wr * 32 + rf * 16 + kq * 4 + r) * TPITCH + c] = silu_f(acc[n][r] + bvv);
                acc[n][r] = 0.f;
            }
        }
    }
    __syncthreads();

    // GEMM9: t4 @ r3w2 -> out = h3 + silu(.)
    tgemm4q(A_.r3w2, nullptr, slotA, slotB, t_lds, rb0, rb1, cb, kq, acol, lane, wid, acc0, acc1);
    #pragma unroll
    for (int rf = 0; rf < 2; ++rf) {
        f32x4* acc = rf ? acc1 : acc0;
        #pragma unroll
        for (int n = 0; n < 4; ++n) {
            const float bvv = A_.r3b2[cb + n * 16 + acol];
            const int c = cb + n * 16 + acol;
            #pragma unroll
            for (int r = 0; r < 4; ++r) {
                const int ge = row0 + rf * 16 + kq * 4 + r;
                if (ge < E)
                    A_.out[(size_t)ge * 128 + c] = res[rf][n][r] + silu_f(acc[n][r] + bvv);
            }
        }
    }
}

// ---------------------------------------------------------------------------

extern "C" void kernel_launch(void* const* d_in, const int* in_sizes, int n_in,
                              void* d_out, int out_size, void* d_ws, size_t ws_size,
                              hipStream_t stream)
{
    const float* x      = (const float*)d_in[0];
    const float* rbf    = (const float*)d_in[1];
    const float* sbf    = (const float*)d_in[2];
    const int*   idx_kj = (const int*)d_in[3];
    const int*   idx_ji = (const int*)d_in[4];
    const float* w_rbf1 = (const float*)d_in[5];
    const float* w_rbf2 = (const float*)d_in[6];
    const float* w_sbf1 = (const float*)d_in[7];
    const float* w_sbf2 = (const float*)d_in[8];
    const float* w_kj   = (const float*)d_in[9];
    const float* b_kj   = (const float*)d_in[10];
    const float* w_ji   = (const float*)d_in[11];
    const float* b_ji   = (const float*)d_in[12];
    const float* w_down = (const float*)d_in[13];
    const float* w_up   = (const float*)d_in[14];
    const float* r1w1   = (const float*)d_in[15];
    const float* r1b1   = (const float*)d_in[16];
    const float* r1w2   = (const float*)d_in[17];
    const float* r1b2   = (const float*)d_in[18];
    const float* w_bs   = (const float*)d_in[19];
    const float* b_bs   = (const float*)d_in[20];
    const float* r2w1   = (const float*)d_in[21];
    const float* r2b1   = (const float*)d_in[22];
    const float* r2w2   = (const float*)d_in[23];
    const float* r2b2   = (const float*)d_in[24];
    const float* r3w1   = (const float*)d_in[25];
    const float* r3b1   = (const float*)d_in[26];
    const float* r3w2   = (const float*)d_in[27];
    const float* r3b2   = (const float*)d_in[28];

    const int E = in_sizes[0] / 128;
    const int T = in_sizes[2] / 42;

    float* OUT = (float*)d_out;
    float* W3  = (float*)((char*)d_ws + (size_t)E * 128 * 4);         // [E,64]
    float* W4  = (float*)((char*)d_ws + (size_t)E * 128 * 4
                                      + (size_t)E * 64 * 4);          // [E,64]

    int*   cnt      = (int*)d_ws;                            // [E]
    int*   offsets  = cnt + (E + 64);                        // [E+1]
    int*   partial  = offsets + (E + 64);                    // [<=1024]
    int*   blockoff = partial + 1024;                        // [<=1024]
    float* E1p      = (float*)((char*)d_ws + (4u << 20));    // [T,8]   96 MB
    int*   kjp      = (int*)((char*)d_ws + (102u << 20));    // [T]     12 MB
    float* re1      = (float*)((char*)d_ws + (116u << 20));  // [E,8]  9.6 MB
    char*  wimg     = (char*)d_ws + (130u << 20);            // 640 KB
    int*   rank     = (int*)((char*)d_ws + (134u << 20));    // [T]     12 MB

    char* wkj_i  = wimg;
    char* wji_i  = wimg + 65536;
    char* wdn_i  = wimg + 131072;
    char* wup_i  = wimg + 163840;
    char* r1w1_i = wimg + 196608;
    char* r1w2_i = wimg + 262144;
    char* wbs_i  = wimg + 327680;
    char* r2w1_i = wimg + 393216;
    char* r2w2_i = wimg + 458752;
    char* r3w1_i = wimg + 524288;
    char* r3w2_i = wimg + 589824;

    WPrepArgs pa;
    pa.w[0]  = {w_kj,   wkj_i,  128, 128};
    pa.w[1]  = {w_ji,   wji_i,  128, 128};
    pa.w[2]  = {w_down, wdn_i,  128,  64};
    pa.w[3]  = {w_up,   wup_i,   64, 128};
    pa.w[4]  = {r1w1,   r1w1_i, 128, 128};
    pa.w[5]  = {r1w2,   r1w2_i, 128, 128};
    pa.w[6]  = {w_bs,   wbs_i,  128, 128};
    pa.w[7]  = {r2w1,   r2w1_i, 128, 128};
    pa.w[8]  = {r2w2,   r2w2_i, 128, 128};
    pa.w[9]  = {r3w1,   r3w1_i, 128, 128};
    pa.w[10] = {r3w2,   r3w2_i, 128, 128};

    const dim3 b256(256);
    const int gB  = (E + 63) / 64;
    const int gT  = (T + 255) / 256;
    const int gT4 = (T + 1023) / 1024;
    const int NB  = (E + 1023) / 1024;
    const int gE4 = (E + 3) / 4;
    const int gR  = (E * 8 + 255) / 256;

    wprep_kernel<<<dim3(4, 11), b256, 0, stream>>>(pa);
    rbf1_kernel<<<gR, b256, 0, stream>>>(rbf, w_rbf1, re1, E);
    hipMemsetAsync(cnt, 0, (size_t)E * 4, stream);
    count_rank_kernel<<<gT4, b256, 0, stream>>>(idx_ji, cnt, rank, T);
    scan_partial_kernel<<<NB, b256, 0, stream>>>(cnt, partial, E);
    scan_block_kernel<<<1, b256, 0, stream>>>(partial, blockoff, NB, offsets, E);
    scan_final_kernel<<<NB, b256, 0, stream>>>(cnt, blockoff, offsets, E);
    e1fill_kernel<<<gT, b256, 0, stream>>>(sbf, w_sbf1, idx_ji, idx_kj, rank, offsets, E1p, kjp, T);

    k1_kernel<<<gB, b256, 0, stream>>>(x, wkj_i, b_kj, re1, w_rbf2, wdn_i, W3, E);
    gather_kernel<<<gE4, b256, 0, stream>>>(E1p, kjp, w_sbf2, offsets, W3, W4, E);

    KBigArgs ka;
    ka.x = x; ka.W4 = W4; ka.out = OUT;
    ka.wji = wji_i; ka.wup = wup_i; ka.r1w1 = r1w1_i; ka.r1w2 = r1w2_i; ka.wbs = wbs_i;
    ka.r2w1 = r2w1_i; ka.r2w2 = r2w2_i; ka.r3w1 = r3w1_i; ka.r3w2 = r3w2_i;
    ka.bji = b_ji; ka.r1b1 = r1b1; ka.r1b2 = r1b2; ka.bbs = b_bs;
    ka.r2b1 = r2b1; ka.r2b2 = r2b2; ka.r3b1 = r3b1; ka.r3b2 = r3b2;
    ka.E = E;
    kbig_kernel<<<gB, b256, 0, stream>>>(ka);
}

// Round 12
// 1213.118 us; speedup vs baseline: 1.2023x; 1.0381x over previous
//
#include <hip/hip_runtime.h>
#include <hip/hip_bf16.h>

// ---------------------------------------------------------------------------
// DimeNet++ interaction block, round 12:
//   - k1 / kbig reverted EXACTLY to round 9 (proven best: kbig 493 us).
//     Rounds 10 (2-wave blocks) and 11 (quadrant split) both regressed:
//     the kernel is latency/barrier-bound, not LDS-traffic-bound.
//   - gather: software-pipeline the xkjd row gather itself (depth-1), not
//     just the indices -- the dependent L2/L3 gather was the loop's
//     critical path.
// ---------------------------------------------------------------------------

typedef __attribute__((ext_vector_type(8))) short bf16x8;
typedef __attribute__((ext_vector_type(4))) float f32x4;
typedef __attribute__((ext_vector_type(4))) unsigned int u32x4;

__device__ __forceinline__ float silu_f(float v) {
    return v * __builtin_amdgcn_rcpf(1.0f + __expf(-v));
}
__device__ __forceinline__ short f2bf(float f) {          // RNE (wprep only)
    unsigned u = __float_as_uint(f);
    unsigned r = u + 0x7fffu + ((u >> 16) & 1u);
    return (short)(r >> 16);
}
__device__ __forceinline__ float bf2f(short s) {
    return __uint_as_float(((unsigned)(unsigned short)s) << 16);
}

__device__ __forceinline__ unsigned cvt_pk_bf16(float a, float b) {
    __hip_bfloat162 h = __float22bfloat162_rn(float2{a, b});   // v_cvt_pk_bf16_f32
    return *reinterpret_cast<unsigned*>(&h);
}
// fp32x8 -> bf16 hi + lo residual, using packed cvt (RNE, bit-identical to f2bf)
__device__ __forceinline__ void split44(f32x4 a, f32x4 b, bf16x8& hi, bf16x8& lo) {
    float f[8] = {a[0], a[1], a[2], a[3], b[0], b[1], b[2], b[3]};
    u32x4 H, L;
    #pragma unroll
    for (int j = 0; j < 4; ++j) {
        const float f0 = f[2 * j], f1 = f[2 * j + 1];
        const unsigned h = cvt_pk_bf16(f0, f1);
        const float r0 = f0 - __uint_as_float(h << 16);
        const float r1 = f1 - __uint_as_float(h & 0xffff0000u);
        H[j] = h;
        L[j] = cvt_pk_bf16(r0, r1);
    }
    hi = __builtin_bit_cast(bf16x8, H);
    lo = __builtin_bit_cast(bf16x8, L);
}

__device__ __forceinline__ void gll16(const void* g, void* l) {
    __builtin_amdgcn_global_load_lds((const __attribute__((address_space(1))) void*)g,
                                     (__attribute__((address_space(3))) void*)l, 16, 0, 0);
}
__device__ __forceinline__ void stage16(const char* g, short* l, int lane, int wid) {
    #pragma unroll
    for (int i = 0; i < 4; ++i) {
        const int off = ((i * 4 + wid) << 10);
        gll16(g + off + lane * 16, (char*)l + off);
    }
}
__device__ __forceinline__ void stage8(const char* g, short* l, int lane, int wid) {
    #pragma unroll
    for (int i = 0; i < 2; ++i) {
        const int off = ((i * 4 + wid) << 10);
        gll16(g + off + lane * 16, (char*)l + off);
    }
}

template<int NF>
__device__ __forceinline__ void mfma_ks(bf16x8 ah, bf16x8 al, const short* slot,
                                        int acol, int kq, f32x4* acc) {
    #pragma unroll
    for (int n = 0; n < NF; ++n) {
        const int c = n * 16 + acol;
        const int x = (c >> 2) & 1;
        const int sw = (kq ^ (c & 3)) << 3;
        const bf16x8 bh = *(const bf16x8*)&slot[c * 64 + x * 32 + sw];
        const bf16x8 bl = *(const bf16x8*)&slot[c * 64 + (x ^ 1) * 32 + sw];
        acc[n] = __builtin_amdgcn_mfma_f32_16x16x32_bf16(ah, bh, acc[n], 0, 0, 0);
        acc[n] = __builtin_amdgcn_mfma_f32_16x16x32_bf16(al, bh, acc[n], 0, 0, 0);
        acc[n] = __builtin_amdgcn_mfma_f32_16x16x32_bf16(ah, bl, acc[n], 0, 0, 0);
    }
}
template<int NF>
__device__ __forceinline__ void gphase(f32x4 a0, f32x4 a1, const short* slot,
                                       int acol, int kq, f32x4* acc) {
    bf16x8 ah, al; split44(a0, a1, ah, al);
    mfma_ks<NF>(ah, al, slot, acol, kq, acc);
}
template<int NF>
__device__ __forceinline__ void tphase(const float* tl, int rowbase, int q,
                                       int kq, int acol, const short* slot, f32x4* acc) {
    const f32x4 ta = *(const f32x4*)&tl[rowbase + q * 32 + kq * 8];
    const f32x4 tb = *(const f32x4*)&tl[rowbase + q * 32 + kq * 8 + 4];
    bf16x8 ah, al; split44(ta, tb, ah, al);
    mfma_ks<NF>(ah, al, slot, acol, kq, acc);
}

__device__ __forceinline__ void tgemm4(const char* img, const char* imgnext,
                                       short* sA, short* sB, const float* tl, int rb,
                                       int kq, int acol, int lane, int wid, f32x4* acc)
{
    stage16(img + 16384, sB, lane, wid);
    tphase<8>(tl, rb, 0, kq, acol, sA, acc); __syncthreads();
    stage16(img + 32768, sA, lane, wid);
    tphase<8>(tl, rb, 1, kq, acol, sB, acc); __syncthreads();
    stage16(img + 49152, sB, lane, wid);
    tphase<8>(tl, rb, 2, kq, acol, sA, acc); __syncthreads();
    if (imgnext) stage16(imgnext, sA, lane, wid);
    tphase<8>(tl, rb, 3, kq, acol, sB, acc); __syncthreads();
}

#define TPITCH 132

// ---------------- weight pre-conversion -------------------------------------
struct WDesc { const float* src; char* dst; int K; int N; };
struct WPrepArgs { WDesc w[11]; };

__global__ void wprep_kernel(WPrepArgs args) {
    const WDesc d = args.w[blockIdx.y];
    const int h = blockIdx.x;
    if (h * 32 >= d.K) return;
    char* slab = d.dst + (size_t)h * d.N * 128;
    for (int idx = threadIdx.x; idx < d.N * 4; idx += 256) {
        const int c = idx >> 2, ch = idx & 3;
        bf16x8 hi, lo;
        #pragma unroll
        for (int j = 0; j < 8; ++j) {
            const float f = d.src[(size_t)(h * 32 + ch * 8 + j) * d.N + c];
            const short hb = f2bf(f);
            hi[j] = hb;
            lo[j] = f2bf(f - bf2f(hb));
        }
        const int x = (c >> 2) & 1;
        const int sw = (ch ^ (c & 3)) * 16;
        *(bf16x8*)(slab + c * 128 + x * 64 + sw)       = hi;
        *(bf16x8*)(slab + c * 128 + (x ^ 1) * 64 + sw) = lo;
    }
}

// ---------------- prologue / CSR --------------------------------------------

__global__ void rbf1_kernel(const float* __restrict__ rbf, const float* __restrict__ w_rbf1,
                            float* __restrict__ re1, int E) {
    const int i = blockIdx.x * 256 + threadIdx.x;
    const int e = i >> 3, p = i & 7;
    if (e < E) {
        float s = 0.f;
        #pragma unroll
        for (int q = 0; q < 6; ++q) s = fmaf(rbf[e * 6 + q], w_rbf1[q * 8 + p], s);
        re1[i] = s;
    }
}

__global__ void count_rank_kernel(const int* __restrict__ idx_ji, int* __restrict__ cnt,
                                  int* __restrict__ rank, int T) {
    const int i = (blockIdx.x * 256 + threadIdx.x) * 4;
    if (i + 3 < T) {
        const int4 j = *(const int4*)&idx_ji[i];
        int4 r;
        r.x = atomicAdd(&cnt[j.x], 1);
        r.y = atomicAdd(&cnt[j.y], 1);
        r.z = atomicAdd(&cnt[j.z], 1);
        r.w = atomicAdd(&cnt[j.w], 1);
        *(int4*)&rank[i] = r;
    } else {
        for (int k = i; k < T; ++k) rank[k] = atomicAdd(&cnt[idx_ji[k]], 1);
    }
}

__global__ void scan_partial_kernel(const int* __restrict__ cnt, int* __restrict__ partial, int E) {
    __shared__ int red[256];
    const int tid = threadIdx.x;
    const int base = blockIdx.x * 1024 + tid * 4;
    int s = 0;
    #pragma unroll
    for (int i = 0; i < 4; ++i) { const int g = base + i; if (g < E) s += cnt[g]; }
    red[tid] = s;
    __syncthreads();
    for (int off = 128; off > 0; off >>= 1) {
        if (tid < off) red[tid] += red[tid + off];
        __syncthreads();
    }
    if (tid == 0) partial[blockIdx.x] = red[0];
}

__global__ void scan_block_kernel(const int* __restrict__ partial, int* __restrict__ blockoff,
                                  int NB, int* offsets, int E) {
    __shared__ int red[256];
    const int tid = threadIdx.x;
    int v[4]; int s = 0;
    #pragma unroll
    for (int i = 0; i < 4; ++i) { const int g = tid * 4 + i; v[i] = (g < NB) ? partial[g] : 0; s += v[i]; }
    red[tid] = s;
    __syncthreads();
    for (int off = 1; off < 256; off <<= 1) {
        const int add = (tid >= off) ? red[tid - off] : 0;
        __syncthreads();
        red[tid] += add;
        __syncthreads();
    }
    int excl = (tid == 0) ? 0 : red[tid - 1];
    #pragma unroll
    for (int i = 0; i < 4; ++i) { const int g = tid * 4 + i; if (g < NB) blockoff[g] = excl; excl += v[i]; }
    if (tid == 255) offsets[E] = red[255];
}

__global__ void scan_final_kernel(const int* __restrict__ cnt, const int* __restrict__ blockoff,
                                  int* __restrict__ offsets, int E) {
    __shared__ int red[256];
    const int tid = threadIdx.x;
    const int base = blockIdx.x * 1024 + tid * 4;
    int v[4]; int s = 0;
    #pragma unroll
    for (int i = 0; i < 4; ++i) { const int g = base + i; v[i] = (g < E) ? cnt[g] : 0; s += v[i]; }
    red[tid] = s;
    __syncthreads();
    for (int off = 1; off < 256; off <<= 1) {
        const int add = (tid >= off) ? red[tid - off] : 0;
        __syncthreads();
        red[tid] += add;
        __syncthreads();
    }
    int run = blockoff[blockIdx.x] + ((tid == 0) ? 0 : red[tid - 1]);
    #pragma unroll
    for (int i = 0; i < 4; ++i) {
        const int g = base + i;
        if (g < E) offsets[g] = run;
        run += v[i];
    }
}

__launch_bounds__(256, 3)
__global__ void e1fill_kernel(const float* __restrict__ sbf, const float* __restrict__ w_sbf1,
                              const int* __restrict__ idx_ji, const int* __restrict__ idx_kj,
                              const int* __restrict__ rank, const int* __restrict__ offsets,
                              float* __restrict__ E1p, int* __restrict__ kjp, int T)
{
    __shared__ float s_lds[256 * 43];
    const int tid = threadIdx.x;
    const long long t0 = (long long)blockIdx.x * 256;
    const int nrow = min(256, (int)(T - t0));
    const int nel  = nrow * 42;
    const float* base = sbf + t0 * 42;

    for (int i = tid * 4; i + 3 < nel; i += 1024) {
        const float4 v = *(const float4*)&base[i];
        s_lds[(i + 0) + (i + 0) / 42] = v.x;
        s_lds[(i + 1) + (i + 1) / 42] = v.y;
        s_lds[(i + 2) + (i + 2) / 42] = v.z;
        s_lds[(i + 3) + (i + 3) / 42] = v.w;
    }
    const int tail0 = nel & ~3;
    if (tid < nel - tail0) { const int g = tail0 + tid; s_lds[g + g / 42] = base[g]; }
    __syncthreads();

    const int t = (int)t0 + tid;
    if (t >= T) return;
    const float* srow = &s_lds[tid * 43];
    float e1[8] = {0.f, 0.f, 0.f, 0.f, 0.f, 0.f, 0.f, 0.f};
    #pragma unroll
    for (int q = 0; q < 42; ++q) {
        const float s = srow[q];
        #pragma unroll
        for (int p = 0; p < 8; ++p) e1[p] = fmaf(s, w_sbf1[q * 8 + p], e1[p]);
    }
    const int ji  = idx_ji[t];
    const int pos = offsets[ji] + rank[t];
    *(float4*)&E1p[(size_t)pos * 8]     = *(float4*)&e1[0];
    *(float4*)&E1p[(size_t)pos * 8 + 4] = *(float4*)&e1[4];
    kjp[pos] = idx_kj[t];
}

// ---------------- gather: depth-1 pipeline incl. the xkjd row gather --------
__launch_bounds__(256, 4)
__global__ void gather_kernel(const float* __restrict__ E1p, const int* __restrict__ kjp,
                              const float* __restrict__ w_sbf2, const int* __restrict__ offsets,
                              const float* __restrict__ xkjd, float* __restrict__ agg, int E)
{
    const int tid  = threadIdx.x;
    const int lane = tid & 63;
    const int e    = blockIdx.x * 4 + (tid >> 6);

    float w2[8];
    #pragma unroll
    for (int p = 0; p < 8; ++p) w2[p] = w_sbf2[p * 64 + lane];

    if (e >= E) return;
    const int j0 = __builtin_amdgcn_readfirstlane(offsets[e]);
    const int j1 = __builtin_amdgcn_readfirstlane(offsets[e + 1]);

    float acc = 0.f;
    if (j0 < j1) {
        int kj = __builtin_amdgcn_readfirstlane(kjp[j0]);
        float4 ea = *(const float4*)&E1p[(size_t)j0 * 8];
        float4 eb = *(const float4*)&E1p[(size_t)j0 * 8 + 4];
        float xv = xkjd[(size_t)kj * 64 + lane];          // value prefetched too
        for (int j = j0; j < j1; ++j) {
            float xn = 0.f; float4 ean = {}, ebn = {};
            if (j + 1 < j1) {                              // prefetch next triplet
                const int kn = __builtin_amdgcn_readfirstlane(kjp[j + 1]);
                ean = *(const float4*)&E1p[(size_t)(j + 1) * 8];
                ebn = *(const float4*)&E1p[(size_t)(j + 1) * 8 + 4];
                xn  = xkjd[(size_t)kn * 64 + lane];
            }
            float sv = ea.x * w2[0];
            sv = fmaf(ea.y, w2[1], sv);
            sv = fmaf(ea.z, w2[2], sv);
            sv = fmaf(ea.w, w2[3], sv);
            sv = fmaf(eb.x, w2[4], sv);
            sv = fmaf(eb.y, w2[5], sv);
            sv = fmaf(eb.z, w2[6], sv);
            sv = fmaf(eb.w, w2[7], sv);
            acc = fmaf(xv, sv, acc);
            ea = ean; eb = ebn; xv = xn;
        }
    }
    agg[(size_t)e * 64 + lane] = acc;
}

// ---------------- K1: W3 = silu((silu(x@w_kj+b)*rbf_e)@w_down) --------------
__launch_bounds__(256, 2)
__global__ void k1_kernel(const float* __restrict__ x, const char* __restrict__ wkj_i,
                          const float* __restrict__ b_kj, const float* __restrict__ re1,
                          const float* __restrict__ w_rbf2, const char* __restrict__ wdn_i,
                          float* __restrict__ W3, int E)
{
    __shared__ short slotA[8192], slotB[8192];
    __shared__ float t_lds[64 * TPITCH];
    __shared__ float w2_lds[8 * 128];
    const int tid = threadIdx.x, lane = tid & 63, wid = tid >> 6;
    const int acol = lane & 15, kq = lane >> 4;
    const int rowW = blockIdx.x * 64 + wid * 16;
    const int arow = rowW + acol;
    const bool av = arow < E;

    stage16(wkj_i, slotA, lane, wid);
    const float* xr = x + (size_t)arow * 128;
    f32x4 a[4][2];
    #pragma unroll
    for (int ks = 0; ks < 4; ++ks) {
        a[ks][0] = f32x4{0.f, 0.f, 0.f, 0.f}; a[ks][1] = f32x4{0.f, 0.f, 0.f, 0.f};
        if (av) { a[ks][0] = *(const f32x4*)&xr[ks * 32 + kq * 8];
                  a[ks][1] = *(const f32x4*)&xr[ks * 32 + kq * 8 + 4]; }
    }
    float bv[8];
    #pragma unroll
    for (int n = 0; n < 8; ++n) bv[n] = b_kj[n * 16 + acol];
    f32x4 e1a[4], e1b[4];
    #pragma unroll
    for (int r = 0; r < 4; ++r) {
        const int ge = rowW + kq * 4 + r;
        e1a[r] = f32x4{0.f, 0.f, 0.f, 0.f}; e1b[r] = f32x4{0.f, 0.f, 0.f, 0.f};
        if (ge < E) { e1a[r] = *(const f32x4*)&re1[(size_t)ge * 8];
                      e1b[r] = *(const f32x4*)&re1[(size_t)ge * 8 + 4]; }
    }
    for (int i = tid; i < 1024; i += 256) w2_lds[i] = w_rbf2[i];
    __syncthreads();

    f32x4 acc[8];
    #pragma unroll
    for (int n = 0; n < 8; ++n) acc[n] = f32x4{0.f, 0.f, 0.f, 0.f};

    stage16(wkj_i + 16384, slotB, lane, wid);
    gphase<8>(a[0][0], a[0][1], slotA, acol, kq, acc); __syncthreads();
    stage16(wkj_i + 32768, slotA, lane, wid);
    gphase<8>(a[1][0], a[1][1], slotB, acol, kq, acc); __syncthreads();
    stage16(wkj_i + 49152, slotB, lane, wid);
    gphase<8>(a[2][0], a[2][1], slotA, acol, kq, acc); __syncthreads();
    stage8(wdn_i, slotA, lane, wid);
    gphase<8>(a[3][0], a[3][1], slotB, acol, kq, acc); __syncthreads();

    #pragma unroll
    for (int n = 0; n < 8; ++n) {
        const int c = n * 16 + acol;
        float w2c[8];
        #pragma unroll
        for (int p = 0; p < 8; ++p) w2c[p] = w2_lds[p * 128 + c];
        #pragma unroll
        for (int r = 0; r < 4; ++r) {
            float s = e1a[r][0] * w2c[0];
            s = fmaf(e1a[r][1], w2c[1], s);
            s = fmaf(e1a[r][2], w2c[2], s);
            s = fmaf(e1a[r][3], w2c[3], s);
            s = fmaf(e1b[r][0], w2c[4], s);
            s = fmaf(e1b[r][1], w2c[5], s);
            s = fmaf(e1b[r][2], w2c[6], s);
            s = fmaf(e1b[r][3], w2c[7], s);
            t_lds[(wid * 16 + kq * 4 + r) * TPITCH + c] = silu_f(acc[n][r] + bv[n]) * s;
        }
    }
    __syncthreads();

    f32x4 acc2[4];
    #pragma unroll
    for (int n = 0; n < 4; ++n) acc2[n] = f32x4{0.f, 0.f, 0.f, 0.f};
    const int rb = (wid * 16 + acol) * TPITCH;

    stage8(wdn_i + 8192, slotB, lane, wid);
    tphase<4>(t_lds, rb, 0, kq, acol, slotA, acc2); __syncthreads();
    stage8(wdn_i + 16384, slotA, lane, wid);
    tphase<4>(t_lds, rb, 1, kq, acol, slotB, acc2); __syncthreads();
    stage8(wdn_i + 24576, slotB, lane, wid);
    tphase<4>(t_lds, rb, 2, kq, acol, slotA, acc2); __syncthreads();
    tphase<4>(t_lds, rb, 3, kq, acol, slotB, acc2);

    #pragma unroll
    for (int n = 0; n < 4; ++n) {
        const int c = n * 16 + acol;
        #pragma unroll
        for (int r = 0; r < 4; ++r) {
            const int ge = rowW + kq * 4 + r;
            if (ge < E) W3[(size_t)ge * 64 + c] = silu_f(acc2[n][r]);
        }
    }
}

// ---------------- kbig: h0 -> res1 -> w_bs+skip -> res2 -> res3 (9 GEMMs) ---
struct KBigArgs {
    const float* x; const float* W4; float* out;
    const char *wji, *wup, *r1w1, *r1w2, *wbs, *r2w1, *r2w2, *r3w1, *r3w2;
    const float *bji, *r1b1, *r1b2, *bbs, *r2b1, *r2b2, *r3b1, *r3b2;
    int E;
};

__launch_bounds__(256, 2)
__global__ void kbig_kernel(KBigArgs A_)
{
    __shared__ short slotA[8192], slotB[8192];
    __shared__ float t_lds[64 * TPITCH];
    const int tid = threadIdx.x, lane = tid & 63, wid = tid >> 6;
    const int acol = lane & 15, kq = lane >> 4;
    const int rowW = blockIdx.x * 64 + wid * 16;
    const int arow = rowW + acol;
    const int E = A_.E;
    const bool av = arow < E;
    const int rb = (wid * 16 + acol) * TPITCH;

    stage16(A_.wji, slotA, lane, wid);

    const float* xr = A_.x + (size_t)arow * 128;
    const float* wr = A_.W4 + (size_t)arow * 64;
    f32x4 a[4][2], u[2][2];
    #pragma unroll
    for (int ks = 0; ks < 4; ++ks) {
        a[ks][0] = f32x4{0.f, 0.f, 0.f, 0.f}; a[ks][1] = f32x4{0.f, 0.f, 0.f, 0.f};
        if (av) { a[ks][0] = *(const f32x4*)&xr[ks * 32 + kq * 8];
                  a[ks][1] = *(const f32x4*)&xr[ks * 32 + kq * 8 + 4]; }
    }
    #pragma unroll
    for (int ks = 0; ks < 2; ++ks) {
        u[ks][0] = f32x4{0.f, 0.f, 0.f, 0.f}; u[ks][1] = f32x4{0.f, 0.f, 0.f, 0.f};
        if (av) { u[ks][0] = *(const f32x4*)&wr[ks * 32 + kq * 8];
                  u[ks][1] = *(const f32x4*)&wr[ks * 32 + kq * 8 + 4]; }
    }
    __syncthreads();

    f32x4 acc[8];
    #pragma unroll
    for (int n = 0; n < 8; ++n) acc[n] = f32x4{0.f, 0.f, 0.f, 0.f};

    // GEMM1: x @ w_ji
    stage16(A_.wji + 16384, slotB, lane, wid);
    gphase<8>(a[0][0], a[0][1], slotA, acol, kq, acc); __syncthreads();
    stage16(A_.wji + 32768, slotA, lane, wid);
    gphase<8>(a[1][0], a[1][1], slotB, acol, kq, acc); __syncthreads();
    stage16(A_.wji + 49152, slotB, lane, wid);
    gphase<8>(a[2][0], a[2][1], slotA, acol, kq, acc); __syncthreads();
    stage16(A_.wup, slotA, lane, wid);
    gphase<8>(a[3][0], a[3][1], slotB, acol, kq, acc); __syncthreads();

    float res[8][4];
    #pragma unroll
    for (int n = 0; n < 8; ++n) {
        const float bv = A_.bji[n * 16 + acol];
        #pragma unroll
        for (int r = 0; r < 4; ++r) { res[n][r] = silu_f(acc[n][r] + bv); acc[n][r] = 0.f; }
    }

    // GEMM2: W4 @ w_up (K=64)
    stage16(A_.wup + 16384, slotB, lane, wid);
    gphase<8>(u[0][0], u[0][1], slotA, acol, kq, acc); __syncthreads();
    stage16(A_.r1w1, slotA, lane, wid);
    gphase<8>(u[1][0], u[1][1], slotB, acol, kq, acc); __syncthreads();

    #pragma unroll
    for (int n = 0; n < 8; ++n) {
        const int c = n * 16 + acol;
        #pragma unroll
        for (int r = 0; r < 4; ++r) {
            res[n][r] += silu_f(acc[n][r]);                     // h0
            t_lds[(wid * 16 + kq * 4 + r) * TPITCH + c] = res[n][r];
            acc[n][r] = 0.f;
        }
    }
    __syncthreads();

    // GEMM3: h0 @ r1w1 -> t1
    tgemm4(A_.r1w1, A_.r1w2, slotA, slotB, t_lds, rb, kq, acol, lane, wid, acc);
    #pragma unroll
    for (int n = 0; n < 8; ++n) {
        const float bv = A_.r1b1[n * 16 + acol];
        const int c = n * 16 + acol;
        #pragma unroll
        for (int r = 0; r < 4; ++r) {
            t_lds[(wid * 16 + kq * 4 + r) * TPITCH + c] = silu_f(acc[n][r] + bv);
            acc[n][r] = 0.f;
        }
    }
    __syncthreads();

    // GEMM4: t1 @ r1w2 -> t2 = h0 + silu(.)
    tgemm4(A_.r1w2, A_.wbs, slotA, slotB, t_lds, rb, kq, acol, lane, wid, acc);
    #pragma unroll
    for (int n = 0; n < 8; ++n) {
        const float bv = A_.r1b2[n * 16 + acol];
        const int c = n * 16 + acol;
        #pragma unroll
        for (int r = 0; r < 4; ++r) {
            t_lds[(wid * 16 + kq * 4 + r) * TPITCH + c] = res[n][r] + silu_f(acc[n][r] + bv);
            acc[n][r] = 0.f;
        }
    }
    __syncthreads();

    // GEMM5: t2 @ w_bs -> h2 = silu(.) + x
    tgemm4(A_.wbs, A_.r2w1, slotA, slotB, t_lds, rb, kq, acol, lane, wid, acc);
    #pragma unroll
    for (int n = 0; n < 8; ++n) {
        const float bv = A_.bbs[n * 16 + acol];
        const int c = n * 16 + acol;
        #pragma unroll
        for (int r = 0; r < 4; ++r) {
            const int ge = rowW + kq * 4 + r;
            const float xv = (ge < E) ? A_.x[(size_t)ge * 128 + c] : 0.f;
            res[n][r] = silu_f(acc[n][r] + bv) + xv;            // h2
            t_lds[(wid * 16 + kq * 4 + r) * TPITCH + c] = res[n][r];
            acc[n][r] = 0.f;
        }
    }
    __syncthreads();

    // GEMM6: h2 @ r2w1 -> t3
    tgemm4(A_.r2w1, A_.r2w2, slotA, slotB, t_lds, rb, kq, acol, lane, wid, acc);
    #pragma unroll
    for (int n = 0; n < 8; ++n) {
        const float bv = A_.r2b1[n * 16 + acol];
        const int c = n * 16 + acol;
        #pragma unroll
        for (int r = 0; r < 4; ++r) {
            t_lds[(wid * 16 + kq * 4 + r) * TPITCH + c] = silu_f(acc[n][r] + bv);
            acc[n][r] = 0.f;
        }
    }
    __syncthreads();

    // GEMM7: t3 @ r2w2 -> h3 = h2 + silu(.)
    tgemm4(A_.r2w2, A_.r3w1, slotA, slotB, t_lds, rb, kq, acol, lane, wid, acc);
    #pragma unroll
    for (int n = 0; n < 8; ++n) {
        const float bv = A_.r2b2[n * 16 + acol];
        const int c = n * 16 + acol;
        #pragma unroll
        for (int r = 0; r < 4; ++r) {
            res[n][r] += silu_f(acc[n][r] + bv);                // h3
            t_lds[(wid * 16 + kq * 4 + r) * TPITCH + c] = res[n][r];
            acc[n][r] = 0.f;
        }
    }
    __syncthreads();

    // GEMM8: h3 @ r3w1 -> t4
    tgemm4(A_.r3w1, A_.r3w2, slotA, slotB, t_lds, rb, kq, acol, lane, wid, acc);
    #pragma unroll
    for (int n = 0; n < 8; ++n) {
        const float bv = A_.r3b1[n * 16 + acol];
        const int c = n * 16 + acol;
        #pragma unroll
        for (int r = 0; r < 4; ++r) {
            t_lds[(wid * 16 + kq * 4 + r) * TPITCH + c] = silu_f(acc[n][r] + bv);
            acc[n][r] = 0.f;
        }
    }
    __syncthreads();

    // GEMM9: t4 @ r3w2 -> out = h3 + silu(.)
    tgemm4(A_.r3w2, nullptr, slotA, slotB, t_lds, rb, kq, acol, lane, wid, acc);
    #pragma unroll
    for (int n = 0; n < 8; ++n) {
        const float bv = A_.r3b2[n * 16 + acol];
        const int c = n * 16 + acol;
        #pragma unroll
        for (int r = 0; r < 4; ++r) {
            const int ge = rowW + kq * 4 + r;
            if (ge < E)
                A_.out[(size_t)ge * 128 + c] = res[n][r] + silu_f(acc[n][r] + bv);
        }
    }
}

// ---------------------------------------------------------------------------

extern "C" void kernel_launch(void* const* d_in, const int* in_sizes, int n_in,
                              void* d_out, int out_size, void* d_ws, size_t ws_size,
                              hipStream_t stream)
{
    const float* x      = (const float*)d_in[0];
    const float* rbf    = (const float*)d_in[1];
    const float* sbf    = (const float*)d_in[2];
    const int*   idx_kj = (const int*)d_in[3];
    const int*   idx_ji = (const int*)d_in[4];
    const float* w_rbf1 = (const float*)d_in[5];
    const float* w_rbf2 = (const float*)d_in[6];
    const float* w_sbf1 = (const float*)d_in[7];
    const float* w_sbf2 = (const float*)d_in[8];
    const float* w_kj   = (const float*)d_in[9];
    const float* b_kj   = (const float*)d_in[10];
    const float* w_ji   = (const float*)d_in[11];
    const float* b_ji   = (const float*)d_in[12];
    const float* w_down = (const float*)d_in[13];
    const float* w_up   = (const float*)d_in[14];
    const float* r1w1   = (const float*)d_in[15];
    const float* r1b1   = (const float*)d_in[16];
    const float* r1w2   = (const float*)d_in[17];
    const float* r1b2   = (const float*)d_in[18];
    const float* w_bs   = (const float*)d_in[19];
    const float* b_bs   = (const float*)d_in[20];
    const float* r2w1   = (const float*)d_in[21];
    const float* r2b1   = (const float*)d_in[22];
    const float* r2w2   = (const float*)d_in[23];
    const float* r2b2   = (const float*)d_in[24];
    const float* r3w1   = (const float*)d_in[25];
    const float* r3b1   = (const float*)d_in[26];
    const float* r3w2   = (const float*)d_in[27];
    const float* r3b2   = (const float*)d_in[28];

    const int E = in_sizes[0] / 128;
    const int T = in_sizes[2] / 42;

    float* OUT = (float*)d_out;
    float* W3  = (float*)((char*)d_ws + (size_t)E * 128 * 4);         // [E,64]
    float* W4  = (float*)((char*)d_ws + (size_t)E * 128 * 4
                                      + (size_t)E * 64 * 4);          // [E,64]

    int*   cnt      = (int*)d_ws;                            // [E]
    int*   offsets  = cnt + (E + 64);                        // [E+1]
    int*   partial  = offsets + (E + 64);                    // [<=1024]
    int*   blockoff = partial + 1024;                        // [<=1024]
    float* E1p      = (float*)((char*)d_ws + (4u << 20));    // [T,8]   96 MB
    int*   kjp      = (int*)((char*)d_ws + (102u << 20));    // [T]     12 MB
    float* re1      = (float*)((char*)d_ws + (116u << 20));  // [E,8]  9.6 MB
    char*  wimg     = (char*)d_ws + (130u << 20);            // 640 KB
    int*   rank     = (int*)((char*)d_ws + (134u << 20));    // [T]     12 MB

    char* wkj_i  = wimg;
    char* wji_i  = wimg + 65536;
    char* wdn_i  = wimg + 131072;
    char* wup_i  = wimg + 163840;
    char* r1w1_i = wimg + 196608;
    char* r1w2_i = wimg + 262144;
    char* wbs_i  = wimg + 327680;
    char* r2w1_i = wimg + 393216;
    char* r2w2_i = wimg + 458752;
    char* r3w1_i = wimg + 524288;
    char* r3w2_i = wimg + 589824;

    WPrepArgs pa;
    pa.w[0]  = {w_kj,   wkj_i,  128, 128};
    pa.w[1]  = {w_ji,   wji_i,  128, 128};
    pa.w[2]  = {w_down, wdn_i,  128,  64};
    pa.w[3]  = {w_up,   wup_i,   64, 128};
    pa.w[4]  = {r1w1,   r1w1_i, 128, 128};
    pa.w[5]  = {r1w2,   r1w2_i, 128, 128};
    pa.w[6]  = {w_bs,   wbs_i,  128, 128};
    pa.w[7]  = {r2w1,   r2w1_i, 128, 128};
    pa.w[8]  = {r2w2,   r2w2_i, 128, 128};
    pa.w[9]  = {r3w1,   r3w1_i, 128, 128};
    pa.w[10] = {r3w2,   r3w2_i, 128, 128};

    const dim3 b256(256);
    const int gB  = (E + 63) / 64;
    const int gT  = (T + 255) / 256;
    const int gT4 = (T + 1023) / 1024;
    const int NB  = (E + 1023) / 1024;
    const int gE4 = (E + 3) / 4;
    const int gR  = (E * 8 + 255) / 256;

    wprep_kernel<<<dim3(4, 11), b256, 0, stream>>>(pa);
    rbf1_kernel<<<gR, b256, 0, stream>>>(rbf, w_rbf1, re1, E);
    hipMemsetAsync(cnt, 0, (size_t)E * 4, stream);
    count_rank_kernel<<<gT4, b256, 0, stream>>>(idx_ji, cnt, rank, T);
    scan_partial_kernel<<<NB, b256, 0, stream>>>(cnt, partial, E);
    scan_block_kernel<<<1, b256, 0, stream>>>(partial, blockoff, NB, offsets, E);
    scan_final_kernel<<<NB, b256, 0, stream>>>(cnt, blockoff, offsets, E);
    e1fill_kernel<<<gT, b256, 0, stream>>>(sbf, w_sbf1, idx_ji, idx_kj, rank, offsets, E1p, kjp, T);

    k1_kernel<<<gB, b256, 0, stream>>>(x, wkj_i, b_kj, re1, w_rbf2, wdn_i, W3, E);
    gather_kernel<<<gE4, b256, 0, stream>>>(E1p, kjp, w_sbf2, offsets, W3, W4, E);

    KBigArgs ka;
    ka.x = x; ka.W4 = W4; ka.out = OUT;
    ka.wji = wji_i; ka.wup = wup_i; ka.r1w1 = r1w1_i; ka.r1w2 = r1w2_i; ka.wbs = wbs_i;
    ka.r2w1 = r2w1_i; ka.r2w2 = r2w2_i; ka.r3w1 = r3w1_i; ka.r3w2 = r3w2_i;
    ka.bji = b_ji; ka.r1b1 = r1b1; ka.r1b2 = r1b2; ka.bbs = b_bs;
    ka.r2b1 = r2b1; ka.r2b2 = r2b2; ka.r3b1 = r3b1; ka.r3b2 = r3b2;
    ka.E = E;
    kbig_kernel<<<gB, b256, 0, stream>>>(ka);
}

// Round 13
// 1200.565 us; speedup vs baseline: 1.2149x; 1.0105x over previous
//
#include <hip/hip_runtime.h>
#include <hip/hip_bf16.h>

// ---------------------------------------------------------------------------
// DimeNet++ interaction block, round 13:
//   Round-9 schedule (proven best) + critical-path hoisting:
//     - tgemm4: all 4 phases' t_lds reads + bf16 splits hoisted to right
//       after the t-publish barrier -> post-barrier phase body is pure MFMA
//     - global-loaded A/U fragments pre-split to bf16 once, not per phase
//   Everything else byte-identical to round 12.
// ---------------------------------------------------------------------------

typedef __attribute__((ext_vector_type(8))) short bf16x8;
typedef __attribute__((ext_vector_type(4))) float f32x4;
typedef __attribute__((ext_vector_type(4))) unsigned int u32x4;

__device__ __forceinline__ float silu_f(float v) {
    return v * __builtin_amdgcn_rcpf(1.0f + __expf(-v));
}
__device__ __forceinline__ short f2bf(float f) {          // RNE (wprep only)
    unsigned u = __float_as_uint(f);
    unsigned r = u + 0x7fffu + ((u >> 16) & 1u);
    return (short)(r >> 16);
}
__device__ __forceinline__ float bf2f(short s) {
    return __uint_as_float(((unsigned)(unsigned short)s) << 16);
}

__device__ __forceinline__ unsigned cvt_pk_bf16(float a, float b) {
    __hip_bfloat162 h = __float22bfloat162_rn(float2{a, b});   // v_cvt_pk_bf16_f32
    return *reinterpret_cast<unsigned*>(&h);
}
// fp32x8 -> bf16 hi + lo residual, using packed cvt (RNE, bit-identical to f2bf)
__device__ __forceinline__ void split44(f32x4 a, f32x4 b, bf16x8& hi, bf16x8& lo) {
    float f[8] = {a[0], a[1], a[2], a[3], b[0], b[1], b[2], b[3]};
    u32x4 H, L;
    #pragma unroll
    for (int j = 0; j < 4; ++j) {
        const float f0 = f[2 * j], f1 = f[2 * j + 1];
        const unsigned h = cvt_pk_bf16(f0, f1);
        const float r0 = f0 - __uint_as_float(h << 16);
        const float r1 = f1 - __uint_as_float(h & 0xffff0000u);
        H[j] = h;
        L[j] = cvt_pk_bf16(r0, r1);
    }
    hi = __builtin_bit_cast(bf16x8, H);
    lo = __builtin_bit_cast(bf16x8, L);
}

__device__ __forceinline__ void gll16(const void* g, void* l) {
    __builtin_amdgcn_global_load_lds((const __attribute__((address_space(1))) void*)g,
                                     (__attribute__((address_space(3))) void*)l, 16, 0, 0);
}
__device__ __forceinline__ void stage16(const char* g, short* l, int lane, int wid) {
    #pragma unroll
    for (int i = 0; i < 4; ++i) {
        const int off = ((i * 4 + wid) << 10);
        gll16(g + off + lane * 16, (char*)l + off);
    }
}
__device__ __forceinline__ void stage8(const char* g, short* l, int lane, int wid) {
    #pragma unroll
    for (int i = 0; i < 2; ++i) {
        const int off = ((i * 4 + wid) << 10);
        gll16(g + off + lane * 16, (char*)l + off);
    }
}

template<int NF>
__device__ __forceinline__ void mfma_ks(bf16x8 ah, bf16x8 al, const short* slot,
                                        int acol, int kq, f32x4* acc) {
    #pragma unroll
    for (int n = 0; n < NF; ++n) {
        const int c = n * 16 + acol;
        const int x = (c >> 2) & 1;
        const int sw = (kq ^ (c & 3)) << 3;
        const bf16x8 bh = *(const bf16x8*)&slot[c * 64 + x * 32 + sw];
        const bf16x8 bl = *(const bf16x8*)&slot[c * 64 + (x ^ 1) * 32 + sw];
        acc[n] = __builtin_amdgcn_mfma_f32_16x16x32_bf16(ah, bh, acc[n], 0, 0, 0);
        acc[n] = __builtin_amdgcn_mfma_f32_16x16x32_bf16(al, bh, acc[n], 0, 0, 0);
        acc[n] = __builtin_amdgcn_mfma_f32_16x16x32_bf16(ah, bl, acc[n], 0, 0, 0);
    }
}

// hoist helper: read + split one t_lds A-fragment
__device__ __forceinline__ void tfrag(const float* tl, int rb, int q, int kq,
                                      bf16x8& Ah, bf16x8& Al) {
    const f32x4 ta = *(const f32x4*)&tl[rb + q * 32 + kq * 8];
    const f32x4 tb = *(const f32x4*)&tl[rb + q * 32 + kq * 8 + 4];
    split44(ta, tb, Ah, Al);
}

// 4-phase 128-k GEMM from t_lds, A hoisted to registers up front.
__device__ __forceinline__ void tgemm4(const char* img, const char* imgnext,
                                       short* sA, short* sB, const float* tl, int rb,
                                       int kq, int acol, int lane, int wid, f32x4* acc)
{
    bf16x8 Ah[4], Al[4];
    #pragma unroll
    for (int q = 0; q < 4; ++q) tfrag(tl, rb, q, kq, Ah[q], Al[q]);

    stage16(img + 16384, sB, lane, wid);
    mfma_ks<8>(Ah[0], Al[0], sA, acol, kq, acc); __syncthreads();
    stage16(img + 32768, sA, lane, wid);
    mfma_ks<8>(Ah[1], Al[1], sB, acol, kq, acc); __syncthreads();
    stage16(img + 49152, sB, lane, wid);
    mfma_ks<8>(Ah[2], Al[2], sA, acol, kq, acc); __syncthreads();
    if (imgnext) stage16(imgnext, sA, lane, wid);
    mfma_ks<8>(Ah[3], Al[3], sB, acol, kq, acc); __syncthreads();
}

#define TPITCH 132

// ---------------- weight pre-conversion -------------------------------------
struct WDesc { const float* src; char* dst; int K; int N; };
struct WPrepArgs { WDesc w[11]; };

__global__ void wprep_kernel(WPrepArgs args) {
    const WDesc d = args.w[blockIdx.y];
    const int h = blockIdx.x;
    if (h * 32 >= d.K) return;
    char* slab = d.dst + (size_t)h * d.N * 128;
    for (int idx = threadIdx.x; idx < d.N * 4; idx += 256) {
        const int c = idx >> 2, ch = idx & 3;
        bf16x8 hi, lo;
        #pragma unroll
        for (int j = 0; j < 8; ++j) {
            const float f = d.src[(size_t)(h * 32 + ch * 8 + j) * d.N + c];
            const short hb = f2bf(f);
            hi[j] = hb;
            lo[j] = f2bf(f - bf2f(hb));
        }
        const int x = (c >> 2) & 1;
        const int sw = (ch ^ (c & 3)) * 16;
        *(bf16x8*)(slab + c * 128 + x * 64 + sw)       = hi;
        *(bf16x8*)(slab + c * 128 + (x ^ 1) * 64 + sw) = lo;
    }
}

// ---------------- prologue / CSR --------------------------------------------

__global__ void rbf1_kernel(const float* __restrict__ rbf, const float* __restrict__ w_rbf1,
                            float* __restrict__ re1, int E) {
    const int i = blockIdx.x * 256 + threadIdx.x;
    const int e = i >> 3, p = i & 7;
    if (e < E) {
        float s = 0.f;
        #pragma unroll
        for (int q = 0; q < 6; ++q) s = fmaf(rbf[e * 6 + q], w_rbf1[q * 8 + p], s);
        re1[i] = s;
    }
}

__global__ void count_rank_kernel(const int* __restrict__ idx_ji, int* __restrict__ cnt,
                                  int* __restrict__ rank, int T) {
    const int i = (blockIdx.x * 256 + threadIdx.x) * 4;
    if (i + 3 < T) {
        const int4 j = *(const int4*)&idx_ji[i];
        int4 r;
        r.x = atomicAdd(&cnt[j.x], 1);
        r.y = atomicAdd(&cnt[j.y], 1);
        r.z = atomicAdd(&cnt[j.z], 1);
        r.w = atomicAdd(&cnt[j.w], 1);
        *(int4*)&rank[i] = r;
    } else {
        for (int k = i; k < T; ++k) rank[k] = atomicAdd(&cnt[idx_ji[k]], 1);
    }
}

__global__ void scan_partial_kernel(const int* __restrict__ cnt, int* __restrict__ partial, int E) {
    __shared__ int red[256];
    const int tid = threadIdx.x;
    const int base = blockIdx.x * 1024 + tid * 4;
    int s = 0;
    #pragma unroll
    for (int i = 0; i < 4; ++i) { const int g = base + i; if (g < E) s += cnt[g]; }
    red[tid] = s;
    __syncthreads();
    for (int off = 128; off > 0; off >>= 1) {
        if (tid < off) red[tid] += red[tid + off];
        __syncthreads();
    }
    if (tid == 0) partial[blockIdx.x] = red[0];
}

__global__ void scan_block_kernel(const int* __restrict__ partial, int* __restrict__ blockoff,
                                  int NB, int* offsets, int E) {
    __shared__ int red[256];
    const int tid = threadIdx.x;
    int v[4]; int s = 0;
    #pragma unroll
    for (int i = 0; i < 4; ++i) { const int g = tid * 4 + i; v[i] = (g < NB) ? partial[g] : 0; s += v[i]; }
    red[tid] = s;
    __syncthreads();
    for (int off = 1; off < 256; off <<= 1) {
        const int add = (tid >= off) ? red[tid - off] : 0;
        __syncthreads();
        red[tid] += add;
        __syncthreads();
    }
    int excl = (tid == 0) ? 0 : red[tid - 1];
    #pragma unroll
    for (int i = 0; i < 4; ++i) { const int g = tid * 4 + i; if (g < NB) blockoff[g] = excl; excl += v[i]; }
    if (tid == 255) offsets[E] = red[255];
}

__global__ void scan_final_kernel(const int* __restrict__ cnt, const int* __restrict__ blockoff,
                                  int* __restrict__ offsets, int E) {
    __shared__ int red[256];
    const int tid = threadIdx.x;
    const int base = blockIdx.x * 1024 + tid * 4;
    int v[4]; int s = 0;
    #pragma unroll
    for (int i = 0; i < 4; ++i) { const int g = base + i; v[i] = (g < E) ? cnt[g] : 0; s += v[i]; }
    red[tid] = s;
    __syncthreads();
    for (int off = 1; off < 256; off <<= 1) {
        const int add = (tid >= off) ? red[tid - off] : 0;
        __syncthreads();
        red[tid] += add;
        __syncthreads();
    }
    int run = blockoff[blockIdx.x] + ((tid == 0) ? 0 : red[tid - 1]);
    #pragma unroll
    for (int i = 0; i < 4; ++i) {
        const int g = base + i;
        if (g < E) offsets[g] = run;
        run += v[i];
    }
}

__launch_bounds__(256, 3)
__global__ void e1fill_kernel(const float* __restrict__ sbf, const float* __restrict__ w_sbf1,
                              const int* __restrict__ idx_ji, const int* __restrict__ idx_kj,
                              const int* __restrict__ rank, const int* __restrict__ offsets,
                              float* __restrict__ E1p, int* __restrict__ kjp, int T)
{
    __shared__ float s_lds[256 * 43];
    const int tid = threadIdx.x;
    const long long t0 = (long long)blockIdx.x * 256;
    const int nrow = min(256, (int)(T - t0));
    const int nel  = nrow * 42;
    const float* base = sbf + t0 * 42;

    for (int i = tid * 4; i + 3 < nel; i += 1024) {
        const float4 v = *(const float4*)&base[i];
        s_lds[(i + 0) + (i + 0) / 42] = v.x;
        s_lds[(i + 1) + (i + 1) / 42] = v.y;
        s_lds[(i + 2) + (i + 2) / 42] = v.z;
        s_lds[(i + 3) + (i + 3) / 42] = v.w;
    }
    const int tail0 = nel & ~3;
    if (tid < nel - tail0) { const int g = tail0 + tid; s_lds[g + g / 42] = base[g]; }
    __syncthreads();

    const int t = (int)t0 + tid;
    if (t >= T) return;
    const float* srow = &s_lds[tid * 43];
    float e1[8] = {0.f, 0.f, 0.f, 0.f, 0.f, 0.f, 0.f, 0.f};
    #pragma unroll
    for (int q = 0; q < 42; ++q) {
        const float s = srow[q];
        #pragma unroll
        for (int p = 0; p < 8; ++p) e1[p] = fmaf(s, w_sbf1[q * 8 + p], e1[p]);
    }
    const int ji  = idx_ji[t];
    const int pos = offsets[ji] + rank[t];
    *(float4*)&E1p[(size_t)pos * 8]     = *(float4*)&e1[0];
    *(float4*)&E1p[(size_t)pos * 8 + 4] = *(float4*)&e1[4];
    kjp[pos] = idx_kj[t];
}

// ---------------- gather: depth-1 pipeline incl. the xkjd row gather --------
__launch_bounds__(256, 4)
__global__ void gather_kernel(const float* __restrict__ E1p, const int* __restrict__ kjp,
                              const float* __restrict__ w_sbf2, const int* __restrict__ offsets,
                              const float* __restrict__ xkjd, float* __restrict__ agg, int E)
{
    const int tid  = threadIdx.x;
    const int lane = tid & 63;
    const int e    = blockIdx.x * 4 + (tid >> 6);

    float w2[8];
    #pragma unroll
    for (int p = 0; p < 8; ++p) w2[p] = w_sbf2[p * 64 + lane];

    if (e >= E) return;
    const int j0 = __builtin_amdgcn_readfirstlane(offsets[e]);
    const int j1 = __builtin_amdgcn_readfirstlane(offsets[e + 1]);

    float acc = 0.f;
    if (j0 < j1) {
        int kj = __builtin_amdgcn_readfirstlane(kjp[j0]);
        float4 ea = *(const float4*)&E1p[(size_t)j0 * 8];
        float4 eb = *(const float4*)&E1p[(size_t)j0 * 8 + 4];
        float xv = xkjd[(size_t)kj * 64 + lane];
        for (int j = j0; j < j1; ++j) {
            float xn = 0.f; float4 ean = {}, ebn = {};
            if (j + 1 < j1) {
                const int kn = __builtin_amdgcn_readfirstlane(kjp[j + 1]);
                ean = *(const float4*)&E1p[(size_t)(j + 1) * 8];
                ebn = *(const float4*)&E1p[(size_t)(j + 1) * 8 + 4];
                xn  = xkjd[(size_t)kn * 64 + lane];
            }
            float sv = ea.x * w2[0];
            sv = fmaf(ea.y, w2[1], sv);
            sv = fmaf(ea.z, w2[2], sv);
            sv = fmaf(ea.w, w2[3], sv);
            sv = fmaf(eb.x, w2[4], sv);
            sv = fmaf(eb.y, w2[5], sv);
            sv = fmaf(eb.z, w2[6], sv);
            sv = fmaf(eb.w, w2[7], sv);
            acc = fmaf(xv, sv, acc);
            ea = ean; eb = ebn; xv = xn;
        }
    }
    agg[(size_t)e * 64 + lane] = acc;
}

// ---------------- K1: W3 = silu((silu(x@w_kj+b)*rbf_e)@w_down) --------------
__launch_bounds__(256, 2)
__global__ void k1_kernel(const float* __restrict__ x, const char* __restrict__ wkj_i,
                          const float* __restrict__ b_kj, const float* __restrict__ re1,
                          const float* __restrict__ w_rbf2, const char* __restrict__ wdn_i,
                          float* __restrict__ W3, int E)
{
    __shared__ short slotA[8192], slotB[8192];
    __shared__ float t_lds[64 * TPITCH];
    __shared__ float w2_lds[8 * 128];
    const int tid = threadIdx.x, lane = tid & 63, wid = tid >> 6;
    const int acol = lane & 15, kq = lane >> 4;
    const int rowW = blockIdx.x * 64 + wid * 16;
    const int arow = rowW + acol;
    const bool av = arow < E;

    stage16(wkj_i, slotA, lane, wid);
    const float* xr = x + (size_t)arow * 128;
    bf16x8 aH[4], aL[4];
    #pragma unroll
    for (int ks = 0; ks < 4; ++ks) {
        f32x4 a0 = f32x4{0.f, 0.f, 0.f, 0.f}, a1 = f32x4{0.f, 0.f, 0.f, 0.f};
        if (av) { a0 = *(const f32x4*)&xr[ks * 32 + kq * 8];
                  a1 = *(const f32x4*)&xr[ks * 32 + kq * 8 + 4]; }
        split44(a0, a1, aH[ks], aL[ks]);
    }
    float bv[8];
    #pragma unroll
    for (int n = 0; n < 8; ++n) bv[n] = b_kj[n * 16 + acol];
    f32x4 e1a[4], e1b[4];
    #pragma unroll
    for (int r = 0; r < 4; ++r) {
        const int ge = rowW + kq * 4 + r;
        e1a[r] = f32x4{0.f, 0.f, 0.f, 0.f}; e1b[r] = f32x4{0.f, 0.f, 0.f, 0.f};
        if (ge < E) { e1a[r] = *(const f32x4*)&re1[(size_t)ge * 8];
                      e1b[r] = *(const f32x4*)&re1[(size_t)ge * 8 + 4]; }
    }
    for (int i = tid; i < 1024; i += 256) w2_lds[i] = w_rbf2[i];
    __syncthreads();

    f32x4 acc[8];
    #pragma unroll
    for (int n = 0; n < 8; ++n) acc[n] = f32x4{0.f, 0.f, 0.f, 0.f};

    stage16(wkj_i + 16384, slotB, lane, wid);
    mfma_ks<8>(aH[0], aL[0], slotA, acol, kq, acc); __syncthreads();
    stage16(wkj_i + 32768, slotA, lane, wid);
    mfma_ks<8>(aH[1], aL[1], slotB, acol, kq, acc); __syncthreads();
    stage16(wkj_i + 49152, slotB, lane, wid);
    mfma_ks<8>(aH[2], aL[2], slotA, acol, kq, acc); __syncthreads();
    stage8(wdn_i, slotA, lane, wid);
    mfma_ks<8>(aH[3], aL[3], slotB, acol, kq, acc); __syncthreads();

    #pragma unroll
    for (int n = 0; n < 8; ++n) {
        const int c = n * 16 + acol;
        float w2c[8];
        #pragma unroll
        for (int p = 0; p < 8; ++p) w2c[p] = w2_lds[p * 128 + c];
        #pragma unroll
        for (int r = 0; r < 4; ++r) {
            float s = e1a[r][0] * w2c[0];
            s = fmaf(e1a[r][1], w2c[1], s);
            s = fmaf(e1a[r][2], w2c[2], s);
            s = fmaf(e1a[r][3], w2c[3], s);
            s = fmaf(e1b[r][0], w2c[4], s);
            s = fmaf(e1b[r][1], w2c[5], s);
            s = fmaf(e1b[r][2], w2c[6], s);
            s = fmaf(e1b[r][3], w2c[7], s);
            t_lds[(wid * 16 + kq * 4 + r) * TPITCH + c] = silu_f(acc[n][r] + bv[n]) * s;
        }
    }
    __syncthreads();

    f32x4 acc2[4];
    #pragma unroll
    for (int n = 0; n < 4; ++n) acc2[n] = f32x4{0.f, 0.f, 0.f, 0.f};
    const int rb = (wid * 16 + acol) * TPITCH;

    bf16x8 tH[4], tL[4];
    #pragma unroll
    for (int q = 0; q < 4; ++q) tfrag(t_lds, rb, q, kq, tH[q], tL[q]);

    stage8(wdn_i + 8192, slotB, lane, wid);
    mfma_ks<4>(tH[0], tL[0], slotA, acol, kq, acc2); __syncthreads();
    stage8(wdn_i + 16384, slotA, lane, wid);
    mfma_ks<4>(tH[1], tL[1], slotB, acol, kq, acc2); __syncthreads();
    stage8(wdn_i + 24576, slotB, lane, wid);
    mfma_ks<4>(tH[2], tL[2], slotA, acol, kq, acc2); __syncthreads();
    mfma_ks<4>(tH[3], tL[3], slotB, acol, kq, acc2);

    #pragma unroll
    for (int n = 0; n < 4; ++n) {
        const int c = n * 16 + acol;
        #pragma unroll
        for (int r = 0; r < 4; ++r) {
            const int ge = rowW + kq * 4 + r;
            if (ge < E) W3[(size_t)ge * 64 + c] = silu_f(acc2[n][r]);
        }
    }
}

// ---------------- kbig: h0 -> res1 -> w_bs+skip -> res2 -> res3 (9 GEMMs) ---
struct KBigArgs {
    const float* x; const float* W4; float* out;
    const char *wji, *wup, *r1w1, *r1w2, *wbs, *r2w1, *r2w2, *r3w1, *r3w2;
    const float *bji, *r1b1, *r1b2, *bbs, *r2b1, *r2b2, *r3b1, *r3b2;
    int E;
};

__launch_bounds__(256, 2)
__global__ void kbig_kernel(KBigArgs A_)
{
    __shared__ short slotA[8192], slotB[8192];
    __shared__ float t_lds[64 * TPITCH];
    const int tid = threadIdx.x, lane = tid & 63, wid = tid >> 6;
    const int acol = lane & 15, kq = lane >> 4;
    const int rowW = blockIdx.x * 64 + wid * 16;
    const int arow = rowW + acol;
    const int E = A_.E;
    const bool av = arow < E;
    const int rb = (wid * 16 + acol) * TPITCH;

    stage16(A_.wji, slotA, lane, wid);

    const float* xr = A_.x + (size_t)arow * 128;
    const float* wr = A_.W4 + (size_t)arow * 64;
    bf16x8 aH[4], aL[4], uH[2], uL[2];
    #pragma unroll
    for (int ks = 0; ks < 4; ++ks) {
        f32x4 a0 = f32x4{0.f, 0.f, 0.f, 0.f}, a1 = f32x4{0.f, 0.f, 0.f, 0.f};
        if (av) { a0 = *(const f32x4*)&xr[ks * 32 + kq * 8];
                  a1 = *(const f32x4*)&xr[ks * 32 + kq * 8 + 4]; }
        split44(a0, a1, aH[ks], aL[ks]);
    }
    #pragma unroll
    for (int ks = 0; ks < 2; ++ks) {
        f32x4 u0 = f32x4{0.f, 0.f, 0.f, 0.f}, u1 = f32x4{0.f, 0.f, 0.f, 0.f};
        if (av) { u0 = *(const f32x4*)&wr[ks * 32 + kq * 8];
                  u1 = *(const f32x4*)&wr[ks * 32 + kq * 8 + 4]; }
        split44(u0, u1, uH[ks], uL[ks]);
    }
    __syncthreads();

    f32x4 acc[8];
    #pragma unroll
    for (int n = 0; n < 8; ++n) acc[n] = f32x4{0.f, 0.f, 0.f, 0.f};

    // GEMM1: x @ w_ji
    stage16(A_.wji + 16384, slotB, lane, wid);
    mfma_ks<8>(aH[0], aL[0], slotA, acol, kq, acc); __syncthreads();
    stage16(A_.wji + 32768, slotA, lane, wid);
    mfma_ks<8>(aH[1], aL[1], slotB, acol, kq, acc); __syncthreads();
    stage16(A_.wji + 49152, slotB, lane, wid);
    mfma_ks<8>(aH[2], aL[2], slotA, acol, kq, acc); __syncthreads();
    stage16(A_.wup, slotA, lane, wid);
    mfma_ks<8>(aH[3], aL[3], slotB, acol, kq, acc); __syncthreads();

    float res[8][4];
    #pragma unroll
    for (int n = 0; n < 8; ++n) {
        const float bv = A_.bji[n * 16 + acol];
        #pragma unroll
        for (int r = 0; r < 4; ++r) { res[n][r] = silu_f(acc[n][r] + bv); acc[n][r] = 0.f; }
    }

    // GEMM2: W4 @ w_up (K=64)
    stage16(A_.wup + 16384, slotB, lane, wid);
    mfma_ks<8>(uH[0], uL[0], slotA, acol, kq, acc); __syncthreads();
    stage16(A_.r1w1, slotA, lane, wid);
    mfma_ks<8>(uH[1], uL[1], slotB, acol, kq, acc); __syncthreads();

    #pragma unroll
    for (int n = 0; n < 8; ++n) {
        const int c = n * 16 + acol;
        #pragma unroll
        for (int r = 0; r < 4; ++r) {
            res[n][r] += silu_f(acc[n][r]);                     // h0
            t_lds[(wid * 16 + kq * 4 + r) * TPITCH + c] = res[n][r];
            acc[n][r] = 0.f;
        }
    }
    __syncthreads();

    // GEMM3: h0 @ r1w1 -> t1
    tgemm4(A_.r1w1, A_.r1w2, slotA, slotB, t_lds, rb, kq, acol, lane, wid, acc);
    #pragma unroll
    for (int n = 0; n < 8; ++n) {
        const float bv = A_.r1b1[n * 16 + acol];
        const int c = n * 16 + acol;
        #pragma unroll
        for (int r = 0; r < 4; ++r) {
            t_lds[(wid * 16 + kq * 4 + r) * TPITCH + c] = silu_f(acc[n][r] + bv);
            acc[n][r] = 0.f;
        }
    }
    __syncthreads();

    // GEMM4: t1 @ r1w2 -> t2 = h0 + silu(.)
    tgemm4(A_.r1w2, A_.wbs, slotA, slotB, t_lds, rb, kq, acol, lane, wid, acc);
    #pragma unroll
    for (int n = 0; n < 8; ++n) {
        const float bv = A_.r1b2[n * 16 + acol];
        const int c = n * 16 + acol;
        #pragma unroll
        for (int r = 0; r < 4; ++r) {
            t_lds[(wid * 16 + kq * 4 + r) * TPITCH + c] = res[n][r] + silu_f(acc[n][r] + bv);
            acc[n][r] = 0.f;
        }
    }
    __syncthreads();

    // GEMM5: t2 @ w_bs -> h2 = silu(.) + x
    tgemm4(A_.wbs, A_.r2w1, slotA, slotB, t_lds, rb, kq, acol, lane, wid, acc);
    #pragma unroll
    for (int n = 0; n < 8; ++n) {
        const float bv = A_.bbs[n * 16 + acol];
        const int c = n * 16 + acol;
        #pragma unroll
        for (int r = 0; r < 4; ++r) {
            const int ge = rowW + kq * 4 + r;
            const float xv = (ge < E) ? A_.x[(size_t)ge * 128 + c] : 0.f;
            res[n][r] = silu_f(acc[n][r] + bv) + xv;            // h2
            t_lds[(wid * 16 + kq * 4 + r) * TPITCH + c] = res[n][r];
            acc[n][r] = 0.f;
        }
    }
    __syncthreads();

    // GEMM6: h2 @ r2w1 -> t3
    tgemm4(A_.r2w1, A_.r2w2, slotA, slotB, t_lds, rb, kq, acol, lane, wid, acc);
    #pragma unroll
    for (int n = 0; n < 8; ++n) {
        const float bv = A_.r2b1[n * 16 + acol];
        const int c = n * 16 + acol;
        #pragma unroll
        for (int r = 0; r < 4; ++r) {
            t_lds[(wid * 16 + kq * 4 + r) * TPITCH + c] = silu_f(acc[n][r] + bv);
            acc[n][r] = 0.f;
        }
    }
    __syncthreads();

    // GEMM7: t3 @ r2w2 -> h3 = h2 + silu(.)
    tgemm4(A_.r2w2, A_.r3w1, slotA, slotB, t_lds, rb, kq, acol, lane, wid, acc);
    #pragma unroll
    for (int n = 0; n < 8; ++n) {
        const float bv = A_.r2b2[n * 16 + acol];
        const int c = n * 16 + acol;
        #pragma unroll
        for (int r = 0; r < 4; ++r) {
            res[n][r] += silu_f(acc[n][r] + bv);                // h3
            t_lds[(wid * 16 + kq * 4 + r) * TPITCH + c] = res[n][r];
            acc[n][r] = 0.f;
        }
    }
    __syncthreads();

    // GEMM8: h3 @ r3w1 -> t4
    tgemm4(A_.r3w1, A_.r3w2, slotA, slotB, t_lds, rb, kq, acol, lane, wid, acc);
    #pragma unroll
    for (int n = 0; n < 8; ++n) {
        const float bv = A_.r3b1[n * 16 + acol];
        const int c = n * 16 + acol;
        #pragma unroll
        for (int r = 0; r < 4; ++r) {
            t_lds[(wid * 16 + kq * 4 + r) * TPITCH + c] = silu_f(acc[n][r] + bv);
            acc[n][r] = 0.f;
        }
    }
    __syncthreads();

    // GEMM9: t4 @ r3w2 -> out = h3 + silu(.)
    tgemm4(A_.r3w2, nullptr, slotA, slotB, t_lds, rb, kq, acol, lane, wid, acc);
    #pragma unroll
    for (int n = 0; n < 8; ++n) {
        const float bv = A_.r3b2[n * 16 + acol];
        const int c = n * 16 + acol;
        #pragma unroll
        for (int r = 0; r < 4; ++r) {
            const int ge = rowW + kq * 4 + r;
            if (ge < E)
                A_.out[(size_t)ge * 128 + c] = res[n][r] + silu_f(acc[n][r] + bv);
        }
    }
}

// ---------------------------------------------------------------------------

extern "C" void kernel_launch(void* const* d_in, const int* in_sizes, int n_in,
                              void* d_out, int out_size, void* d_ws, size_t ws_size,
                              hipStream_t stream)
{
    const float* x      = (const float*)d_in[0];
    const float* rbf    = (const float*)d_in[1];
    const float* sbf    = (const float*)d_in[2];
    const int*   idx_kj = (const int*)d_in[3];
    const int*   idx_ji = (const int*)d_in[4];
    const float* w_rbf1 = (const float*)d_in[5];
    const float* w_rbf2 = (const float*)d_in[6];
    const float* w_sbf1 = (const float*)d_in[7];
    const float* w_sbf2 = (const float*)d_in[8];
    const float* w_kj   = (const float*)d_in[9];
    const float* b_kj   = (const float*)d_in[10];
    const float* w_ji   = (const float*)d_in[11];
    const float* b_ji   = (const float*)d_in[12];
    const float* w_down = (const float*)d_in[13];
    const float* w_up   = (const float*)d_in[14];
    const float* r1w1   = (const float*)d_in[15];
    const float* r1b1   = (const float*)d_in[16];
    const float* r1w2   = (const float*)d_in[17];
    const float* r1b2   = (const float*)d_in[18];
    const float* w_bs   = (const float*)d_in[19];
    const float* b_bs   = (const float*)d_in[20];
    const float* r2w1   = (const float*)d_in[21];
    const float* r2b1   = (const float*)d_in[22];
    const float* r2w2   = (const float*)d_in[23];
    const float* r2b2   = (const float*)d_in[24];
    const float* r3w1   = (const float*)d_in[25];
    const float* r3b1   = (const float*)d_in[26];
    const float* r3w2   = (const float*)d_in[27];
    const float* r3b2   = (const float*)d_in[28];

    const int E = in_sizes[0] / 128;
    const int T = in_sizes[2] / 42;

    float* OUT = (float*)d_out;
    float* W3  = (float*)((char*)d_ws + (size_t)E * 128 * 4);         // [E,64]
    float* W4  = (float*)((char*)d_ws + (size_t)E * 128 * 4
                                      + (size_t)E * 64 * 4);          // [E,64]

    int*   cnt      = (int*)d_ws;                            // [E]
    int*   offsets  = cnt + (E + 64);                        // [E+1]
    int*   partial  = offsets + (E + 64);                    // [<=1024]
    int*   blockoff = partial + 1024;                        // [<=1024]
    float* E1p      = (float*)((char*)d_ws + (4u << 20));    // [T,8]   96 MB
    int*   kjp      = (int*)((char*)d_ws + (102u << 20));    // [T]     12 MB
    float* re1      = (float*)((char*)d_ws + (116u << 20));  // [E,8]  9.6 MB
    char*  wimg     = (char*)d_ws + (130u << 20);            // 640 KB
    int*   rank     = (int*)((char*)d_ws + (134u << 20));    // [T]     12 MB

    char* wkj_i  = wimg;
    char* wji_i  = wimg + 65536;
    char* wdn_i  = wimg + 131072;
    char* wup_i  = wimg + 163840;
    char* r1w1_i = wimg + 196608;
    char* r1w2_i = wimg + 262144;
    char* wbs_i  = wimg + 327680;
    char* r2w1_i = wimg + 393216;
    char* r2w2_i = wimg + 458752;
    char* r3w1_i = wimg + 524288;
    char* r3w2_i = wimg + 589824;

    WPrepArgs pa;
    pa.w[0]  = {w_kj,   wkj_i,  128, 128};
    pa.w[1]  = {w_ji,   wji_i,  128, 128};
    pa.w[2]  = {w_down, wdn_i,  128,  64};
    pa.w[3]  = {w_up,   wup_i,   64, 128};
    pa.w[4]  = {r1w1,   r1w1_i, 128, 128};
    pa.w[5]  = {r1w2,   r1w2_i, 128, 128};
    pa.w[6]  = {w_bs,   wbs_i,  128, 128};
    pa.w[7]  = {r2w1,   r2w1_i, 128, 128};
    pa.w[8]  = {r2w2,   r2w2_i, 128, 128};
    pa.w[9]  = {r3w1,   r3w1_i, 128, 128};
    pa.w[10] = {r3w2,   r3w2_i, 128, 128};

    const dim3 b256(256);
    const int gB  = (E + 63) / 64;
    const int gT  = (T + 255) / 256;
    const int gT4 = (T + 1023) / 1024;
    const int NB  = (E + 1023) / 1024;
    const int gE4 = (E + 3) / 4;
    const int gR  = (E * 8 + 255) / 256;

    wprep_kernel<<<dim3(4, 11), b256, 0, stream>>>(pa);
    rbf1_kernel<<<gR, b256, 0, stream>>>(rbf, w_rbf1, re1, E);
    hipMemsetAsync(cnt, 0, (size_t)E * 4, stream);
    count_rank_kernel<<<gT4, b256, 0, stream>>>(idx_ji, cnt, rank, T);
    scan_partial_kernel<<<NB, b256, 0, stream>>>(cnt, partial, E);
    scan_block_kernel<<<1, b256, 0, stream>>>(partial, blockoff, NB, offsets, E);
    scan_final_kernel<<<NB, b256, 0, stream>>>(cnt, blockoff, offsets, E);
    e1fill_kernel<<<gT, b256, 0, stream>>>(sbf, w_sbf1, idx_ji, idx_kj, rank, offsets, E1p, kjp, T);

    k1_kernel<<<gB, b256, 0, stream>>>(x, wkj_i, b_kj, re1, w_rbf2, wdn_i, W3, E);
    gather_kernel<<<gE4, b256, 0, stream>>>(E1p, kjp, w_sbf2, offsets, W3, W4, E);

    KBigArgs ka;
    ka.x = x; ka.W4 = W4; ka.out = OUT;
    ka.wji = wji_i; ka.wup = wup_i; ka.r1w1 = r1w1_i; ka.r1w2 = r1w2_i; ka.wbs = wbs_i;
    ka.r2w1 = r2w1_i; ka.r2w2 = r2w2_i; ka.r3w1 = r3w1_i; ka.r3w2 = r3w2_i;
    ka.bji = b_ji; ka.r1b1 = r1b1; ka.r1b2 = r1b2; ka.bbs = b_bs;
    ka.r2b1 = r2b1; ka.r2b2 = r2b2; ka.r3b1 = r3b1; ka.r3b2 = r3b2;
    ka.E = E;
    kbig_kernel<<<gB, b256, 0, stream>>>(ka);
}

// Round 14
// 1019.606 us; speedup vs baseline: 1.4305x; 1.1775x over previous
//
#include <hip/hip_runtime.h>
#include <hip/hip_bf16.h>

// ---------------------------------------------------------------------------
// DimeNet++ interaction block, round 14:
//   split-fp16 2-pass MFMA replaces split-bf16 3-pass:
//     - weights: single-plane fp16 (incoherent 2^-12 quantization error)
//     - activations: fp16 hi + exact fp16 residual (2^-22)
//     - per col-frag: 1 LDS B-read + 2 MFMA (was 2 reads + 3 MFMA)
//   Weight slabs halve (8 KB) -> LDS/block 50 KB -> 3 blocks/CU (12 waves).
//   Schedule / barriers / wave layout byte-identical to round 13.
// ---------------------------------------------------------------------------

typedef __attribute__((ext_vector_type(8))) _Float16 f16x8;
typedef __attribute__((ext_vector_type(4))) float f32x4;

__device__ __forceinline__ float silu_f(float v) {
    return v * __builtin_amdgcn_rcpf(1.0f + __expf(-v));
}

// fp32x8 -> fp16 hi + exact residual lo
__device__ __forceinline__ void split44h(f32x4 a, f32x4 b, f16x8& hi, f16x8& lo) {
    float f[8] = {a[0], a[1], a[2], a[3], b[0], b[1], b[2], b[3]};
    #pragma unroll
    for (int j = 0; j < 8; ++j) {
        const _Float16 h = (_Float16)f[j];
        hi[j] = h;
        lo[j] = (_Float16)(f[j] - (float)h);
    }
}

__device__ __forceinline__ void gll16(const void* g, void* l) {
    __builtin_amdgcn_global_load_lds((const __attribute__((address_space(1))) void*)g,
                                     (__attribute__((address_space(3))) void*)l, 16, 0, 0);
}
// stage an 8 KB slab (N=128) with 4 waves
__device__ __forceinline__ void stage8k(const char* g, _Float16* l, int lane, int wid) {
    #pragma unroll
    for (int i = 0; i < 2; ++i) {
        const int off = ((i * 4 + wid) << 10);
        gll16(g + off + lane * 16, (char*)l + off);
    }
}
// stage a 4 KB slab (N=64) with 4 waves
__device__ __forceinline__ void stage4k(const char* g, _Float16* l, int lane, int wid) {
    const int off = (wid << 10);
    gll16(g + off + lane * 16, (char*)l + off);
}

// one 32-k step, 2-pass split-fp16 MFMA over NF col-frags
// slot layout per slab: halfs at c*32 + ((kq ^ (c&3))<<3)  (image pre-swizzled)
template<int NF>
__device__ __forceinline__ void mfma_ks(f16x8 ah, f16x8 al, const _Float16* slot,
                                        int acol, int kq, f32x4* acc) {
    #pragma unroll
    for (int n = 0; n < NF; ++n) {
        const int c = n * 16 + acol;
        const int sw = (kq ^ (c & 3)) << 3;
        const f16x8 bh = *(const f16x8*)&slot[c * 32 + sw];
        acc[n] = __builtin_amdgcn_mfma_f32_16x16x32_f16(ah, bh, acc[n], 0, 0, 0);
        acc[n] = __builtin_amdgcn_mfma_f32_16x16x32_f16(al, bh, acc[n], 0, 0, 0);
    }
}

// read + split one t_lds A-fragment
__device__ __forceinline__ void tfrag(const float* tl, int rb, int q, int kq,
                                      f16x8& Ah, f16x8& Al) {
    const f32x4 ta = *(const f32x4*)&tl[rb + q * 32 + kq * 8];
    const f32x4 tb = *(const f32x4*)&tl[rb + q * 32 + kq * 8 + 4];
    split44h(ta, tb, Ah, Al);
}

// 4-phase 128-k GEMM from t_lds (N=128, 8 KB slabs at img+8192*i)
__device__ __forceinline__ void tgemm4(const char* img, const char* imgnext,
                                       _Float16* sA, _Float16* sB, const float* tl, int rb,
                                       int kq, int acol, int lane, int wid, f32x4* acc)
{
    f16x8 Ah[4], Al[4];
    #pragma unroll
    for (int q = 0; q < 4; ++q) tfrag(tl, rb, q, kq, Ah[q], Al[q]);

    stage8k(img + 8192, sB, lane, wid);
    mfma_ks<8>(Ah[0], Al[0], sA, acol, kq, acc); __syncthreads();
    stage8k(img + 16384, sA, lane, wid);
    mfma_ks<8>(Ah[1], Al[1], sB, acol, kq, acc); __syncthreads();
    stage8k(img + 24576, sB, lane, wid);
    mfma_ks<8>(Ah[2], Al[2], sA, acol, kq, acc); __syncthreads();
    if (imgnext) stage8k(imgnext, sA, lane, wid);
    mfma_ks<8>(Ah[3], Al[3], sB, acol, kq, acc); __syncthreads();
}

#define TPITCH 132

// ---------------- weight pre-conversion (fp16, swizzled image) --------------
struct WDesc { const float* src; char* dst; int K; int N; };
struct WPrepArgs { WDesc w[11]; };

__global__ void wprep_kernel(WPrepArgs args) {
    const WDesc d = args.w[blockIdx.y];
    const int h = blockIdx.x;
    if (h * 32 >= d.K) return;
    char* slab = d.dst + (size_t)h * d.N * 64;
    for (int idx = threadIdx.x; idx < d.N * 4; idx += 256) {
        const int c = idx >> 2, ch = idx & 3;
        f16x8 v;
        #pragma unroll
        for (int j = 0; j < 8; ++j)
            v[j] = (_Float16)d.src[(size_t)(h * 32 + ch * 8 + j) * d.N + c];
        *(f16x8*)(slab + c * 64 + ((ch ^ (c & 3)) << 4)) = v;
    }
}

// ---------------- prologue / CSR --------------------------------------------

__global__ void rbf1_kernel(const float* __restrict__ rbf, const float* __restrict__ w_rbf1,
                            float* __restrict__ re1, int E) {
    const int i = blockIdx.x * 256 + threadIdx.x;
    const int e = i >> 3, p = i & 7;
    if (e < E) {
        float s = 0.f;
        #pragma unroll
        for (int q = 0; q < 6; ++q) s = fmaf(rbf[e * 6 + q], w_rbf1[q * 8 + p], s);
        re1[i] = s;
    }
}

__global__ void count_rank_kernel(const int* __restrict__ idx_ji, int* __restrict__ cnt,
                                  int* __restrict__ rank, int T) {
    const int i = (blockIdx.x * 256 + threadIdx.x) * 4;
    if (i + 3 < T) {
        const int4 j = *(const int4*)&idx_ji[i];
        int4 r;
        r.x = atomicAdd(&cnt[j.x], 1);
        r.y = atomicAdd(&cnt[j.y], 1);
        r.z = atomicAdd(&cnt[j.z], 1);
        r.w = atomicAdd(&cnt[j.w], 1);
        *(int4*)&rank[i] = r;
    } else {
        for (int k = i; k < T; ++k) rank[k] = atomicAdd(&cnt[idx_ji[k]], 1);
    }
}

__global__ void scan_partial_kernel(const int* __restrict__ cnt, int* __restrict__ partial, int E) {
    __shared__ int red[256];
    const int tid = threadIdx.x;
    const int base = blockIdx.x * 1024 + tid * 4;
    int s = 0;
    #pragma unroll
    for (int i = 0; i < 4; ++i) { const int g = base + i; if (g < E) s += cnt[g]; }
    red[tid] = s;
    __syncthreads();
    for (int off = 128; off > 0; off >>= 1) {
        if (tid < off) red[tid] += red[tid + off];
        __syncthreads();
    }
    if (tid == 0) partial[blockIdx.x] = red[0];
}

__global__ void scan_block_kernel(const int* __restrict__ partial, int* __restrict__ blockoff,
                                  int NB, int* offsets, int E) {
    __shared__ int red[256];
    const int tid = threadIdx.x;
    int v[4]; int s = 0;
    #pragma unroll
    for (int i = 0; i < 4; ++i) { const int g = tid * 4 + i; v[i] = (g < NB) ? partial[g] : 0; s += v[i]; }
    red[tid] = s;
    __syncthreads();
    for (int off = 1; off < 256; off <<= 1) {
        const int add = (tid >= off) ? red[tid - off] : 0;
        __syncthreads();
        red[tid] += add;
        __syncthreads();
    }
    int excl = (tid == 0) ? 0 : red[tid - 1];
    #pragma unroll
    for (int i = 0; i < 4; ++i) { const int g = tid * 4 + i; if (g < NB) blockoff[g] = excl; excl += v[i]; }
    if (tid == 255) offsets[E] = red[255];
}

__global__ void scan_final_kernel(const int* __restrict__ cnt, const int* __restrict__ blockoff,
                                  int* __restrict__ offsets, int E) {
    __shared__ int red[256];
    const int tid = threadIdx.x;
    const int base = blockIdx.x * 1024 + tid * 4;
    int v[4]; int s = 0;
    #pragma unroll
    for (int i = 0; i < 4; ++i) { const int g = base + i; v[i] = (g < E) ? cnt[g] : 0; s += v[i]; }
    red[tid] = s;
    __syncthreads();
    for (int off = 1; off < 256; off <<= 1) {
        const int add = (tid >= off) ? red[tid - off] : 0;
        __syncthreads();
        red[tid] += add;
        __syncthreads();
    }
    int run = blockoff[blockIdx.x] + ((tid == 0) ? 0 : red[tid - 1]);
    #pragma unroll
    for (int i = 0; i < 4; ++i) {
        const int g = base + i;
        if (g < E) offsets[g] = run;
        run += v[i];
    }
}

__launch_bounds__(256, 3)
__global__ void e1fill_kernel(const float* __restrict__ sbf, const float* __restrict__ w_sbf1,
                              const int* __restrict__ idx_ji, const int* __restrict__ idx_kj,
                              const int* __restrict__ rank, const int* __restrict__ offsets,
                              float* __restrict__ E1p, int* __restrict__ kjp, int T)
{
    __shared__ float s_lds[256 * 43];
    const int tid = threadIdx.x;
    const long long t0 = (long long)blockIdx.x * 256;
    const int nrow = min(256, (int)(T - t0));
    const int nel  = nrow * 42;
    const float* base = sbf + t0 * 42;

    for (int i = tid * 4; i + 3 < nel; i += 1024) {
        const float4 v = *(const float4*)&base[i];
        s_lds[(i + 0) + (i + 0) / 42] = v.x;
        s_lds[(i + 1) + (i + 1) / 42] = v.y;
        s_lds[(i + 2) + (i + 2) / 42] = v.z;
        s_lds[(i + 3) + (i + 3) / 42] = v.w;
    }
    const int tail0 = nel & ~3;
    if (tid < nel - tail0) { const int g = tail0 + tid; s_lds[g + g / 42] = base[g]; }
    __syncthreads();

    const int t = (int)t0 + tid;
    if (t >= T) return;
    const float* srow = &s_lds[tid * 43];
    float e1[8] = {0.f, 0.f, 0.f, 0.f, 0.f, 0.f, 0.f, 0.f};
    #pragma unroll
    for (int q = 0; q < 42; ++q) {
        const float s = srow[q];
        #pragma unroll
        for (int p = 0; p < 8; ++p) e1[p] = fmaf(s, w_sbf1[q * 8 + p], e1[p]);
    }
    const int ji  = idx_ji[t];
    const int pos = offsets[ji] + rank[t];
    *(float4*)&E1p[(size_t)pos * 8]     = *(float4*)&e1[0];
    *(float4*)&E1p[(size_t)pos * 8 + 4] = *(float4*)&e1[4];
    kjp[pos] = idx_kj[t];
}

// ---------------- gather: depth-1 pipeline incl. the xkjd row gather --------
__launch_bounds__(256, 4)
__global__ void gather_kernel(const float* __restrict__ E1p, const int* __restrict__ kjp,
                              const float* __restrict__ w_sbf2, const int* __restrict__ offsets,
                              const float* __restrict__ xkjd, float* __restrict__ agg, int E)
{
    const int tid  = threadIdx.x;
    const int lane = tid & 63;
    const int e    = blockIdx.x * 4 + (tid >> 6);

    float w2[8];
    #pragma unroll
    for (int p = 0; p < 8; ++p) w2[p] = w_sbf2[p * 64 + lane];

    if (e >= E) return;
    const int j0 = __builtin_amdgcn_readfirstlane(offsets[e]);
    const int j1 = __builtin_amdgcn_readfirstlane(offsets[e + 1]);

    float acc = 0.f;
    if (j0 < j1) {
        int kj = __builtin_amdgcn_readfirstlane(kjp[j0]);
        float4 ea = *(const float4*)&E1p[(size_t)j0 * 8];
        float4 eb = *(const float4*)&E1p[(size_t)j0 * 8 + 4];
        float xv = xkjd[(size_t)kj * 64 + lane];
        for (int j = j0; j < j1; ++j) {
            float xn = 0.f; float4 ean = {}, ebn = {};
            if (j + 1 < j1) {
                const int kn = __builtin_amdgcn_readfirstlane(kjp[j + 1]);
                ean = *(const float4*)&E1p[(size_t)(j + 1) * 8];
                ebn = *(const float4*)&E1p[(size_t)(j + 1) * 8 + 4];
                xn  = xkjd[(size_t)kn * 64 + lane];
            }
            float sv = ea.x * w2[0];
            sv = fmaf(ea.y, w2[1], sv);
            sv = fmaf(ea.z, w2[2], sv);
            sv = fmaf(ea.w, w2[3], sv);
            sv = fmaf(eb.x, w2[4], sv);
            sv = fmaf(eb.y, w2[5], sv);
            sv = fmaf(eb.z, w2[6], sv);
            sv = fmaf(eb.w, w2[7], sv);
            acc = fmaf(xv, sv, acc);
            ea = ean; eb = ebn; xv = xn;
        }
    }
    agg[(size_t)e * 64 + lane] = acc;
}

// ---------------- K1: W3 = silu((silu(x@w_kj+b)*rbf_e)@w_down) --------------
__launch_bounds__(256, 3)
__global__ void k1_kernel(const float* __restrict__ x, const char* __restrict__ wkj_i,
                          const float* __restrict__ b_kj, const float* __restrict__ re1,
                          const float* __restrict__ w_rbf2, const char* __restrict__ wdn_i,
                          float* __restrict__ W3, int E)
{
    __shared__ _Float16 slotA[4096], slotB[4096];
    __shared__ float t_lds[64 * TPITCH];
    __shared__ float w2_lds[8 * 128];
    const int tid = threadIdx.x, lane = tid & 63, wid = tid >> 6;
    const int acol = lane & 15, kq = lane >> 4;
    const int rowW = blockIdx.x * 64 + wid * 16;
    const int arow = rowW + acol;
    const bool av = arow < E;

    stage8k(wkj_i, slotA, lane, wid);
    const float* xr = x + (size_t)arow * 128;
    f16x8 aH[4], aL[4];
    #pragma unroll
    for (int ks = 0; ks < 4; ++ks) {
        f32x4 a0 = f32x4{0.f, 0.f, 0.f, 0.f}, a1 = f32x4{0.f, 0.f, 0.f, 0.f};
        if (av) { a0 = *(const f32x4*)&xr[ks * 32 + kq * 8];
                  a1 = *(const f32x4*)&xr[ks * 32 + kq * 8 + 4]; }
        split44h(a0, a1, aH[ks], aL[ks]);
    }
    float bv[8];
    #pragma unroll
    for (int n = 0; n < 8; ++n) bv[n] = b_kj[n * 16 + acol];
    f32x4 e1a[4], e1b[4];
    #pragma unroll
    for (int r = 0; r < 4; ++r) {
        const int ge = rowW + kq * 4 + r;
        e1a[r] = f32x4{0.f, 0.f, 0.f, 0.f}; e1b[r] = f32x4{0.f, 0.f, 0.f, 0.f};
        if (ge < E) { e1a[r] = *(const f32x4*)&re1[(size_t)ge * 8];
                      e1b[r] = *(const f32x4*)&re1[(size_t)ge * 8 + 4]; }
    }
    for (int i = tid; i < 1024; i += 256) w2_lds[i] = w_rbf2[i];
    __syncthreads();

    f32x4 acc[8];
    #pragma unroll
    for (int n = 0; n < 8; ++n) acc[n] = f32x4{0.f, 0.f, 0.f, 0.f};

    stage8k(wkj_i + 8192, slotB, lane, wid);
    mfma_ks<8>(aH[0], aL[0], slotA, acol, kq, acc); __syncthreads();
    stage8k(wkj_i + 16384, slotA, lane, wid);
    mfma_ks<8>(aH[1], aL[1], slotB, acol, kq, acc); __syncthreads();
    stage8k(wkj_i + 24576, slotB, lane, wid);
    mfma_ks<8>(aH[2], aL[2], slotA, acol, kq, acc); __syncthreads();
    stage4k(wdn_i, slotA, lane, wid);
    mfma_ks<8>(aH[3], aL[3], slotB, acol, kq, acc); __syncthreads();

    #pragma unroll
    for (int n = 0; n < 8; ++n) {
        const int c = n * 16 + acol;
        float w2c[8];
        #pragma unroll
        for (int p = 0; p < 8; ++p) w2c[p] = w2_lds[p * 128 + c];
        #pragma unroll
        for (int r = 0; r < 4; ++r) {
            float s = e1a[r][0] * w2c[0];
            s = fmaf(e1a[r][1], w2c[1], s);
            s = fmaf(e1a[r][2], w2c[2], s);
            s = fmaf(e1a[r][3], w2c[3], s);
            s = fmaf(e1b[r][0], w2c[4], s);
            s = fmaf(e1b[r][1], w2c[5], s);
            s = fmaf(e1b[r][2], w2c[6], s);
            s = fmaf(e1b[r][3], w2c[7], s);
            t_lds[(wid * 16 + kq * 4 + r) * TPITCH + c] = silu_f(acc[n][r] + bv[n]) * s;
        }
    }
    __syncthreads();

    f32x4 acc2[4];
    #pragma unroll
    for (int n = 0; n < 4; ++n) acc2[n] = f32x4{0.f, 0.f, 0.f, 0.f};
    const int rb = (wid * 16 + acol) * TPITCH;

    f16x8 tH[4], tL[4];
    #pragma unroll
    for (int q = 0; q < 4; ++q) tfrag(t_lds, rb, q, kq, tH[q], tL[q]);

    stage4k(wdn_i + 4096, slotB, lane, wid);
    mfma_ks<4>(tH[0], tL[0], slotA, acol, kq, acc2); __syncthreads();
    stage4k(wdn_i + 8192, slotA, lane, wid);
    mfma_ks<4>(tH[1], tL[1], slotB, acol, kq, acc2); __syncthreads();
    stage4k(wdn_i + 12288, slotB, lane, wid);
    mfma_ks<4>(tH[2], tL[2], slotA, acol, kq, acc2); __syncthreads();
    mfma_ks<4>(tH[3], tL[3], slotB, acol, kq, acc2);

    #pragma unroll
    for (int n = 0; n < 4; ++n) {
        const int c = n * 16 + acol;
        #pragma unroll
        for (int r = 0; r < 4; ++r) {
            const int ge = rowW + kq * 4 + r;
            if (ge < E) W3[(size_t)ge * 64 + c] = silu_f(acc2[n][r]);
        }
    }
}

// ---------------- kbig: h0 -> res1 -> w_bs+skip -> res2 -> res3 (9 GEMMs) ---
struct KBigArgs {
    const float* x; const float* W4; float* out;
    const char *wji, *wup, *r1w1, *r1w2, *wbs, *r2w1, *r2w2, *r3w1, *r3w2;
    const float *bji, *r1b1, *r1b2, *bbs, *r2b1, *r2b2, *r3b1, *r3b2;
    int E;
};

__launch_bounds__(256, 3)
__global__ void kbig_kernel(KBigArgs A_)
{
    __shared__ _Float16 slotA[4096], slotB[4096];
    __shared__ float t_lds[64 * TPITCH];
    const int tid = threadIdx.x, lane = tid & 63, wid = tid >> 6;
    const int acol = lane & 15, kq = lane >> 4;
    const int rowW = blockIdx.x * 64 + wid * 16;
    const int arow = rowW + acol;
    const int E = A_.E;
    const bool av = arow < E;
    const int rb = (wid * 16 + acol) * TPITCH;

    stage8k(A_.wji, slotA, lane, wid);

    const float* xr = A_.x + (size_t)arow * 128;
    const float* wr = A_.W4 + (size_t)arow * 64;
    f16x8 aH[4], aL[4], uH[2], uL[2];
    #pragma unroll
    for (int ks = 0; ks < 4; ++ks) {
        f32x4 a0 = f32x4{0.f, 0.f, 0.f, 0.f}, a1 = f32x4{0.f, 0.f, 0.f, 0.f};
        if (av) { a0 = *(const f32x4*)&xr[ks * 32 + kq * 8];
                  a1 = *(const f32x4*)&xr[ks * 32 + kq * 8 + 4]; }
        split44h(a0, a1, aH[ks], aL[ks]);
    }
    #pragma unroll
    for (int ks = 0; ks < 2; ++ks) {
        f32x4 u0 = f32x4{0.f, 0.f, 0.f, 0.f}, u1 = f32x4{0.f, 0.f, 0.f, 0.f};
        if (av) { u0 = *(const f32x4*)&wr[ks * 32 + kq * 8];
                  u1 = *(const f32x4*)&wr[ks * 32 + kq * 8 + 4]; }
        split44h(u0, u1, uH[ks], uL[ks]);
    }
    __syncthreads();

    f32x4 acc[8];
    #pragma unroll
    for (int n = 0; n < 8; ++n) acc[n] = f32x4{0.f, 0.f, 0.f, 0.f};

    // GEMM1: x @ w_ji
    stage8k(A_.wji + 8192, slotB, lane, wid);
    mfma_ks<8>(aH[0], aL[0], slotA, acol, kq, acc); __syncthreads();
    stage8k(A_.wji + 16384, slotA, lane, wid);
    mfma_ks<8>(aH[1], aL[1], slotB, acol, kq, acc); __syncthreads();
    stage8k(A_.wji + 24576, slotB, lane, wid);
    mfma_ks<8>(aH[2], aL[2], slotA, acol, kq, acc); __syncthreads();
    stage8k(A_.wup, slotA, lane, wid);
    mfma_ks<8>(aH[3], aL[3], slotB, acol, kq, acc); __syncthreads();

    float res[8][4];
    #pragma unroll
    for (int n = 0; n < 8; ++n) {
        const float bv = A_.bji[n * 16 + acol];
        #pragma unroll
        for (int r = 0; r < 4; ++r) { res[n][r] = silu_f(acc[n][r] + bv); acc[n][r] = 0.f; }
    }

    // GEMM2: W4 @ w_up (K=64)
    stage8k(A_.wup + 8192, slotB, lane, wid);
    mfma_ks<8>(uH[0], uL[0], slotA, acol, kq, acc); __syncthreads();
    stage8k(A_.r1w1, slotA, lane, wid);
    mfma_ks<8>(uH[1], uL[1], slotB, acol, kq, acc); __syncthreads();

    #pragma unroll
    for (int n = 0; n < 8; ++n) {
        const int c = n * 16 + acol;
        #pragma unroll
        for (int r = 0; r < 4; ++r) {
            res[n][r] += silu_f(acc[n][r]);                     // h0
            t_lds[(wid * 16 + kq * 4 + r) * TPITCH + c] = res[n][r];
            acc[n][r] = 0.f;
        }
    }
    __syncthreads();

    // GEMM3: h0 @ r1w1 -> t1
    tgemm4(A_.r1w1, A_.r1w2, slotA, slotB, t_lds, rb, kq, acol, lane, wid, acc);
    #pragma unroll
    for (int n = 0; n < 8; ++n) {
        const float bv = A_.r1b1[n * 16 + acol];
        const int c = n * 16 + acol;
        #pragma unroll
        for (int r = 0; r < 4; ++r) {
            t_lds[(wid * 16 + kq * 4 + r) * TPITCH + c] = silu_f(acc[n][r] + bv);
            acc[n][r] = 0.f;
        }
    }
    __syncthreads();

    // GEMM4: t1 @ r1w2 -> t2 = h0 + silu(.)
    tgemm4(A_.r1w2, A_.wbs, slotA, slotB, t_lds, rb, kq, acol, lane, wid, acc);
    #pragma unroll
    for (int n = 0; n < 8; ++n) {
        const float bv = A_.r1b2[n * 16 + acol];
        const int c = n * 16 + acol;
        #pragma unroll
        for (int r = 0; r < 4; ++r) {
            t_lds[(wid * 16 + kq * 4 + r) * TPITCH + c] = res[n][r] + silu_f(acc[n][r] + bv);
            acc[n][r] = 0.f;
        }
    }
    __syncthreads();

    // GEMM5: t2 @ w_bs -> h2 = silu(.) + x
    tgemm4(A_.wbs, A_.r2w1, slotA, slotB, t_lds, rb, kq, acol, lane, wid, acc);
    #pragma unroll
    for (int n = 0; n < 8; ++n) {
        const float bv = A_.bbs[n * 16 + acol];
        const int c = n * 16 + acol;
        #pragma unroll
        for (int r = 0; r < 4; ++r) {
            const int ge = rowW + kq * 4 + r;
            const float xv = (ge < E) ? A_.x[(size_t)ge * 128 + c] : 0.f;
            res[n][r] = silu_f(acc[n][r] + bv) + xv;            // h2
            t_lds[(wid * 16 + kq * 4 + r) * TPITCH + c] = res[n][r];
            acc[n][r] = 0.f;
        }
    }
    __syncthreads();

    // GEMM6: h2 @ r2w1 -> t3
    tgemm4(A_.r2w1, A_.r2w2, slotA, slotB, t_lds, rb, kq, acol, lane, wid, acc);
    #pragma unroll
    for (int n = 0; n < 8; ++n) {
        const float bv = A_.r2b1[n * 16 + acol];
        const int c = n * 16 + acol;
        #pragma unroll
        for (int r = 0; r < 4; ++r) {
            t_lds[(wid * 16 + kq * 4 + r) * TPITCH + c] = silu_f(acc[n][r] + bv);
            acc[n][r] = 0.f;
        }
    }
    __syncthreads();

    // GEMM7: t3 @ r2w2 -> h3 = h2 + silu(.)
    tgemm4(A_.r2w2, A_.r3w1, slotA, slotB, t_lds, rb, kq, acol, lane, wid, acc);
    #pragma unroll
    for (int n = 0; n < 8; ++n) {
        const float bv = A_.r2b2[n * 16 + acol];
        const int c = n * 16 + acol;
        #pragma unroll
        for (int r = 0; r < 4; ++r) {
            res[n][r] += silu_f(acc[n][r] + bv);                // h3
            t_lds[(wid * 16 + kq * 4 + r) * TPITCH + c] = res[n][r];
            acc[n][r] = 0.f;
        }
    }
    __syncthreads();

    // GEMM8: h3 @ r3w1 -> t4
    tgemm4(A_.r3w1, A_.r3w2, slotA, slotB, t_lds, rb, kq, acol, lane, wid, acc);
    #pragma unroll
    for (int n = 0; n < 8; ++n) {
        const float bv = A_.r3b1[n * 16 + acol];
        const int c = n * 16 + acol;
        #pragma unroll
        for (int r = 0; r < 4; ++r) {
            t_lds[(wid * 16 + kq * 4 + r) * TPITCH + c] = silu_f(acc[n][r] + bv);
            acc[n][r] = 0.f;
        }
    }
    __syncthreads();

    // GEMM9: t4 @ r3w2 -> out = h3 + silu(.)
    tgemm4(A_.r3w2, nullptr, slotA, slotB, t_lds, rb, kq, acol, lane, wid, acc);
    #pragma unroll
    for (int n = 0; n < 8; ++n) {
        const float bv = A_.r3b2[n * 16 + acol];
        const int c = n * 16 + acol;
        #pragma unroll
        for (int r = 0; r < 4; ++r) {
            const int ge = rowW + kq * 4 + r;
            if (ge < E)
                A_.out[(size_t)ge * 128 + c] = res[n][r] + silu_f(acc[n][r] + bv);
        }
    }
}

// ---------------------------------------------------------------------------

extern "C" void kernel_launch(void* const* d_in, const int* in_sizes, int n_in,
                              void* d_out, int out_size, void* d_ws, size_t ws_size,
                              hipStream_t stream)
{
    const float* x      = (const float*)d_in[0];
    const float* rbf    = (const float*)d_in[1];
    const float* sbf    = (const float*)d_in[2];
    const int*   idx_kj = (const int*)d_in[3];
    const int*   idx_ji = (const int*)d_in[4];
    const float* w_rbf1 = (const float*)d_in[5];
    const float* w_rbf2 = (const float*)d_in[6];
    const float* w_sbf1 = (const float*)d_in[7];
    const float* w_sbf2 = (const float*)d_in[8];
    const float* w_kj   = (const float*)d_in[9];
    const float* b_kj   = (const float*)d_in[10];
    const float* w_ji   = (const float*)d_in[11];
    const float* b_ji   = (const float*)d_in[12];
    const float* w_down = (const float*)d_in[13];
    const float* w_up   = (const float*)d_in[14];
    const float* r1w1   = (const float*)d_in[15];
    const float* r1b1   = (const float*)d_in[16];
    const float* r1w2   = (const float*)d_in[17];
    const float* r1b2   = (const float*)d_in[18];
    const float* w_bs   = (const float*)d_in[19];
    const float* b_bs   = (const float*)d_in[20];
    const float* r2w1   = (const float*)d_in[21];
    const float* r2b1   = (const float*)d_in[22];
    const float* r2w2   = (const float*)d_in[23];
    const float* r2b2   = (const float*)d_in[24];
    const float* r3w1   = (const float*)d_in[25];
    const float* r3b1   = (const float*)d_in[26];
    const float* r3w2   = (const float*)d_in[27];
    const float* r3b2   = (const float*)d_in[28];

    const int E = in_sizes[0] / 128;
    const int T = in_sizes[2] / 42;

    float* OUT = (float*)d_out;
    float* W3  = (float*)((char*)d_ws + (size_t)E * 128 * 4);         // [E,64]
    float* W4  = (float*)((char*)d_ws + (size_t)E * 128 * 4
                                      + (size_t)E * 64 * 4);          // [E,64]

    int*   cnt      = (int*)d_ws;                            // [E]
    int*   offsets  = cnt + (E + 64);                        // [E+1]
    int*   partial  = offsets + (E + 64);                    // [<=1024]
    int*   blockoff = partial + 1024;                        // [<=1024]
    float* E1p      = (float*)((char*)d_ws + (4u << 20));    // [T,8]   96 MB
    int*   kjp      = (int*)((char*)d_ws + (102u << 20));    // [T]     12 MB
    float* re1      = (float*)((char*)d_ws + (116u << 20));  // [E,8]  9.6 MB
    char*  wimg     = (char*)d_ws + (130u << 20);            // 320 KB fp16 images
    int*   rank     = (int*)((char*)d_ws + (134u << 20));    // [T]     12 MB

    char* wkj_i  = wimg;
    char* wji_i  = wimg + 32768;
    char* wdn_i  = wimg + 65536;    // 16 KB (128x64)
    char* wup_i  = wimg + 81920;    // 16 KB (64x128)
    char* r1w1_i = wimg + 98304;
    char* r1w2_i = wimg + 131072;
    char* wbs_i  = wimg + 163840;
    char* r2w1_i = wimg + 196608;
    char* r2w2_i = wimg + 229376;
    char* r3w1_i = wimg + 262144;
    char* r3w2_i = wimg + 294912;

    WPrepArgs pa;
    pa.w[0]  = {w_kj,   wkj_i,  128, 128};
    pa.w[1]  = {w_ji,   wji_i,  128, 128};
    pa.w[2]  = {w_down, wdn_i,  128,  64};
    pa.w[3]  = {w_up,   wup_i,   64, 128};
    pa.w[4]  = {r1w1,   r1w1_i, 128, 128};
    pa.w[5]  = {r1w2,   r1w2_i, 128, 128};
    pa.w[6]  = {w_bs,   wbs_i,  128, 128};
    pa.w[7]  = {r2w1,   r2w1_i, 128, 128};
    pa.w[8]  = {r2w2,   r2w2_i, 128, 128};
    pa.w[9]  = {r3w1,   r3w1_i, 128, 128};
    pa.w[10] = {r3w2,   r3w2_i, 128, 128};

    const dim3 b256(256);
    const int gB  = (E + 63) / 64;
    const int gT  = (T + 255) / 256;
    const int gT4 = (T + 1023) / 1024;
    const int NB  = (E + 1023) / 1024;
    const int gE4 = (E + 3) / 4;
    const int gR  = (E * 8 + 255) / 256;

    wprep_kernel<<<dim3(4, 11), b256, 0, stream>>>(pa);
    rbf1_kernel<<<gR, b256, 0, stream>>>(rbf, w_rbf1, re1, E);
    hipMemsetAsync(cnt, 0, (size_t)E * 4, stream);
    count_rank_kernel<<<gT4, b256, 0, stream>>>(idx_ji, cnt, rank, T);
    scan_partial_kernel<<<NB, b256, 0, stream>>>(cnt, partial, E);
    scan_block_kernel<<<1, b256, 0, stream>>>(partial, blockoff, NB, offsets, E);
    scan_final_kernel<<<NB, b256, 0, stream>>>(cnt, blockoff, offsets, E);
    e1fill_kernel<<<gT, b256, 0, stream>>>(sbf, w_sbf1, idx_ji, idx_kj, rank, offsets, E1p, kjp, T);

    k1_kernel<<<gB, b256, 0, stream>>>(x, wkj_i, b_kj, re1, w_rbf2, wdn_i, W3, E);
    gather_kernel<<<gE4, b256, 0, stream>>>(E1p, kjp, w_sbf2, offsets, W3, W4, E);

    KBigArgs ka;
    ka.x = x; ka.W4 = W4; ka.out = OUT;
    ka.wji = wji_i; ka.wup = wup_i; ka.r1w1 = r1w1_i; ka.r1w2 = r1w2_i; ka.wbs = wbs_i;
    ka.r2w1 = r2w1_i; ka.r2w2 = r2w2_i; ka.r3w1 = r3w1_i; ka.r3w2 = r3w2_i;
    ka.bji = b_ji; ka.r1b1 = r1b1; ka.r1b2 = r1b2; ka.bbs = b_bs;
    ka.r2b1 = r2b1; ka.r2b2 = r2b2; ka.r3b1 = r3b1; ka.r3b2 = r3b2;
    ka.E = E;
    kbig_kernel<<<gB, b256, 0, stream>>>(ka);
}

// Round 15
// 1013.664 us; speedup vs baseline: 1.4389x; 1.0059x over previous
//
#include <hip/hip_runtime.h>
#include <hip/hip_bf16.h>

// ---------------------------------------------------------------------------
// DimeNet++ interaction block, round 15:
//   Round-14 (split-fp16 2-pass, 3 blocks/CU) + corrected LDS swizzle:
//   chunk swizzle (ch ^ ((c>>1)&3)) for the 64 B col stride -- the round-14
//   (ch ^ (c&3)) aliased with the c&1 bank bit => 4-way conflict (24.6M).
//   Now 8 distinct 16B slots per quarter-phase = conflict-free.
// ---------------------------------------------------------------------------

typedef __attribute__((ext_vector_type(8))) _Float16 f16x8;
typedef __attribute__((ext_vector_type(4))) float f32x4;

__device__ __forceinline__ float silu_f(float v) {
    return v * __builtin_amdgcn_rcpf(1.0f + __expf(-v));
}

// fp32x8 -> fp16 hi + exact residual lo
__device__ __forceinline__ void split44h(f32x4 a, f32x4 b, f16x8& hi, f16x8& lo) {
    float f[8] = {a[0], a[1], a[2], a[3], b[0], b[1], b[2], b[3]};
    #pragma unroll
    for (int j = 0; j < 8; ++j) {
        const _Float16 h = (_Float16)f[j];
        hi[j] = h;
        lo[j] = (_Float16)(f[j] - (float)h);
    }
}

__device__ __forceinline__ void gll16(const void* g, void* l) {
    __builtin_amdgcn_global_load_lds((const __attribute__((address_space(1))) void*)g,
                                     (__attribute__((address_space(3))) void*)l, 16, 0, 0);
}
// stage an 8 KB slab (N=128) with 4 waves
__device__ __forceinline__ void stage8k(const char* g, _Float16* l, int lane, int wid) {
    #pragma unroll
    for (int i = 0; i < 2; ++i) {
        const int off = ((i * 4 + wid) << 10);
        gll16(g + off + lane * 16, (char*)l + off);
    }
}
// stage a 4 KB slab (N=64) with 4 waves
__device__ __forceinline__ void stage4k(const char* g, _Float16* l, int lane, int wid) {
    const int off = (wid << 10);
    gll16(g + off + lane * 16, (char*)l + off);
}

// one 32-k step, 2-pass split-fp16 MFMA over NF col-frags
// slab layout: col c (64 B), chunk s stored at (s ^ ((c>>1)&3)); read chunk kq
template<int NF>
__device__ __forceinline__ void mfma_ks(f16x8 ah, f16x8 al, const _Float16* slot,
                                        int acol, int kq, f32x4* acc) {
    #pragma unroll
    for (int n = 0; n < NF; ++n) {
        const int c = n * 16 + acol;
        const int sw = (kq ^ ((c >> 1) & 3)) << 3;
        const f16x8 bh = *(const f16x8*)&slot[c * 32 + sw];
        acc[n] = __builtin_amdgcn_mfma_f32_16x16x32_f16(ah, bh, acc[n], 0, 0, 0);
        acc[n] = __builtin_amdgcn_mfma_f32_16x16x32_f16(al, bh, acc[n], 0, 0, 0);
    }
}

// read + split one t_lds A-fragment
__device__ __forceinline__ void tfrag(const float* tl, int rb, int q, int kq,
                                      f16x8& Ah, f16x8& Al) {
    const f32x4 ta = *(const f32x4*)&tl[rb + q * 32 + kq * 8];
    const f32x4 tb = *(const f32x4*)&tl[rb + q * 32 + kq * 8 + 4];
    split44h(ta, tb, Ah, Al);
}

// 4-phase 128-k GEMM from t_lds (N=128, 8 KB slabs at img+8192*i)
__device__ __forceinline__ void tgemm4(const char* img, const char* imgnext,
                                       _Float16* sA, _Float16* sB, const float* tl, int rb,
                                       int kq, int acol, int lane, int wid, f32x4* acc)
{
    f16x8 Ah[4], Al[4];
    #pragma unroll
    for (int q = 0; q < 4; ++q) tfrag(tl, rb, q, kq, Ah[q], Al[q]);

    stage8k(img + 8192, sB, lane, wid);
    mfma_ks<8>(Ah[0], Al[0], sA, acol, kq, acc); __syncthreads();
    stage8k(img + 16384, sA, lane, wid);
    mfma_ks<8>(Ah[1], Al[1], sB, acol, kq, acc); __syncthreads();
    stage8k(img + 24576, sB, lane, wid);
    mfma_ks<8>(Ah[2], Al[2], sA, acol, kq, acc); __syncthreads();
    if (imgnext) stage8k(imgnext, sA, lane, wid);
    mfma_ks<8>(Ah[3], Al[3], sB, acol, kq, acc); __syncthreads();
}

#define TPITCH 132

// ---------------- weight pre-conversion (fp16, swizzled image) --------------
struct WDesc { const float* src; char* dst; int K; int N; };
struct WPrepArgs { WDesc w[11]; };

__global__ void wprep_kernel(WPrepArgs args) {
    const WDesc d = args.w[blockIdx.y];
    const int h = blockIdx.x;
    if (h * 32 >= d.K) return;
    char* slab = d.dst + (size_t)h * d.N * 64;
    for (int idx = threadIdx.x; idx < d.N * 4; idx += 256) {
        const int c = idx >> 2, ch = idx & 3;
        f16x8 v;
        #pragma unroll
        for (int j = 0; j < 8; ++j)
            v[j] = (_Float16)d.src[(size_t)(h * 32 + ch * 8 + j) * d.N + c];
        *(f16x8*)(slab + c * 64 + ((ch ^ ((c >> 1) & 3)) << 4)) = v;
    }
}

// ---------------- prologue / CSR --------------------------------------------

__global__ void rbf1_kernel(const float* __restrict__ rbf, const float* __restrict__ w_rbf1,
                            float* __restrict__ re1, int E) {
    const int i = blockIdx.x * 256 + threadIdx.x;
    const int e = i >> 3, p = i & 7;
    if (e < E) {
        float s = 0.f;
        #pragma unroll
        for (int q = 0; q < 6; ++q) s = fmaf(rbf[e * 6 + q], w_rbf1[q * 8 + p], s);
        re1[i] = s;
    }
}

__global__ void count_rank_kernel(const int* __restrict__ idx_ji, int* __restrict__ cnt,
                                  int* __restrict__ rank, int T) {
    const int i = (blockIdx.x * 256 + threadIdx.x) * 4;
    if (i + 3 < T) {
        const int4 j = *(const int4*)&idx_ji[i];
        int4 r;
        r.x = atomicAdd(&cnt[j.x], 1);
        r.y = atomicAdd(&cnt[j.y], 1);
        r.z = atomicAdd(&cnt[j.z], 1);
        r.w = atomicAdd(&cnt[j.w], 1);
        *(int4*)&rank[i] = r;
    } else {
        for (int k = i; k < T; ++k) rank[k] = atomicAdd(&cnt[idx_ji[k]], 1);
    }
}

__global__ void scan_partial_kernel(const int* __restrict__ cnt, int* __restrict__ partial, int E) {
    __shared__ int red[256];
    const int tid = threadIdx.x;
    const int base = blockIdx.x * 1024 + tid * 4;
    int s = 0;
    #pragma unroll
    for (int i = 0; i < 4; ++i) { const int g = base + i; if (g < E) s += cnt[g]; }
    red[tid] = s;
    __syncthreads();
    for (int off = 128; off > 0; off >>= 1) {
        if (tid < off) red[tid] += red[tid + off];
        __syncthreads();
    }
    if (tid == 0) partial[blockIdx.x] = red[0];
}

__global__ void scan_block_kernel(const int* __restrict__ partial, int* __restrict__ blockoff,
                                  int NB, int* offsets, int E) {
    __shared__ int red[256];
    const int tid = threadIdx.x;
    int v[4]; int s = 0;
    #pragma unroll
    for (int i = 0; i < 4; ++i) { const int g = tid * 4 + i; v[i] = (g < NB) ? partial[g] : 0; s += v[i]; }
    red[tid] = s;
    __syncthreads();
    for (int off = 1; off < 256; off <<= 1) {
        const int add = (tid >= off) ? red[tid - off] : 0;
        __syncthreads();
        red[tid] += add;
        __syncthreads();
    }
    int excl = (tid == 0) ? 0 : red[tid - 1];
    #pragma unroll
    for (int i = 0; i < 4; ++i) { const int g = tid * 4 + i; if (g < NB) blockoff[g] = excl; excl += v[i]; }
    if (tid == 255) offsets[E] = red[255];
}

__global__ void scan_final_kernel(const int* __restrict__ cnt, const int* __restrict__ blockoff,
                                  int* __restrict__ offsets, int E) {
    __shared__ int red[256];
    const int tid = threadIdx.x;
    const int base = blockIdx.x * 1024 + tid * 4;
    int v[4]; int s = 0;
    #pragma unroll
    for (int i = 0; i < 4; ++i) { const int g = base + i; v[i] = (g < E) ? cnt[g] : 0; s += v[i]; }
    red[tid] = s;
    __syncthreads();
    for (int off = 1; off < 256; off <<= 1) {
        const int add = (tid >= off) ? red[tid - off] : 0;
        __syncthreads();
        red[tid] += add;
        __syncthreads();
    }
    int run = blockoff[blockIdx.x] + ((tid == 0) ? 0 : red[tid - 1]);
    #pragma unroll
    for (int i = 0; i < 4; ++i) {
        const int g = base + i;
        if (g < E) offsets[g] = run;
        run += v[i];
    }
}

__launch_bounds__(256, 3)
__global__ void e1fill_kernel(const float* __restrict__ sbf, const float* __restrict__ w_sbf1,
                              const int* __restrict__ idx_ji, const int* __restrict__ idx_kj,
                              const int* __restrict__ rank, const int* __restrict__ offsets,
                              float* __restrict__ E1p, int* __restrict__ kjp, int T)
{
    __shared__ float s_lds[256 * 43];
    const int tid = threadIdx.x;
    const long long t0 = (long long)blockIdx.x * 256;
    const int nrow = min(256, (int)(T - t0));
    const int nel  = nrow * 42;
    const float* base = sbf + t0 * 42;

    for (int i = tid * 4; i + 3 < nel; i += 1024) {
        const float4 v = *(const float4*)&base[i];
        s_lds[(i + 0) + (i + 0) / 42] = v.x;
        s_lds[(i + 1) + (i + 1) / 42] = v.y;
        s_lds[(i + 2) + (i + 2) / 42] = v.z;
        s_lds[(i + 3) + (i + 3) / 42] = v.w;
    }
    const int tail0 = nel & ~3;
    if (tid < nel - tail0) { const int g = tail0 + tid; s_lds[g + g / 42] = base[g]; }
    __syncthreads();

    const int t = (int)t0 + tid;
    if (t >= T) return;
    const float* srow = &s_lds[tid * 43];
    float e1[8] = {0.f, 0.f, 0.f, 0.f, 0.f, 0.f, 0.f, 0.f};
    #pragma unroll
    for (int q = 0; q < 42; ++q) {
        const float s = srow[q];
        #pragma unroll
        for (int p = 0; p < 8; ++p) e1[p] = fmaf(s, w_sbf1[q * 8 + p], e1[p]);
    }
    const int ji  = idx_ji[t];
    const int pos = offsets[ji] + rank[t];
    *(float4*)&E1p[(size_t)pos * 8]     = *(float4*)&e1[0];
    *(float4*)&E1p[(size_t)pos * 8 + 4] = *(float4*)&e1[4];
    kjp[pos] = idx_kj[t];
}

// ---------------- gather: depth-1 pipeline incl. the xkjd row gather --------
__launch_bounds__(256, 4)
__global__ void gather_kernel(const float* __restrict__ E1p, const int* __restrict__ kjp,
                              const float* __restrict__ w_sbf2, const int* __restrict__ offsets,
                              const float* __restrict__ xkjd, float* __restrict__ agg, int E)
{
    const int tid  = threadIdx.x;
    const int lane = tid & 63;
    const int e    = blockIdx.x * 4 + (tid >> 6);

    float w2[8];
    #pragma unroll
    for (int p = 0; p < 8; ++p) w2[p] = w_sbf2[p * 64 + lane];

    if (e >= E) return;
    const int j0 = __builtin_amdgcn_readfirstlane(offsets[e]);
    const int j1 = __builtin_amdgcn_readfirstlane(offsets[e + 1]);

    float acc = 0.f;
    if (j0 < j1) {
        int kj = __builtin_amdgcn_readfirstlane(kjp[j0]);
        float4 ea = *(const float4*)&E1p[(size_t)j0 * 8];
        float4 eb = *(const float4*)&E1p[(size_t)j0 * 8 + 4];
        float xv = xkjd[(size_t)kj * 64 + lane];
        for (int j = j0; j < j1; ++j) {
            float xn = 0.f; float4 ean = {}, ebn = {};
            if (j + 1 < j1) {
                const int kn = __builtin_amdgcn_readfirstlane(kjp[j + 1]);
                ean = *(const float4*)&E1p[(size_t)(j + 1) * 8];
                ebn = *(const float4*)&E1p[(size_t)(j + 1) * 8 + 4];
                xn  = xkjd[(size_t)kn * 64 + lane];
            }
            float sv = ea.x * w2[0];
            sv = fmaf(ea.y, w2[1], sv);
            sv = fmaf(ea.z, w2[2], sv);
            sv = fmaf(ea.w, w2[3], sv);
            sv = fmaf(eb.x, w2[4], sv);
            sv = fmaf(eb.y, w2[5], sv);
            sv = fmaf(eb.z, w2[6], sv);
            sv = fmaf(eb.w, w2[7], sv);
            acc = fmaf(xv, sv, acc);
            ea = ean; eb = ebn; xv = xn;
        }
    }
    agg[(size_t)e * 64 + lane] = acc;
}

// ---------------- K1: W3 = silu((silu(x@w_kj+b)*rbf_e)@w_down) --------------
__launch_bounds__(256, 3)
__global__ void k1_kernel(const float* __restrict__ x, const char* __restrict__ wkj_i,
                          const float* __restrict__ b_kj, const float* __restrict__ re1,
                          const float* __restrict__ w_rbf2, const char* __restrict__ wdn_i,
                          float* __restrict__ W3, int E)
{
    __shared__ _Float16 slotA[4096], slotB[4096];
    __shared__ float t_lds[64 * TPITCH];
    __shared__ float w2_lds[8 * 128];
    const int tid = threadIdx.x, lane = tid & 63, wid = tid >> 6;
    const int acol = lane & 15, kq = lane >> 4;
    const int rowW = blockIdx.x * 64 + wid * 16;
    const int arow = rowW + acol;
    const bool av = arow < E;

    stage8k(wkj_i, slotA, lane, wid);
    const float* xr = x + (size_t)arow * 128;
    f16x8 aH[4], aL[4];
    #pragma unroll
    for (int ks = 0; ks < 4; ++ks) {
        f32x4 a0 = f32x4{0.f, 0.f, 0.f, 0.f}, a1 = f32x4{0.f, 0.f, 0.f, 0.f};
        if (av) { a0 = *(const f32x4*)&xr[ks * 32 + kq * 8];
                  a1 = *(const f32x4*)&xr[ks * 32 + kq * 8 + 4]; }
        split44h(a0, a1, aH[ks], aL[ks]);
    }
    float bv[8];
    #pragma unroll
    for (int n = 0; n < 8; ++n) bv[n] = b_kj[n * 16 + acol];
    f32x4 e1a[4], e1b[4];
    #pragma unroll
    for (int r = 0; r < 4; ++r) {
        const int ge = rowW + kq * 4 + r;
        e1a[r] = f32x4{0.f, 0.f, 0.f, 0.f}; e1b[r] = f32x4{0.f, 0.f, 0.f, 0.f};
        if (ge < E) { e1a[r] = *(const f32x4*)&re1[(size_t)ge * 8];
                      e1b[r] = *(const f32x4*)&re1[(size_t)ge * 8 + 4]; }
    }
    for (int i = tid; i < 1024; i += 256) w2_lds[i] = w_rbf2[i];
    __syncthreads();

    f32x4 acc[8];
    #pragma unroll
    for (int n = 0; n < 8; ++n) acc[n] = f32x4{0.f, 0.f, 0.f, 0.f};

    stage8k(wkj_i + 8192, slotB, lane, wid);
    mfma_ks<8>(aH[0], aL[0], slotA, acol, kq, acc); __syncthreads();
    stage8k(wkj_i + 16384, slotA, lane, wid);
    mfma_ks<8>(aH[1], aL[1], slotB, acol, kq, acc); __syncthreads();
    stage8k(wkj_i + 24576, slotB, lane, wid);
    mfma_ks<8>(aH[2], aL[2], slotA, acol, kq, acc); __syncthreads();
    stage4k(wdn_i, slotA, lane, wid);
    mfma_ks<8>(aH[3], aL[3], slotB, acol, kq, acc); __syncthreads();

    #pragma unroll
    for (int n = 0; n < 8; ++n) {
        const int c = n * 16 + acol;
        float w2c[8];
        #pragma unroll
        for (int p = 0; p < 8; ++p) w2c[p] = w2_lds[p * 128 + c];
        #pragma unroll
        for (int r = 0; r < 4; ++r) {
            float s = e1a[r][0] * w2c[0];
            s = fmaf(e1a[r][1], w2c[1], s);
            s = fmaf(e1a[r][2], w2c[2], s);
            s = fmaf(e1a[r][3], w2c[3], s);
            s = fmaf(e1b[r][0], w2c[4], s);
            s = fmaf(e1b[r][1], w2c[5], s);
            s = fmaf(e1b[r][2], w2c[6], s);
            s = fmaf(e1b[r][3], w2c[7], s);
            t_lds[(wid * 16 + kq * 4 + r) * TPITCH + c] = silu_f(acc[n][r] + bv[n]) * s;
        }
    }
    __syncthreads();

    f32x4 acc2[4];
    #pragma unroll
    for (int n = 0; n < 4; ++n) acc2[n] = f32x4{0.f, 0.f, 0.f, 0.f};
    const int rb = (wid * 16 + acol) * TPITCH;

    f16x8 tH[4], tL[4];
    #pragma unroll
    for (int q = 0; q < 4; ++q) tfrag(t_lds, rb, q, kq, tH[q], tL[q]);

    stage4k(wdn_i + 4096, slotB, lane, wid);
    mfma_ks<4>(tH[0], tL[0], slotA, acol, kq, acc2); __syncthreads();
    stage4k(wdn_i + 8192, slotA, lane, wid);
    mfma_ks<4>(tH[1], tL[1], slotB, acol, kq, acc2); __syncthreads();
    stage4k(wdn_i + 12288, slotB, lane, wid);
    mfma_ks<4>(tH[2], tL[2], slotA, acol, kq, acc2); __syncthreads();
    mfma_ks<4>(tH[3], tL[3], slotB, acol, kq, acc2);

    #pragma unroll
    for (int n = 0; n < 4; ++n) {
        const int c = n * 16 + acol;
        #pragma unroll
        for (int r = 0; r < 4; ++r) {
            const int ge = rowW + kq * 4 + r;
            if (ge < E) W3[(size_t)ge * 64 + c] = silu_f(acc2[n][r]);
        }
    }
}

// ---------------- kbig: h0 -> res1 -> w_bs+skip -> res2 -> res3 (9 GEMMs) ---
struct KBigArgs {
    const float* x; const float* W4; float* out;
    const char *wji, *wup, *r1w1, *r1w2, *wbs, *r2w1, *r2w2, *r3w1, *r3w2;
    const float *bji, *r1b1, *r1b2, *bbs, *r2b1, *r2b2, *r3b1, *r3b2;
    int E;
};

__launch_bounds__(256, 3)
__global__ void kbig_kernel(KBigArgs A_)
{
    __shared__ _Float16 slotA[4096], slotB[4096];
    __shared__ float t_lds[64 * TPITCH];
    const int tid = threadIdx.x, lane = tid & 63, wid = tid >> 6;
    const int acol = lane & 15, kq = lane >> 4;
    const int rowW = blockIdx.x * 64 + wid * 16;
    const int arow = rowW + acol;
    const int E = A_.E;
    const bool av = arow < E;
    const int rb = (wid * 16 + acol) * TPITCH;

    stage8k(A_.wji, slotA, lane, wid);

    const float* xr = A_.x + (size_t)arow * 128;
    const float* wr = A_.W4 + (size_t)arow * 64;
    f16x8 aH[4], aL[4], uH[2], uL[2];
    #pragma unroll
    for (int ks = 0; ks < 4; ++ks) {
        f32x4 a0 = f32x4{0.f, 0.f, 0.f, 0.f}, a1 = f32x4{0.f, 0.f, 0.f, 0.f};
        if (av) { a0 = *(const f32x4*)&xr[ks * 32 + kq * 8];
                  a1 = *(const f32x4*)&xr[ks * 32 + kq * 8 + 4]; }
        split44h(a0, a1, aH[ks], aL[ks]);
    }
    #pragma unroll
    for (int ks = 0; ks < 2; ++ks) {
        f32x4 u0 = f32x4{0.f, 0.f, 0.f, 0.f}, u1 = f32x4{0.f, 0.f, 0.f, 0.f};
        if (av) { u0 = *(const f32x4*)&wr[ks * 32 + kq * 8];
                  u1 = *(const f32x4*)&wr[ks * 32 + kq * 8 + 4]; }
        split44h(u0, u1, uH[ks], uL[ks]);
    }
    __syncthreads();

    f32x4 acc[8];
    #pragma unroll
    for (int n = 0; n < 8; ++n) acc[n] = f32x4{0.f, 0.f, 0.f, 0.f};

    // GEMM1: x @ w_ji
    stage8k(A_.wji + 8192, slotB, lane, wid);
    mfma_ks<8>(aH[0], aL[0], slotA, acol, kq, acc); __syncthreads();
    stage8k(A_.wji + 16384, slotA, lane, wid);
    mfma_ks<8>(aH[1], aL[1], slotB, acol, kq, acc); __syncthreads();
    stage8k(A_.wji + 24576, slotB, lane, wid);
    mfma_ks<8>(aH[2], aL[2], slotA, acol, kq, acc); __syncthreads();
    stage8k(A_.wup, slotA, lane, wid);
    mfma_ks<8>(aH[3], aL[3], slotB, acol, kq, acc); __syncthreads();

    float res[8][4];
    #pragma unroll
    for (int n = 0; n < 8; ++n) {
        const float bv = A_.bji[n * 16 + acol];
        #pragma unroll
        for (int r = 0; r < 4; ++r) { res[n][r] = silu_f(acc[n][r] + bv); acc[n][r] = 0.f; }
    }

    // GEMM2: W4 @ w_up (K=64)
    stage8k(A_.wup + 8192, slotB, lane, wid);
    mfma_ks<8>(uH[0], uL[0], slotA, acol, kq, acc); __syncthreads();
    stage8k(A_.r1w1, slotA, lane, wid);
    mfma_ks<8>(uH[1], uL[1], slotB, acol, kq, acc); __syncthreads();

    #pragma unroll
    for (int n = 0; n < 8; ++n) {
        const int c = n * 16 + acol;
        #pragma unroll
        for (int r = 0; r < 4; ++r) {
            res[n][r] += silu_f(acc[n][r]);                     // h0
            t_lds[(wid * 16 + kq * 4 + r) * TPITCH + c] = res[n][r];
            acc[n][r] = 0.f;
        }
    }
    __syncthreads();

    // GEMM3: h0 @ r1w1 -> t1
    tgemm4(A_.r1w1, A_.r1w2, slotA, slotB, t_lds, rb, kq, acol, lane, wid, acc);
    #pragma unroll
    for (int n = 0; n < 8; ++n) {
        const float bv = A_.r1b1[n * 16 + acol];
        const int c = n * 16 + acol;
        #pragma unroll
        for (int r = 0; r < 4; ++r) {
            t_lds[(wid * 16 + kq * 4 + r) * TPITCH + c] = silu_f(acc[n][r] + bv);
            acc[n][r] = 0.f;
        }
    }
    __syncthreads();

    // GEMM4: t1 @ r1w2 -> t2 = h0 + silu(.)
    tgemm4(A_.r1w2, A_.wbs, slotA, slotB, t_lds, rb, kq, acol, lane, wid, acc);
    #pragma unroll
    for (int n = 0; n < 8; ++n) {
        const float bv = A_.r1b2[n * 16 + acol];
        const int c = n * 16 + acol;
        #pragma unroll
        for (int r = 0; r < 4; ++r) {
            t_lds[(wid * 16 + kq * 4 + r) * TPITCH + c] = res[n][r] + silu_f(acc[n][r] + bv);
            acc[n][r] = 0.f;
        }
    }
    __syncthreads();

    // GEMM5: t2 @ w_bs -> h2 = silu(.) + x
    tgemm4(A_.wbs, A_.r2w1, slotA, slotB, t_lds, rb, kq, acol, lane, wid, acc);
    #pragma unroll
    for (int n = 0; n < 8; ++n) {
        const float bv = A_.bbs[n * 16 + acol];
        const int c = n * 16 + acol;
        #pragma unroll
        for (int r = 0; r < 4; ++r) {
            const int ge = rowW + kq * 4 + r;
            const float xv = (ge < E) ? A_.x[(size_t)ge * 128 + c] : 0.f;
            res[n][r] = silu_f(acc[n][r] + bv) + xv;            // h2
            t_lds[(wid * 16 + kq * 4 + r) * TPITCH + c] = res[n][r];
            acc[n][r] = 0.f;
        }
    }
    __syncthreads();

    // GEMM6: h2 @ r2w1 -> t3
    tgemm4(A_.r2w1, A_.r2w2, slotA, slotB, t_lds, rb, kq, acol, lane, wid, acc);
    #pragma unroll
    for (int n = 0; n < 8; ++n) {
        const float bv = A_.r2b1[n * 16 + acol];
        const int c = n * 16 + acol;
        #pragma unroll
        for (int r = 0; r < 4; ++r) {
            t_lds[(wid * 16 + kq * 4 + r) * TPITCH + c] = silu_f(acc[n][r] + bv);
            acc[n][r] = 0.f;
        }
    }
    __syncthreads();

    // GEMM7: t3 @ r2w2 -> h3 = h2 + silu(.)
    tgemm4(A_.r2w2, A_.r3w1, slotA, slotB, t_lds, rb, kq, acol, lane, wid, acc);
    #pragma unroll
    for (int n = 0; n < 8; ++n) {
        const float bv = A_.r2b2[n * 16 + acol];
        const int c = n * 16 + acol;
        #pragma unroll
        for (int r = 0; r < 4; ++r) {
            res[n][r] += silu_f(acc[n][r] + bv);                // h3
            t_lds[(wid * 16 + kq * 4 + r) * TPITCH + c] = res[n][r];
            acc[n][r] = 0.f;
        }
    }
    __syncthreads();

    // GEMM8: h3 @ r3w1 -> t4
    tgemm4(A_.r3w1, A_.r3w2, slotA, slotB, t_lds, rb, kq, acol, lane, wid, acc);
    #pragma unroll
    for (int n = 0; n < 8; ++n) {
        const float bv = A_.r3b1[n * 16 + acol];
        const int c = n * 16 + acol;
        #pragma unroll
        for (int r = 0; r < 4; ++r) {
            t_lds[(wid * 16 + kq * 4 + r) * TPITCH + c] = silu_f(acc[n][r] + bv);
            acc[n][r] = 0.f;
        }
    }
    __syncthreads();

    // GEMM9: t4 @ r3w2 -> out = h3 + silu(.)
    tgemm4(A_.r3w2, nullptr, slotA, slotB, t_lds, rb, kq, acol, lane, wid, acc);
    #pragma unroll
    for (int n = 0; n < 8; ++n) {
        const float bv = A_.r3b2[n * 16 + acol];
        const int c = n * 16 + acol;
        #pragma unroll
        for (int r = 0; r < 4; ++r) {
            const int ge = rowW + kq * 4 + r;
            if (ge < E)
                A_.out[(size_t)ge * 128 + c] = res[n][r] + silu_f(acc[n][r] + bv);
        }
    }
}

// ---------------------------------------------------------------------------

extern "C" void kernel_launch(void* const* d_in, const int* in_sizes, int n_in,
                              void* d_out, int out_size, void* d_ws, size_t ws_size,
                              hipStream_t stream)
{
    const float* x      = (const float*)d_in[0];
    const float* rbf    = (const float*)d_in[1];
    const float* sbf    = (const float*)d_in[2];
    const int*   idx_kj = (const int*)d_in[3];
    const int*   idx_ji = (const int*)d_in[4];
    const float* w_rbf1 = (const float*)d_in[5];
    const float* w_rbf2 = (const float*)d_in[6];
    const float* w_sbf1 = (const float*)d_in[7];
    const float* w_sbf2 = (const float*)d_in[8];
    const float* w_kj   = (const float*)d_in[9];
    const float* b_kj   = (const float*)d_in[10];
    const float* w_ji   = (const float*)d_in[11];
    const float* b_ji   = (const float*)d_in[12];
    const float* w_down = (const float*)d_in[13];
    const float* w_up   = (const float*)d_in[14];
    const float* r1w1   = (const float*)d_in[15];
    const float* r1b1   = (const float*)d_in[16];
    const float* r1w2   = (const float*)d_in[17];
    const float* r1b2   = (const float*)d_in[18];
    const float* w_bs   = (const float*)d_in[19];
    const float* b_bs   = (const float*)d_in[20];
    const float* r2w1   = (const float*)d_in[21];
    const float* r2b1   = (const float*)d_in[22];
    const float* r2w2   = (const float*)d_in[23];
    const float* r2b2   = (const float*)d_in[24];
    const float* r3w1   = (const float*)d_in[25];
    const float* r3b1   = (const float*)d_in[26];
    const float* r3w2   = (const float*)d_in[27];
    const float* r3b2   = (const float*)d_in[28];

    const int E = in_sizes[0] / 128;
    const int T = in_sizes[2] / 42;

    float* OUT = (float*)d_out;
    float* W3  = (float*)((char*)d_ws + (size_t)E * 128 * 4);         // [E,64]
    float* W4  = (float*)((char*)d_ws + (size_t)E * 128 * 4
                                      + (size_t)E * 64 * 4);          // [E,64]

    int*   cnt      = (int*)d_ws;                            // [E]
    int*   offsets  = cnt + (E + 64);                        // [E+1]
    int*   partial  = offsets + (E + 64);                    // [<=1024]
    int*   blockoff = partial + 1024;                        // [<=1024]
    float* E1p      = (float*)((char*)d_ws + (4u << 20));    // [T,8]   96 MB
    int*   kjp      = (int*)((char*)d_ws + (102u << 20));    // [T]     12 MB
    float* re1      = (float*)((char*)d_ws + (116u << 20));  // [E,8]  9.6 MB
    char*  wimg     = (char*)d_ws + (130u << 20);            // 320 KB fp16 images
    int*   rank     = (int*)((char*)d_ws + (134u << 20));    // [T]     12 MB

    char* wkj_i  = wimg;
    char* wji_i  = wimg + 32768;
    char* wdn_i  = wimg + 65536;    // 16 KB (128x64)
    char* wup_i  = wimg + 81920;    // 16 KB (64x128)
    char* r1w1_i = wimg + 98304;
    char* r1w2_i = wimg + 131072;
    char* wbs_i  = wimg + 163840;
    char* r2w1_i = wimg + 196608;
    char* r2w2_i = wimg + 229376;
    char* r3w1_i = wimg + 262144;
    char* r3w2_i = wimg + 294912;

    WPrepArgs pa;
    pa.w[0]  = {w_kj,   wkj_i,  128, 128};
    pa.w[1]  = {w_ji,   wji_i,  128, 128};
    pa.w[2]  = {w_down, wdn_i,  128,  64};
    pa.w[3]  = {w_up,   wup_i,   64, 128};
    pa.w[4]  = {r1w1,   r1w1_i, 128, 128};
    pa.w[5]  = {r1w2,   r1w2_i, 128, 128};
    pa.w[6]  = {w_bs,   wbs_i,  128, 128};
    pa.w[7]  = {r2w1,   r2w1_i, 128, 128};
    pa.w[8]  = {r2w2,   r2w2_i, 128, 128};
    pa.w[9]  = {r3w1,   r3w1_i, 128, 128};
    pa.w[10] = {r3w2,   r3w2_i, 128, 128};

    const dim3 b256(256);
    const int gB  = (E + 63) / 64;
    const int gT  = (T + 255) / 256;
    const int gT4 = (T + 1023) / 1024;
    const int NB  = (E + 1023) / 1024;
    const int gE4 = (E + 3) / 4;
    const int gR  = (E * 8 + 255) / 256;

    wprep_kernel<<<dim3(4, 11), b256, 0, stream>>>(pa);
    rbf1_kernel<<<gR, b256, 0, stream>>>(rbf, w_rbf1, re1, E);
    hipMemsetAsync(cnt, 0, (size_t)E * 4, stream);
    count_rank_kernel<<<gT4, b256, 0, stream>>>(idx_ji, cnt, rank, T);
    scan_partial_kernel<<<NB, b256, 0, stream>>>(cnt, partial, E);
    scan_block_kernel<<<1, b256, 0, stream>>>(partial, blockoff, NB, offsets, E);
    scan_final_kernel<<<NB, b256, 0, stream>>>(cnt, blockoff, offsets, E);
    e1fill_kernel<<<gT, b256, 0, stream>>>(sbf, w_sbf1, idx_ji, idx_kj, rank, offsets, E1p, kjp, T);

    k1_kernel<<<gB, b256, 0, stream>>>(x, wkj_i, b_kj, re1, w_rbf2, wdn_i, W3, E);
    gather_kernel<<<gE4, b256, 0, stream>>>(E1p, kjp, w_sbf2, offsets, W3, W4, E);

    KBigArgs ka;
    ka.x = x; ka.W4 = W4; ka.out = OUT;
    ka.wji = wji_i; ka.wup = wup_i; ka.r1w1 = r1w1_i; ka.r1w2 = r1w2_i; ka.wbs = wbs_i;
    ka.r2w1 = r2w1_i; ka.r2w2 = r2w2_i; ka.r3w1 = r3w1_i; ka.r3w2 = r3w2_i;
    ka.bji = b_ji; ka.r1b1 = r1b1; ka.r1b2 = r1b2; ka.bbs = b_bs;
    ka.r2b1 = r2b1; ka.r2b2 = r2b2; ka.r3b1 = r3b1; ka.r3b2 = r3b2;
    ka.E = E;
    kbig_kernel<<<gB, b256, 0, stream>>>(ka);
}

// Round 16
// 998.966 us; speedup vs baseline: 1.4600x; 1.0147x over previous
//
#include <hip/hip_runtime.h>
#include <hip/hip_bf16.h>

// ---------------------------------------------------------------------------
// DimeNet++ interaction block, round 16:
//   Round-15 GEMM core (split-fp16 2-pass, fixed swizzle, 3 blocks/CU) +
//   triplet-path traffic cut:
//     - E1p stored fp16 (one 16B f16x8 per triplet; write 96->48 MB)
//     - W3  stored fp16 (xkjd gather table 76.8->38.4 MB, L2-friendlier)
//   Precision budget per r14 analysis: 2^-11 rel on O(1) values -> ~1e-3
//   absolute in agg; threshold margin stays >3x.
// ---------------------------------------------------------------------------

typedef __attribute__((ext_vector_type(8))) _Float16 f16x8;
typedef __attribute__((ext_vector_type(4))) float f32x4;

__device__ __forceinline__ float silu_f(float v) {
    return v * __builtin_amdgcn_rcpf(1.0f + __expf(-v));
}

// fp32x8 -> fp16 hi + exact residual lo
__device__ __forceinline__ void split44h(f32x4 a, f32x4 b, f16x8& hi, f16x8& lo) {
    float f[8] = {a[0], a[1], a[2], a[3], b[0], b[1], b[2], b[3]};
    #pragma unroll
    for (int j = 0; j < 8; ++j) {
        const _Float16 h = (_Float16)f[j];
        hi[j] = h;
        lo[j] = (_Float16)(f[j] - (float)h);
    }
}

__device__ __forceinline__ void gll16(const void* g, void* l) {
    __builtin_amdgcn_global_load_lds((const __attribute__((address_space(1))) void*)g,
                                     (__attribute__((address_space(3))) void*)l, 16, 0, 0);
}
__device__ __forceinline__ void stage8k(const char* g, _Float16* l, int lane, int wid) {
    #pragma unroll
    for (int i = 0; i < 2; ++i) {
        const int off = ((i * 4 + wid) << 10);
        gll16(g + off + lane * 16, (char*)l + off);
    }
}
__device__ __forceinline__ void stage4k(const char* g, _Float16* l, int lane, int wid) {
    const int off = (wid << 10);
    gll16(g + off + lane * 16, (char*)l + off);
}

// one 32-k step, 2-pass split-fp16 MFMA over NF col-frags
// slab layout: col c (64 B), chunk s stored at (s ^ ((c>>1)&3)); read chunk kq
template<int NF>
__device__ __forceinline__ void mfma_ks(f16x8 ah, f16x8 al, const _Float16* slot,
                                        int acol, int kq, f32x4* acc) {
    #pragma unroll
    for (int n = 0; n < NF; ++n) {
        const int c = n * 16 + acol;
        const int sw = (kq ^ ((c >> 1) & 3)) << 3;
        const f16x8 bh = *(const f16x8*)&slot[c * 32 + sw];
        acc[n] = __builtin_amdgcn_mfma_f32_16x16x32_f16(ah, bh, acc[n], 0, 0, 0);
        acc[n] = __builtin_amdgcn_mfma_f32_16x16x32_f16(al, bh, acc[n], 0, 0, 0);
    }
}

// read + split one t_lds A-fragment
__device__ __forceinline__ void tfrag(const float* tl, int rb, int q, int kq,
                                      f16x8& Ah, f16x8& Al) {
    const f32x4 ta = *(const f32x4*)&tl[rb + q * 32 + kq * 8];
    const f32x4 tb = *(const f32x4*)&tl[rb + q * 32 + kq * 8 + 4];
    split44h(ta, tb, Ah, Al);
}

// 4-phase 128-k GEMM from t_lds (N=128, 8 KB slabs at img+8192*i)
__device__ __forceinline__ void tgemm4(const char* img, const char* imgnext,
                                       _Float16* sA, _Float16* sB, const float* tl, int rb,
                                       int kq, int acol, int lane, int wid, f32x4* acc)
{
    f16x8 Ah[4], Al[4];
    #pragma unroll
    for (int q = 0; q < 4; ++q) tfrag(tl, rb, q, kq, Ah[q], Al[q]);

    stage8k(img + 8192, sB, lane, wid);
    mfma_ks<8>(Ah[0], Al[0], sA, acol, kq, acc); __syncthreads();
    stage8k(img + 16384, sA, lane, wid);
    mfma_ks<8>(Ah[1], Al[1], sB, acol, kq, acc); __syncthreads();
    stage8k(img + 24576, sB, lane, wid);
    mfma_ks<8>(Ah[2], Al[2], sA, acol, kq, acc); __syncthreads();
    if (imgnext) stage8k(imgnext, sA, lane, wid);
    mfma_ks<8>(Ah[3], Al[3], sB, acol, kq, acc); __syncthreads();
}

#define TPITCH 132

// ---------------- weight pre-conversion (fp16, swizzled image) --------------
struct WDesc { const float* src; char* dst; int K; int N; };
struct WPrepArgs { WDesc w[11]; };

__global__ void wprep_kernel(WPrepArgs args) {
    const WDesc d = args.w[blockIdx.y];
    const int h = blockIdx.x;
    if (h * 32 >= d.K) return;
    char* slab = d.dst + (size_t)h * d.N * 64;
    for (int idx = threadIdx.x; idx < d.N * 4; idx += 256) {
        const int c = idx >> 2, ch = idx & 3;
        f16x8 v;
        #pragma unroll
        for (int j = 0; j < 8; ++j)
            v[j] = (_Float16)d.src[(size_t)(h * 32 + ch * 8 + j) * d.N + c];
        *(f16x8*)(slab + c * 64 + ((ch ^ ((c >> 1) & 3)) << 4)) = v;
    }
}

// ---------------- prologue / CSR --------------------------------------------

__global__ void rbf1_kernel(const float* __restrict__ rbf, const float* __restrict__ w_rbf1,
                            float* __restrict__ re1, int E) {
    const int i = blockIdx.x * 256 + threadIdx.x;
    const int e = i >> 3, p = i & 7;
    if (e < E) {
        float s = 0.f;
        #pragma unroll
        for (int q = 0; q < 6; ++q) s = fmaf(rbf[e * 6 + q], w_rbf1[q * 8 + p], s);
        re1[i] = s;
    }
}

__global__ void count_rank_kernel(const int* __restrict__ idx_ji, int* __restrict__ cnt,
                                  int* __restrict__ rank, int T) {
    const int i = (blockIdx.x * 256 + threadIdx.x) * 4;
    if (i + 3 < T) {
        const int4 j = *(const int4*)&idx_ji[i];
        int4 r;
        r.x = atomicAdd(&cnt[j.x], 1);
        r.y = atomicAdd(&cnt[j.y], 1);
        r.z = atomicAdd(&cnt[j.z], 1);
        r.w = atomicAdd(&cnt[j.w], 1);
        *(int4*)&rank[i] = r;
    } else {
        for (int k = i; k < T; ++k) rank[k] = atomicAdd(&cnt[idx_ji[k]], 1);
    }
}

__global__ void scan_partial_kernel(const int* __restrict__ cnt, int* __restrict__ partial, int E) {
    __shared__ int red[256];
    const int tid = threadIdx.x;
    const int base = blockIdx.x * 1024 + tid * 4;
    int s = 0;
    #pragma unroll
    for (int i = 0; i < 4; ++i) { const int g = base + i; if (g < E) s += cnt[g]; }
    red[tid] = s;
    __syncthreads();
    for (int off = 128; off > 0; off >>= 1) {
        if (tid < off) red[tid] += red[tid + off];
        __syncthreads();
    }
    if (tid == 0) partial[blockIdx.x] = red[0];
}

__global__ void scan_block_kernel(const int* __restrict__ partial, int* __restrict__ blockoff,
                                  int NB, int* offsets, int E) {
    __shared__ int red[256];
    const int tid = threadIdx.x;
    int v[4]; int s = 0;
    #pragma unroll
    for (int i = 0; i < 4; ++i) { const int g = tid * 4 + i; v[i] = (g < NB) ? partial[g] : 0; s += v[i]; }
    red[tid] = s;
    __syncthreads();
    for (int off = 1; off < 256; off <<= 1) {
        const int add = (tid >= off) ? red[tid - off] : 0;
        __syncthreads();
        red[tid] += add;
        __syncthreads();
    }
    int excl = (tid == 0) ? 0 : red[tid - 1];
    #pragma unroll
    for (int i = 0; i < 4; ++i) { const int g = tid * 4 + i; if (g < NB) blockoff[g] = excl; excl += v[i]; }
    if (tid == 255) offsets[E] = red[255];
}

__global__ void scan_final_kernel(const int* __restrict__ cnt, const int* __restrict__ blockoff,
                                  int* __restrict__ offsets, int E) {
    __shared__ int red[256];
    const int tid = threadIdx.x;
    const int base = blockIdx.x * 1024 + tid * 4;
    int v[4]; int s = 0;
    #pragma unroll
    for (int i = 0; i < 4; ++i) { const int g = base + i; v[i] = (g < E) ? cnt[g] : 0; s += v[i]; }
    red[tid] = s;
    __syncthreads();
    for (int off = 1; off < 256; off <<= 1) {
        const int add = (tid >= off) ? red[tid - off] : 0;
        __syncthreads();
        red[tid] += add;
        __syncthreads();
    }
    int run = blockoff[blockIdx.x] + ((tid == 0) ? 0 : red[tid - 1]);
    #pragma unroll
    for (int i = 0; i < 4; ++i) {
        const int g = base + i;
        if (g < E) offsets[g] = run;
        run += v[i];
    }
}

__launch_bounds__(256, 3)
__global__ void e1fill_kernel(const float* __restrict__ sbf, const float* __restrict__ w_sbf1,
                              const int* __restrict__ idx_ji, const int* __restrict__ idx_kj,
                              const int* __restrict__ rank, const int* __restrict__ offsets,
                              _Float16* __restrict__ E1p, int* __restrict__ kjp, int T)
{
    __shared__ float s_lds[256 * 43];
    const int tid = threadIdx.x;
    const long long t0 = (long long)blockIdx.x * 256;
    const int nrow = min(256, (int)(T - t0));
    const int nel  = nrow * 42;
    const float* base = sbf + t0 * 42;

    for (int i = tid * 4; i + 3 < nel; i += 1024) {
        const float4 v = *(const float4*)&base[i];
        s_lds[(i + 0) + (i + 0) / 42] = v.x;
        s_lds[(i + 1) + (i + 1) / 42] = v.y;
        s_lds[(i + 2) + (i + 2) / 42] = v.z;
        s_lds[(i + 3) + (i + 3) / 42] = v.w;
    }
    const int tail0 = nel & ~3;
    if (tid < nel - tail0) { const int g = tail0 + tid; s_lds[g + g / 42] = base[g]; }
    __syncthreads();

    const int t = (int)t0 + tid;
    if (t >= T) return;
    const float* srow = &s_lds[tid * 43];
    float e1[8] = {0.f, 0.f, 0.f, 0.f, 0.f, 0.f, 0.f, 0.f};
    #pragma unroll
    for (int q = 0; q < 42; ++q) {
        const float s = srow[q];
        #pragma unroll
        for (int p = 0; p < 8; ++p) e1[p] = fmaf(s, w_sbf1[q * 8 + p], e1[p]);
    }
    f16x8 eh;
    #pragma unroll
    for (int p = 0; p < 8; ++p) eh[p] = (_Float16)e1[p];
    const int ji  = idx_ji[t];
    const int pos = offsets[ji] + rank[t];
    *(f16x8*)&E1p[(size_t)pos * 8] = eh;
    kjp[pos] = idx_kj[t];
}

// ---------------- gather: fp16 E1 stream + fp16 xkjd table ------------------
__launch_bounds__(256, 4)
__global__ void gather_kernel(const _Float16* __restrict__ E1p, const int* __restrict__ kjp,
                              const float* __restrict__ w_sbf2, const int* __restrict__ offsets,
                              const _Float16* __restrict__ xkjd, float* __restrict__ agg, int E)
{
    const int tid  = threadIdx.x;
    const int lane = tid & 63;
    const int e    = blockIdx.x * 4 + (tid >> 6);

    float w2[8];
    #pragma unroll
    for (int p = 0; p < 8; ++p) w2[p] = w_sbf2[p * 64 + lane];

    if (e >= E) return;
    const int j0 = __builtin_amdgcn_readfirstlane(offsets[e]);
    const int j1 = __builtin_amdgcn_readfirstlane(offsets[e + 1]);

    float acc = 0.f;
    if (j0 < j1) {
        int kj = __builtin_amdgcn_readfirstlane(kjp[j0]);
        f16x8 ev = *(const f16x8*)&E1p[(size_t)j0 * 8];
        float xv = (float)xkjd[(size_t)kj * 64 + lane];
        for (int j = j0; j < j1; ++j) {
            float xn = 0.f; f16x8 evn = {};
            if (j + 1 < j1) {
                const int kn = __builtin_amdgcn_readfirstlane(kjp[j + 1]);
                evn = *(const f16x8*)&E1p[(size_t)(j + 1) * 8];
                xn  = (float)xkjd[(size_t)kn * 64 + lane];
            }
            float sv = (float)ev[0] * w2[0];
            sv = fmaf((float)ev[1], w2[1], sv);
            sv = fmaf((float)ev[2], w2[2], sv);
            sv = fmaf((float)ev[3], w2[3], sv);
            sv = fmaf((float)ev[4], w2[4], sv);
            sv = fmaf((float)ev[5], w2[5], sv);
            sv = fmaf((float)ev[6], w2[6], sv);
            sv = fmaf((float)ev[7], w2[7], sv);
            acc = fmaf(xv, sv, acc);
            ev = evn; xv = xn;
        }
    }
    agg[(size_t)e * 64 + lane] = acc;
}

// ---------------- K1: W3 = silu((silu(x@w_kj+b)*rbf_e)@w_down)  (fp16 out) --
__launch_bounds__(256, 3)
__global__ void k1_kernel(const float* __restrict__ x, const char* __restrict__ wkj_i,
                          const float* __restrict__ b_kj, const float* __restrict__ re1,
                          const float* __restrict__ w_rbf2, const char* __restrict__ wdn_i,
                          _Float16* __restrict__ W3, int E)
{
    __shared__ _Float16 slotA[4096], slotB[4096];
    __shared__ float t_lds[64 * TPITCH];
    __shared__ float w2_lds[8 * 128];
    const int tid = threadIdx.x, lane = tid & 63, wid = tid >> 6;
    const int acol = lane & 15, kq = lane >> 4;
    const int rowW = blockIdx.x * 64 + wid * 16;
    const int arow = rowW + acol;
    const bool av = arow < E;

    stage8k(wkj_i, slotA, lane, wid);
    const float* xr = x + (size_t)arow * 128;
    f16x8 aH[4], aL[4];
    #pragma unroll
    for (int ks = 0; ks < 4; ++ks) {
        f32x4 a0 = f32x4{0.f, 0.f, 0.f, 0.f}, a1 = f32x4{0.f, 0.f, 0.f, 0.f};
        if (av) { a0 = *(const f32x4*)&xr[ks * 32 + kq * 8];
                  a1 = *(const f32x4*)&xr[ks * 32 + kq * 8 + 4]; }
        split44h(a0, a1, aH[ks], aL[ks]);
    }
    float bv[8];
    #pragma unroll
    for (int n = 0; n < 8; ++n) bv[n] = b_kj[n * 16 + acol];
    f32x4 e1a[4], e1b[4];
    #pragma unroll
    for (int r = 0; r < 4; ++r) {
        const int ge = rowW + kq * 4 + r;
        e1a[r] = f32x4{0.f, 0.f, 0.f, 0.f}; e1b[r] = f32x4{0.f, 0.f, 0.f, 0.f};
        if (ge < E) { e1a[r] = *(const f32x4*)&re1[(size_t)ge * 8];
                      e1b[r] = *(const f32x4*)&re1[(size_t)ge * 8 + 4]; }
    }
    for (int i = tid; i < 1024; i += 256) w2_lds[i] = w_rbf2[i];
    __syncthreads();

    f32x4 acc[8];
    #pragma unroll
    for (int n = 0; n < 8; ++n) acc[n] = f32x4{0.f, 0.f, 0.f, 0.f};

    stage8k(wkj_i + 8192, slotB, lane, wid);
    mfma_ks<8>(aH[0], aL[0], slotA, acol, kq, acc); __syncthreads();
    stage8k(wkj_i + 16384, slotA, lane, wid);
    mfma_ks<8>(aH[1], aL[1], slotB, acol, kq, acc); __syncthreads();
    stage8k(wkj_i + 24576, slotB, lane, wid);
    mfma_ks<8>(aH[2], aL[2], slotA, acol, kq, acc); __syncthreads();
    stage4k(wdn_i, slotA, lane, wid);
    mfma_ks<8>(aH[3], aL[3], slotB, acol, kq, acc); __syncthreads();

    #pragma unroll
    for (int n = 0; n < 8; ++n) {
        const int c = n * 16 + acol;
        float w2c[8];
        #pragma unroll
        for (int p = 0; p < 8; ++p) w2c[p] = w2_lds[p * 128 + c];
        #pragma unroll
        for (int r = 0; r < 4; ++r) {
            float s = e1a[r][0] * w2c[0];
            s = fmaf(e1a[r][1], w2c[1], s);
            s = fmaf(e1a[r][2], w2c[2], s);
            s = fmaf(e1a[r][3], w2c[3], s);
            s = fmaf(e1b[r][0], w2c[4], s);
            s = fmaf(e1b[r][1], w2c[5], s);
            s = fmaf(e1b[r][2], w2c[6], s);
            s = fmaf(e1b[r][3], w2c[7], s);
            t_lds[(wid * 16 + kq * 4 + r) * TPITCH + c] = silu_f(acc[n][r] + bv[n]) * s;
        }
    }
    __syncthreads();

    f32x4 acc2[4];
    #pragma unroll
    for (int n = 0; n < 4; ++n) acc2[n] = f32x4{0.f, 0.f, 0.f, 0.f};
    const int rb = (wid * 16 + acol) * TPITCH;

    f16x8 tH[4], tL[4];
    #pragma unroll
    for (int q = 0; q < 4; ++q) tfrag(t_lds, rb, q, kq, tH[q], tL[q]);

    stage4k(wdn_i + 4096, slotB, lane, wid);
    mfma_ks<4>(tH[0], tL[0], slotA, acol, kq, acc2); __syncthreads();
    stage4k(wdn_i + 8192, slotA, lane, wid);
    mfma_ks<4>(tH[1], tL[1], slotB, acol, kq, acc2); __syncthreads();
    stage4k(wdn_i + 12288, slotB, lane, wid);
    mfma_ks<4>(tH[2], tL[2], slotA, acol, kq, acc2); __syncthreads();
    mfma_ks<4>(tH[3], tL[3], slotB, acol, kq, acc2);

    #pragma unroll
    for (int n = 0; n < 4; ++n) {
        const int c = n * 16 + acol;
        #pragma unroll
        for (int r = 0; r < 4; ++r) {
            const int ge = rowW + kq * 4 + r;
            if (ge < E) W3[(size_t)ge * 64 + c] = (_Float16)silu_f(acc2[n][r]);
        }
    }
}

// ---------------- kbig: h0 -> res1 -> w_bs+skip -> res2 -> res3 (9 GEMMs) ---
struct KBigArgs {
    const float* x; const float* W4; float* out;
    const char *wji, *wup, *r1w1, *r1w2, *wbs, *r2w1, *r2w2, *r3w1, *r3w2;
    const float *bji, *r1b1, *r1b2, *bbs, *r2b1, *r2b2, *r3b1, *r3b2;
    int E;
};

__launch_bounds__(256, 3)
__global__ void kbig_kernel(KBigArgs A_)
{
    __shared__ _Float16 slotA[4096], slotB[4096];
    __shared__ float t_lds[64 * TPITCH];
    const int tid = threadIdx.x, lane = tid & 63, wid = tid >> 6;
    const int acol = lane & 15, kq = lane >> 4;
    const int rowW = blockIdx.x * 64 + wid * 16;
    const int arow = rowW + acol;
    const int E = A_.E;
    const bool av = arow < E;
    const int rb = (wid * 16 + acol) * TPITCH;

    stage8k(A_.wji, slotA, lane, wid);

    const float* xr = A_.x + (size_t)arow * 128;
    const float* wr = A_.W4 + (size_t)arow * 64;
    f16x8 aH[4], aL[4], uH[2], uL[2];
    #pragma unroll
    for (int ks = 0; ks < 4; ++ks) {
        f32x4 a0 = f32x4{0.f, 0.f, 0.f, 0.f}, a1 = f32x4{0.f, 0.f, 0.f, 0.f};
        if (av) { a0 = *(const f32x4*)&xr[ks * 32 + kq * 8];
                  a1 = *(const f32x4*)&xr[ks * 32 + kq * 8 + 4]; }
        split44h(a0, a1, aH[ks], aL[ks]);
    }
    #pragma unroll
    for (int ks = 0; ks < 2; ++ks) {
        f32x4 u0 = f32x4{0.f, 0.f, 0.f, 0.f}, u1 = f32x4{0.f, 0.f, 0.f, 0.f};
        if (av) { u0 = *(const f32x4*)&wr[ks * 32 + kq * 8];
                  u1 = *(const f32x4*)&wr[ks * 32 + kq * 8 + 4]; }
        split44h(u0, u1, uH[ks], uL[ks]);
    }
    __syncthreads();

    f32x4 acc[8];
    #pragma unroll
    for (int n = 0; n < 8; ++n) acc[n] = f32x4{0.f, 0.f, 0.f, 0.f};

    // GEMM1: x @ w_ji
    stage8k(A_.wji + 8192, slotB, lane, wid);
    mfma_ks<8>(aH[0], aL[0], slotA, acol, kq, acc); __syncthreads();
    stage8k(A_.wji + 16384, slotA, lane, wid);
    mfma_ks<8>(aH[1], aL[1], slotB, acol, kq, acc); __syncthreads();
    stage8k(A_.wji + 24576, slotB, lane, wid);
    mfma_ks<8>(aH[2], aL[2], slotA, acol, kq, acc); __syncthreads();
    stage8k(A_.wup, slotA, lane, wid);
    mfma_ks<8>(aH[3], aL[3], slotB, acol, kq, acc); __syncthreads();

    float res[8][4];
    #pragma unroll
    for (int n = 0; n < 8; ++n) {
        const float bv = A_.bji[n * 16 + acol];
        #pragma unroll
        for (int r = 0; r < 4; ++r) { res[n][r] = silu_f(acc[n][r] + bv); acc[n][r] = 0.f; }
    }

    // GEMM2: W4 @ w_up (K=64)
    stage8k(A_.wup + 8192, slotB, lane, wid);
    mfma_ks<8>(uH[0], uL[0], slotA, acol, kq, acc); __syncthreads();
    stage8k(A_.r1w1, slotA, lane, wid);
    mfma_ks<8>(uH[1], uL[1], slotB, acol, kq, acc); __syncthreads();

    #pragma unroll
    for (int n = 0; n < 8; ++n) {
        const int c = n * 16 + acol;
        #pragma unroll
        for (int r = 0; r < 4; ++r) {
            res[n][r] += silu_f(acc[n][r]);                     // h0
            t_lds[(wid * 16 + kq * 4 + r) * TPITCH + c] = res[n][r];
            acc[n][r] = 0.f;
        }
    }
    __syncthreads();

    // GEMM3: h0 @ r1w1 -> t1
    tgemm4(A_.r1w1, A_.r1w2, slotA, slotB, t_lds, rb, kq, acol, lane, wid, acc);
    #pragma unroll
    for (int n = 0; n < 8; ++n) {
        const float bv = A_.r1b1[n * 16 + acol];
        const int c = n * 16 + acol;
        #pragma unroll
        for (int r = 0; r < 4; ++r) {
            t_lds[(wid * 16 + kq * 4 + r) * TPITCH + c] = silu_f(acc[n][r] + bv);
            acc[n][r] = 0.f;
        }
    }
    __syncthreads();

    // GEMM4: t1 @ r1w2 -> t2 = h0 + silu(.)
    tgemm4(A_.r1w2, A_.wbs, slotA, slotB, t_lds, rb, kq, acol, lane, wid, acc);
    #pragma unroll
    for (int n = 0; n < 8; ++n) {
        const float bv = A_.r1b2[n * 16 + acol];
        const int c = n * 16 + acol;
        #pragma unroll
        for (int r = 0; r < 4; ++r) {
            t_lds[(wid * 16 + kq * 4 + r) * TPITCH + c] = res[n][r] + silu_f(acc[n][r] + bv);
            acc[n][r] = 0.f;
        }
    }
    __syncthreads();

    // GEMM5: t2 @ w_bs -> h2 = silu(.) + x
    tgemm4(A_.wbs, A_.r2w1, slotA, slotB, t_lds, rb, kq, acol, lane, wid, acc);
    #pragma unroll
    for (int n = 0; n < 8; ++n) {
        const float bv = A_.bbs[n * 16 + acol];
        const int c = n * 16 + acol;
        #pragma unroll
        for (int r = 0; r < 4; ++r) {
            const int ge = rowW + kq * 4 + r;
            const float xv = (ge < E) ? A_.x[(size_t)ge * 128 + c] : 0.f;
            res[n][r] = silu_f(acc[n][r] + bv) + xv;            // h2
            t_lds[(wid * 16 + kq * 4 + r) * TPITCH + c] = res[n][r];
            acc[n][r] = 0.f;
        }
    }
    __syncthreads();

    // GEMM6: h2 @ r2w1 -> t3
    tgemm4(A_.r2w1, A_.r2w2, slotA, slotB, t_lds, rb, kq, acol, lane, wid, acc);
    #pragma unroll
    for (int n = 0; n < 8; ++n) {
        const float bv = A_.r2b1[n * 16 + acol];
        const int c = n * 16 + acol;
        #pragma unroll
        for (int r = 0; r < 4; ++r) {
            t_lds[(wid * 16 + kq * 4 + r) * TPITCH + c] = silu_f(acc[n][r] + bv);
            acc[n][r] = 0.f;
        }
    }
    __syncthreads();

    // GEMM7: t3 @ r2w2 -> h3 = h2 + silu(.)
    tgemm4(A_.r2w2, A_.r3w1, slotA, slotB, t_lds, rb, kq, acol, lane, wid, acc);
    #pragma unroll
    for (int n = 0; n < 8; ++n) {
        const float bv = A_.r2b2[n * 16 + acol];
        const int c = n * 16 + acol;
        #pragma unroll
        for (int r = 0; r < 4; ++r) {
            res[n][r] += silu_f(acc[n][r] + bv);                // h3
            t_lds[(wid * 16 + kq * 4 + r) * TPITCH + c] = res[n][r];
            acc[n][r] = 0.f;
        }
    }
    __syncthreads();

    // GEMM8: h3 @ r3w1 -> t4
    tgemm4(A_.r3w1, A_.r3w2, slotA, slotB, t_lds, rb, kq, acol, lane, wid, acc);
    #pragma unroll
    for (int n = 0; n < 8; ++n) {
        const float bv = A_.r3b1[n * 16 + acol];
        const int c = n * 16 + acol;
        #pragma unroll
        for (int r = 0; r < 4; ++r) {
            t_lds[(wid * 16 + kq * 4 + r) * TPITCH + c] = silu_f(acc[n][r] + bv);
            acc[n][r] = 0.f;
        }
    }
    __syncthreads();

    // GEMM9: t4 @ r3w2 -> out = h3 + silu(.)
    tgemm4(A_.r3w2, nullptr, slotA, slotB, t_lds, rb, kq, acol, lane, wid, acc);
    #pragma unroll
    for (int n = 0; n < 8; ++n) {
        const float bv = A_.r3b2[n * 16 + acol];
        const int c = n * 16 + acol;
        #pragma unroll
        for (int r = 0; r < 4; ++r) {
            const int ge = rowW + kq * 4 + r;
            if (ge < E)
                A_.out[(size_t)ge * 128 + c] = res[n][r] + silu_f(acc[n][r] + bv);
        }
    }
}

// ---------------------------------------------------------------------------

extern "C" void kernel_launch(void* const* d_in, const int* in_sizes, int n_in,
                              void* d_out, int out_size, void* d_ws, size_t ws_size,
                              hipStream_t stream)
{
    const float* x      = (const float*)d_in[0];
    const float* rbf    = (const float*)d_in[1];
    const float* sbf    = (const float*)d_in[2];
    const int*   idx_kj = (const int*)d_in[3];
    const int*   idx_ji = (const int*)d_in[4];
    const float* w_rbf1 = (const float*)d_in[5];
    const float* w_rbf2 = (const float*)d_in[6];
    const float* w_sbf1 = (const float*)d_in[7];
    const float* w_sbf2 = (const float*)d_in[8];
    const float* w_kj   = (const float*)d_in[9];
    const float* b_kj   = (const float*)d_in[10];
    const float* w_ji   = (const float*)d_in[11];
    const float* b_ji   = (const float*)d_in[12];
    const float* w_down = (const float*)d_in[13];
    const float* w_up   = (const float*)d_in[14];
    const float* r1w1   = (const float*)d_in[15];
    const float* r1b1   = (const float*)d_in[16];
    const float* r1w2   = (const float*)d_in[17];
    const float* r1b2   = (const float*)d_in[18];
    const float* w_bs   = (const float*)d_in[19];
    const float* b_bs   = (const float*)d_in[20];
    const float* r2w1   = (const float*)d_in[21];
    const float* r2b1   = (const float*)d_in[22];
    const float* r2w2   = (const float*)d_in[23];
    const float* r2b2   = (const float*)d_in[24];
    const float* r3w1   = (const float*)d_in[25];
    const float* r3b1   = (const float*)d_in[26];
    const float* r3w2   = (const float*)d_in[27];
    const float* r3b2   = (const float*)d_in[28];

    const int E = in_sizes[0] / 128;
    const int T = in_sizes[2] / 42;

    float* OUT = (float*)d_out;
    _Float16* W3 = (_Float16*)((char*)d_ws + (size_t)E * 128 * 4);    // [E,64] fp16
    float* W4  = (float*)((char*)d_ws + (size_t)E * 128 * 4
                                      + (size_t)E * 64 * 4);          // [E,64] fp32

    int*   cnt      = (int*)d_ws;                            // [E]
    int*   offsets  = cnt + (E + 64);                        // [E+1]
    int*   partial  = offsets + (E + 64);                    // [<=1024]
    int*   blockoff = partial + 1024;                        // [<=1024]
    _Float16* E1p   = (_Float16*)((char*)d_ws + (4u << 20)); // [T,8] fp16  48 MB
    int*   kjp      = (int*)((char*)d_ws + (102u << 20));    // [T]     12 MB
    float* re1      = (float*)((char*)d_ws + (116u << 20));  // [E,8]  9.6 MB
    char*  wimg     = (char*)d_ws + (130u << 20);            // 320 KB fp16 images
    int*   rank     = (int*)((char*)d_ws + (134u << 20));    // [T]     12 MB

    char* wkj_i  = wimg;
    char* wji_i  = wimg + 32768;
    char* wdn_i  = wimg + 65536;    // 16 KB (128x64)
    char* wup_i  = wimg + 81920;    // 16 KB (64x128)
    char* r1w1_i = wimg + 98304;
    char* r1w2_i = wimg + 131072;
    char* wbs_i  = wimg + 163840;
    char* r2w1_i = wimg + 196608;
    char* r2w2_i = wimg + 229376;
    char* r3w1_i = wimg + 262144;
    char* r3w2_i = wimg + 294912;

    WPrepArgs pa;
    pa.w[0]  = {w_kj,   wkj_i,  128, 128};
    pa.w[1]  = {w_ji,   wji_i,  128, 128};
    pa.w[2]  = {w_down, wdn_i,  128,  64};
    pa.w[3]  = {w_up,   wup_i,   64, 128};
    pa.w[4]  = {r1w1,   r1w1_i, 128, 128};
    pa.w[5]  = {r1w2,   r1w2_i, 128, 128};
    pa.w[6]  = {w_bs,   wbs_i,  128, 128};
    pa.w[7]  = {r2w1,   r2w1_i, 128, 128};
    pa.w[8]  = {r2w2,   r2w2_i, 128, 128};
    pa.w[9]  = {r3w1,   r3w1_i, 128, 128};
    pa.w[10] = {r3w2,   r3w2_i, 128, 128};

    const dim3 b256(256);
    const int gB  = (E + 63) / 64;
    const int gT  = (T + 255) / 256;
    const int gT4 = (T + 1023) / 1024;
    const int NB  = (E + 1023) / 1024;
    const int gE4 = (E + 3) / 4;
    const int gR  = (E * 8 + 255) / 256;

    wprep_kernel<<<dim3(4, 11), b256, 0, stream>>>(pa);
    rbf1_kernel<<<gR, b256, 0, stream>>>(rbf, w_rbf1, re1, E);
    hipMemsetAsync(cnt, 0, (size_t)E * 4, stream);
    count_rank_kernel<<<gT4, b256, 0, stream>>>(idx_ji, cnt, rank, T);
    scan_partial_kernel<<<NB, b256, 0, stream>>>(cnt, partial, E);
    scan_block_kernel<<<1, b256, 0, stream>>>(partial, blockoff, NB, offsets, E);
    scan_final_kernel<<<NB, b256, 0, stream>>>(cnt, blockoff, offsets, E);
    e1fill_kernel<<<gT, b256, 0, stream>>>(sbf, w_sbf1, idx_ji, idx_kj, rank, offsets, E1p, kjp, T);

    k1_kernel<<<gB, b256, 0, stream>>>(x, wkj_i, b_kj, re1, w_rbf2, wdn_i, W3, E);
    gather_kernel<<<gE4, b256, 0, stream>>>(E1p, kjp, w_sbf2, offsets, W3, W4, E);

    KBigArgs ka;
    ka.x = x; ka.W4 = W4; ka.out = OUT;
    ka.wji = wji_i; ka.wup = wup_i; ka.r1w1 = r1w1_i; ka.r1w2 = r1w2_i; ka.wbs = wbs_i;
    ka.r2w1 = r2w1_i; ka.r2w2 = r2w2_i; ka.r3w1 = r3w1_i; ka.r3w2 = r3w2_i;
    ka.bji = b_ji; ka.r1b1 = r1b1; ka.r1b2 = r1b2; ka.bbs = b_bs;
    ka.r2b1 = r2b1; ka.r2b2 = r2b2; ka.r3b1 = r3b1; ka.r3b2 = r3b2;
    ka.E = E;
    kbig_kernel<<<gB, b256, 0, stream>>>(ka);
}